// Round 4
// baseline (8248.500 us; speedup 1.0000x reference)
//
#include <hip/hip_runtime.h>
#include <hip/hip_bf16.h>

#define NN 50000
#define EE 800000

// ---------- helpers ----------
__device__ __forceinline__ unsigned fkey(float x){
  unsigned u = __float_as_uint(x);
  return (u & 0x80000000u) ? ~u : (u | 0x80000000u);   // order-preserving key
}
__device__ __forceinline__ float funkey(unsigned k){
  unsigned u = (k & 0x80000000u) ? (k & 0x7fffffffu) : ~k;
  return __uint_as_float(u);
}

// radial MLP: basis[16] -> silu(64) -> 5 path weights. Weight ptrs pre-offset by layer.
__device__ __forceinline__ void radial_mlp(const float* __restrict__ W1,
                                           const float* __restrict__ b1,
                                           const float* __restrict__ W2,
                                           const float* __restrict__ b2,
                                           const float* basis, float* rk){
#pragma unroll
  for(int p=0;p<5;p++) rk[p]=b2[p];
  for(int h=0;h<64;h++){
    float t=b1[h];
#pragma unroll
    for(int b=0;b<16;b++) t += basis[b]*W1[b*64+h];     // uniform idx -> s_load
    float sg = t/(1.f+__expf(-t));
#pragma unroll
    for(int p=0;p<5;p++) rk[p]+=sg*W2[h*5+p];
  }
}

__device__ __forceinline__ void edge_geom(const float* __restrict__ pos, int src, int dst,
                                          float& yx, float& yy, float& yz, float* basis){
  float px = pos[src*3+0]-pos[dst*3+0];
  float py = pos[src*3+1]-pos[dst*3+1];
  float pz = pos[src*3+2]-pos[dst*3+2];
  float r = sqrtf(px*px+py*py+pz*pz);
  float inv = 1.f/(r+1e-9f);
  yx=px*inv; yy=py*inv; yz=pz*inv;
#pragma unroll
  for(int b=0;b<16;b++){
    float d=(r - (10.f/15.f)*(float)b)*1.6f;            // centers linspace(0,10,16); width = MAXR/NB = 0.625
    basis[b]=__expf(-d*d);
  }
}

// ---------- s = f @ W_in ----------
__global__ __launch_bounds__(256) void k_sinit(const float* __restrict__ f,
                                               const float* __restrict__ Win,
                                               float* __restrict__ s){
  int n = blockIdx.x*256 + threadIdx.x;
  if(n>=NN) return;
  float fi[32], acc[32];
  const float4* fp = reinterpret_cast<const float4*>(f + (size_t)n*32);
#pragma unroll
  for(int i=0;i<8;i++){ float4 t=fp[i]; fi[4*i]=t.x; fi[4*i+1]=t.y; fi[4*i+2]=t.z; fi[4*i+3]=t.w; }
#pragma unroll
  for(int j=0;j<32;j++) acc[j]=0.f;
  for(int i=0;i<32;i++){
    float c=fi[i];
#pragma unroll
    for(int j=0;j<32;j++) acc[j]+=c*Win[i*32+j];
  }
  float4* sp = reinterpret_cast<float4*>(s + (size_t)n*32);
#pragma unroll
  for(int i=0;i<8;i++){ float4 t; t.x=acc[4*i]; t.y=acc[4*i+1]; t.z=acc[4*i+2]; t.w=acc[4*i+3]; sp[i]=t; }
}

// ---------- per-node precompute: q and hoisted TP operands (weight ptrs pre-offset by layer) ----------
__global__ __launch_bounds__(256) void k_nodeprep(
  const float* __restrict__ s, const float* __restrict__ v,
  const float* __restrict__ Wqs, const float* __restrict__ Wqv,
  const float* __restrict__ Kss, const float* __restrict__ Ksv, const float* __restrict__ Kvs,
  const float* __restrict__ Kvvs, const float* __restrict__ Kvvv,
  const float* __restrict__ Vss, const float* __restrict__ Vsv, const float* __restrict__ Vvs,
  const float* __restrict__ Vvvs, const float* __restrict__ Vvvv,
  float* __restrict__ q_s, float* __restrict__ q_v,
  float* __restrict__ AKss, float* __restrict__ AKsv, float* __restrict__ PKvs,
  float* __restrict__ PKvvs, float* __restrict__ PKvvv,
  float* __restrict__ AVss, float* __restrict__ AVsv, float* __restrict__ PVvs,
  float* __restrict__ PVvvs, float* __restrict__ PVvvv)
{
  int n = blockIdx.x*256 + threadIdx.x;
  if(n>=NN) return;
  float sn[32], vn[48];
  const float4* sp=reinterpret_cast<const float4*>(s+(size_t)n*32);
#pragma unroll
  for(int i=0;i<8;i++){ float4 t=sp[i]; sn[4*i]=t.x; sn[4*i+1]=t.y; sn[4*i+2]=t.z; sn[4*i+3]=t.w; }
  const float4* vp=reinterpret_cast<const float4*>(v+(size_t)n*48);
#pragma unroll
  for(int i=0;i<12;i++){ float4 t=vp[i]; vn[4*i]=t.x; vn[4*i+1]=t.y; vn[4*i+2]=t.z; vn[4*i+3]=t.w; }

  // scalar -> 32-wide mats: q_s, AK_ss, AV_ss
#define SMAT32(W, OUT) { float acc[32]; \
  _Pragma("unroll") for(int j=0;j<32;j++) acc[j]=0.f; \
  for(int i=0;i<32;i++){ float c=sn[i]; \
    _Pragma("unroll") for(int j=0;j<32;j++) acc[j]+=c*W[i*32+j]; } \
  _Pragma("unroll") for(int j=0;j<32;j++) OUT[(size_t)n*32+j]=acc[j]; }
  SMAT32(Wqs, q_s)
  SMAT32(Kss, AKss)
  SMAT32(Vss, AVss)
#undef SMAT32
  // scalar -> 16-wide mats: AK_sv, AV_sv
#define SMAT16(W, OUT) { float acc[16]; \
  _Pragma("unroll") for(int j=0;j<16;j++) acc[j]=0.f; \
  for(int i=0;i<32;i++){ float c=sn[i]; \
    _Pragma("unroll") for(int j=0;j<16;j++) acc[j]+=c*W[i*16+j]; } \
  _Pragma("unroll") for(int j=0;j<16;j++) OUT[(size_t)n*16+j]=acc[j]; }
  SMAT16(Ksv, AKsv)
  SMAT16(Vsv, AVsv)
#undef SMAT16
  // vector -> 16-wide mats ([V,V]): q_v, PK_vs, PK_vvv, PV_vs, PV_vvv : out[w][c]=sum_t vn[t][c]*W[t*16+w]
#define VMAT16(W, OUT) \
  for(int w=0;w<16;w++){ float ax=0,ay=0,az=0; \
    _Pragma("unroll") for(int t=0;t<16;t++){ float wt=W[t*16+w]; ax+=vn[t*3]*wt; ay+=vn[t*3+1]*wt; az+=vn[t*3+2]*wt; } \
    OUT[(size_t)n*48+w*3]=ax; OUT[(size_t)n*48+w*3+1]=ay; OUT[(size_t)n*48+w*3+2]=az; }
  VMAT16(Wqv, q_v)
  VMAT16(Kvs, PKvs)
  VMAT16(Kvvv, PKvvv)
  VMAT16(Vvs, PVvs)
  VMAT16(Vvvv, PVvvv)
#undef VMAT16
  // vector -> 32-wide mats ([V,S]): PK_vvs, PV_vvs : out[j][c]=sum_t vn[t][c]*W[t*32+j]
#define VMAT32(W, OUT) \
  for(int j=0;j<32;j++){ float ax=0,ay=0,az=0; \
    _Pragma("unroll") for(int t=0;t<16;t++){ float wt=W[t*32+j]; ax+=vn[t*3]*wt; ay+=vn[t*3+1]*wt; az+=vn[t*3+2]*wt; } \
    OUT[(size_t)n*96+j*3]=ax; OUT[(size_t)n*96+j*3+1]=ay; OUT[(size_t)n*96+j*3+2]=az; }
  VMAT32(Kvvs, PKvvs)
  VMAT32(Vvvs, PVvvs)
#undef VMAT32
}

// ---------- edge pass A: logits + segment max ----------
__global__ __launch_bounds__(256) void k_edgeA(
  const float* __restrict__ pos, const int* __restrict__ esrc, const int* __restrict__ edst,
  const float* __restrict__ W1, const float* __restrict__ b1,
  const float* __restrict__ W2, const float* __restrict__ b2,
  const float* __restrict__ q_s, const float* __restrict__ q_v,
  const float* __restrict__ AKss, const float* __restrict__ AKsv,
  const float* __restrict__ PKvs, const float* __restrict__ PKvvs, const float* __restrict__ PKvvv,
  float* __restrict__ logit, unsigned* __restrict__ mxu)
{
  int e = blockIdx.x*256 + threadIdx.x;
  if(e>=EE) return;
  int src=esrc[e], dst=edst[e];
  float yx,yy,yz, basis[16];
  edge_geom(pos,src,dst,yx,yy,yz,basis);
  float rk[5];
  radial_mlp(W1,b1,W2,b2,basis,rk);

  float lg=0.f;
  const float* qs = q_s + (size_t)dst*32;
  const float* As = AKss + (size_t)src*32;
  const float* Pz = PKvvs + (size_t)src*96;
  for(int j=0;j<32;j++){
    float d = yx*Pz[j*3]+yy*Pz[j*3+1]+yz*Pz[j*3+2];
    lg += qs[j]*(rk[0]*As[j] + rk[3]*d);
  }
  const float* qv = q_v + (size_t)dst*48;
  const float* Asv= AKsv + (size_t)src*16;
  const float* Pv = PKvs + (size_t)src*48;
  const float* Pw = PKvvv+ (size_t)src*48;
  for(int w=0;w<16;w++){
    float ax=Pw[w*3],ay=Pw[w*3+1],az=Pw[w*3+2];
    float cx=ay*yz-az*yy, cy=az*yx-ax*yz, cz=ax*yy-ay*yx;   // cross(Pvvv, y)
    float aw=rk[1]*Asv[w];
    float kx=aw*yx + rk[2]*Pv[w*3]   + rk[4]*cx;
    float ky=aw*yy + rk[2]*Pv[w*3+1] + rk[4]*cy;
    float kz=aw*yz + rk[2]*Pv[w*3+2] + rk[4]*cz;
    lg += qv[w*3]*kx + qv[w*3+1]*ky + qv[w*3+2]*kz;
  }
  lg *= 0.11180339887498948f;   // (S + 3V)^-0.5 = 80^-0.5
  logit[e]=lg;
  atomicMax(&mxu[dst], fkey(lg));
}

// ---------- edge pass B: a=exp(logit-max), accumulate z and a*m ----------
__global__ __launch_bounds__(256) void k_edgeB(
  const float* __restrict__ pos, const int* __restrict__ esrc, const int* __restrict__ edst,
  const float* __restrict__ W1, const float* __restrict__ b1,
  const float* __restrict__ W2, const float* __restrict__ b2,
  const float* __restrict__ logit, const unsigned* __restrict__ mxu,
  const float* __restrict__ AVss, const float* __restrict__ AVsv,
  const float* __restrict__ PVvs, const float* __restrict__ PVvvs, const float* __restrict__ PVvvv,
  float* __restrict__ z, float* __restrict__ sacc, float* __restrict__ vacc)
{
  int e = blockIdx.x*256 + threadIdx.x;
  if(e>=EE) return;
  int src=esrc[e], dst=edst[e];
  float yx,yy,yz, basis[16];
  edge_geom(pos,src,dst,yx,yy,yz,basis);
  float rv[5];
  radial_mlp(W1,b1,W2,b2,basis,rv);

  float mx = funkey(mxu[dst]);
  float a  = __expf(logit[e]-mx);
  atomicAdd(&z[dst], a);

  const float* As = AVss + (size_t)src*32;
  const float* Pz = PVvvs + (size_t)src*96;
  float* so = sacc + (size_t)dst*32;
  for(int j=0;j<32;j++){
    float d = yx*Pz[j*3]+yy*Pz[j*3+1]+yz*Pz[j*3+2];
    atomicAdd(&so[j], a*(rv[0]*As[j] + rv[3]*d));
  }
  const float* Asv= AVsv + (size_t)src*16;
  const float* Pv = PVvs + (size_t)src*48;
  const float* Pw = PVvvv+ (size_t)src*48;
  float* vo = vacc + (size_t)dst*48;
  for(int w=0;w<16;w++){
    float ax=Pw[w*3],ay=Pw[w*3+1],az=Pw[w*3+2];
    float cx=ay*yz-az*yy, cy=az*yx-ax*yz, cz=ax*yy-ay*yx;
    float aw=rv[1]*Asv[w];
    atomicAdd(&vo[w*3],   a*(aw*yx + rv[2]*Pv[w*3]   + rv[4]*cx));
    atomicAdd(&vo[w*3+1], a*(aw*yy + rv[2]*Pv[w*3+1] + rv[4]*cy));
    atomicAdd(&vo[w*3+2], a*(aw*yz + rv[2]*Pv[w*3+2] + rv[4]*cz));
  }
}

// ---------- residual update ----------
__global__ __launch_bounds__(256) void k_update(
  float* __restrict__ s, float* __restrict__ v,
  const float* __restrict__ sacc, const float* __restrict__ vacc,
  const float* __restrict__ z)
{
  int n = blockIdx.x*256 + threadIdx.x;
  if(n>=NN) return;
  float zi = 1.f/(z[n]+1e-9f);
#pragma unroll 4
  for(int j=0;j<32;j++) s[(size_t)n*32+j] += sacc[(size_t)n*32+j]*zi;
#pragma unroll 4
  for(int t=0;t<48;t++) v[(size_t)n*48+t] += vacc[(size_t)n*48+t]*zi;
}

// ---------- readout: FullyConnectedTensorProduct (f32 output!) ----------
__global__ __launch_bounds__(256) void k_readout(
  const float* __restrict__ s, const float* __restrict__ v,
  const float* __restrict__ Wsss, const float* __restrict__ Wvvs,
  const float* __restrict__ Wsvv, const float* __restrict__ Wvsv, const float* __restrict__ Wvvv,
  float* __restrict__ out)
{
  int n = blockIdx.x*256 + threadIdx.x;
  if(n>=NN) return;
  float sn[32], vn[48];
  const float4* sp=reinterpret_cast<const float4*>(s+(size_t)n*32);
#pragma unroll
  for(int i=0;i<8;i++){ float4 t=sp[i]; sn[4*i]=t.x; sn[4*i+1]=t.y; sn[4*i+2]=t.z; sn[4*i+3]=t.w; }
  const float4* vp=reinterpret_cast<const float4*>(v+(size_t)n*48);
#pragma unroll
  for(int i=0;i<12;i++){ float4 t=vp[i]; vn[4*i]=t.x; vn[4*i+1]=t.y; vn[4*i+2]=t.z; vn[4*i+3]=t.w; }

  float os[16];
#pragma unroll
  for(int o=0;o<16;o++) os[o]=0.f;
  // sss: sum_{a,t} s_a s_t W[a,t,o]
  for(int a=0;a<32;a++){
    float sa=sn[a];
    for(int t=0;t<32;t++){
      float st=sa*sn[t];
      const float* w=Wsss+((size_t)a*32+t)*16;
#pragma unroll
      for(int o=0;o<16;o++) os[o]+=st*w[o];
    }
  }
  // vvs: sum_{a,b} (v_a . v_b) W[a,b,o]
  for(int a=0;a<16;a++){
    float ax=vn[a*3],ay=vn[a*3+1],az=vn[a*3+2];
    for(int b=0;b<16;b++){
      float d=ax*vn[b*3]+ay*vn[b*3+1]+az*vn[b*3+2];
      const float* w=Wvvs+((size_t)a*16+b)*16;
#pragma unroll
      for(int o=0;o<16;o++) os[o]+=d*w[o];
    }
  }
  float ov[24];
#pragma unroll
  for(int t=0;t<24;t++) ov[t]=0.f;
  // svv: out[o,i] += sum_w v_w[i] * (sum_a s_a W[a,w,o])
  for(int w=0;w<16;w++){
    float B[8];
#pragma unroll
    for(int o=0;o<8;o++) B[o]=0.f;
    for(int a=0;a<32;a++){
      const float* ww=Wsvv+((size_t)a*16+w)*8;
      float sa=sn[a];
#pragma unroll
      for(int o=0;o<8;o++) B[o]+=sa*ww[o];
    }
#pragma unroll
    for(int o=0;o<8;o++){ float b=B[o]; ov[o*3]+=b*vn[w*3]; ov[o*3+1]+=b*vn[w*3+1]; ov[o*3+2]+=b*vn[w*3+2]; }
  }
  // vsv: out[o,i] += sum_vv v_vv[i] * (sum_a s_a W[vv,a,o])
  for(int vv=0;vv<16;vv++){
    float B[8];
#pragma unroll
    for(int o=0;o<8;o++) B[o]=0.f;
    for(int a=0;a<32;a++){
      const float* ww=Wvsv+((size_t)vv*32+a)*8;
      float sa=sn[a];
#pragma unroll
      for(int o=0;o<8;o++) B[o]+=sa*ww[o];
    }
#pragma unroll
    for(int o=0;o<8;o++){ float b=B[o]; ov[o*3]+=b*vn[vv*3]; ov[o*3+1]+=b*vn[vv*3+1]; ov[o*3+2]+=b*vn[vv*3+2]; }
  }
  // vvv: out[o,i] += sum_{a,b} cross(v_a,v_b)[i] W[a,b,o]
  for(int a=0;a<16;a++){
    float ax=vn[a*3],ay=vn[a*3+1],az=vn[a*3+2];
    for(int b=0;b<16;b++){
      float bx=vn[b*3],by=vn[b*3+1],bz=vn[b*3+2];
      float cx=ay*bz-az*by, cy=az*bx-ax*bz, cz=ax*by-ay*bx;
      const float* w=Wvvv+((size_t)a*16+b)*8;
#pragma unroll
      for(int o=0;o<8;o++){ float wv=w[o]; ov[o*3]+=cx*wv; ov[o*3+1]+=cy*wv; ov[o*3+2]+=cz*wv; }
    }
  }
  float* op = out + (size_t)n*40;
#pragma unroll
  for(int o=0;o<16;o++) op[o]=os[o];
#pragma unroll
  for(int t=0;t<24;t++) op[16+t]=ov[t];
}

// ---------- launch ----------
extern "C" void kernel_launch(void* const* d_in, const int* in_sizes, int n_in,
                              void* d_out, int out_size, void* d_ws, size_t ws_size,
                              hipStream_t stream) {
  const float* f      = (const float*)d_in[0];
  const float* pos    = (const float*)d_in[1];
  const float* W_in   = (const float*)d_in[2];
  const float* Wq_s   = (const float*)d_in[3];
  const float* Wq_v   = (const float*)d_in[4];
  const float* Wk_ss  = (const float*)d_in[5];
  const float* Wk_sv  = (const float*)d_in[6];
  const float* Wk_vs  = (const float*)d_in[7];
  const float* Wk_vvs = (const float*)d_in[8];
  const float* Wk_vvv = (const float*)d_in[9];
  const float* W1k    = (const float*)d_in[10];
  const float* b1k    = (const float*)d_in[11];
  const float* W2k    = (const float*)d_in[12];
  const float* b2k    = (const float*)d_in[13];
  const float* Wv_ss  = (const float*)d_in[14];
  const float* Wv_sv  = (const float*)d_in[15];
  const float* Wv_vs  = (const float*)d_in[16];
  const float* Wv_vvs = (const float*)d_in[17];
  const float* Wv_vvv = (const float*)d_in[18];
  const float* W1v    = (const float*)d_in[19];
  const float* b1v    = (const float*)d_in[20];
  const float* W2v    = (const float*)d_in[21];
  const float* b2v    = (const float*)d_in[22];
  const float* Wr_sss = (const float*)d_in[23];
  const float* Wr_vvs = (const float*)d_in[24];
  const float* Wr_svv = (const float*)d_in[25];
  const float* Wr_vsv = (const float*)d_in[26];
  const float* Wr_vvv = (const float*)d_in[27];
  const int* esrc     = (const int*)d_in[28];
  const int* edst     = (const int*)d_in[29];

  float* w = (float*)d_ws;
  size_t off=0;
  auto take=[&](size_t ne){ float* p=w+off; off+=ne; return p; };
  float* s     = take((size_t)NN*32);
  float* v     = take((size_t)NN*48);
  float* q_s   = take((size_t)NN*32);
  float* q_v   = take((size_t)NN*48);
  float* AKss  = take((size_t)NN*32);
  float* AKsv  = take((size_t)NN*16);
  float* PKvs  = take((size_t)NN*48);
  float* PKvvs = take((size_t)NN*96);
  float* PKvvv = take((size_t)NN*48);
  float* AVss  = take((size_t)NN*32);
  float* AVsv  = take((size_t)NN*16);
  float* PVvs  = take((size_t)NN*48);
  float* PVvvs = take((size_t)NN*96);
  float* PVvvv = take((size_t)NN*48);
  float* logit = take((size_t)EE);
  unsigned* mxu= (unsigned*)take((size_t)NN);
  float* zz    = take((size_t)NN);
  float* sacc  = take((size_t)NN*32);
  float* vacc  = take((size_t)NN*48);

  const int NB_N = (NN+255)/256;
  const int NB_E = (EE+255)/256;

  hipMemsetAsync(v, 0, (size_t)NN*48*sizeof(float), stream);
  k_sinit<<<NB_N,256,0,stream>>>(f, W_in, s);

  for(int l=0;l<2;l++){
    k_nodeprep<<<NB_N,256,0,stream>>>(s, v,
      Wq_s+l*1024, Wq_v+l*256,
      Wk_ss+l*1024, Wk_sv+l*512, Wk_vs+l*256, Wk_vvs+l*512, Wk_vvv+l*256,
      Wv_ss+l*1024, Wv_sv+l*512, Wv_vs+l*256, Wv_vvs+l*512, Wv_vvv+l*256,
      q_s, q_v, AKss, AKsv, PKvs, PKvvs, PKvvv, AVss, AVsv, PVvs, PVvvs, PVvvv);
    hipMemsetAsync(mxu, 0, (size_t)NN*sizeof(unsigned), stream);
    hipMemsetAsync(zz,  0, (size_t)NN*sizeof(float), stream);
    hipMemsetAsync(sacc,0, (size_t)NN*32*sizeof(float), stream);
    hipMemsetAsync(vacc,0, (size_t)NN*48*sizeof(float), stream);
    k_edgeA<<<NB_E,256,0,stream>>>(pos, esrc, edst,
      W1k+l*1024, b1k+l*64, W2k+l*320, b2k+l*5,
      q_s, q_v, AKss, AKsv, PKvs, PKvvs, PKvvv, logit, mxu);
    k_edgeB<<<NB_E,256,0,stream>>>(pos, esrc, edst,
      W1v+l*1024, b1v+l*64, W2v+l*320, b2v+l*5,
      logit, mxu, AVss, AVsv, PVvs, PVvvs, PVvvv, zz, sacc, vacc);
    k_update<<<NB_N,256,0,stream>>>(s, v, sacc, vacc, zz);
  }

  k_readout<<<NB_N,256,0,stream>>>(s, v, Wr_sss, Wr_vvs, Wr_svv, Wr_vsv, Wr_vvv,
                                   (float*)d_out);
}

// Round 5
// 2927.710 us; speedup vs baseline: 2.8174x; 2.8174x over previous
//
#include <hip/hip_runtime.h>

#define NN 50000
#define EE 800000

// ---------- bf16 pack helpers (RNE) ----------
__device__ __forceinline__ unsigned f2bf(float f){
  unsigned u = __float_as_uint(f);
  return (u + 0x7fffu + ((u>>16)&1u)) >> 16;
}
__device__ __forceinline__ float bf2f(unsigned hs){ return __uint_as_float(hs<<16); }
__device__ __forceinline__ unsigned pk2(float a, float b){ return f2bf(a) | (f2bf(b)<<16); }

// radial MLP: basis[16] -> silu(64) -> 5 path weights. Weight ptrs pre-offset by layer.
__device__ __forceinline__ void radial_mlp(const float* __restrict__ W1,
                                           const float* __restrict__ b1,
                                           const float* __restrict__ W2,
                                           const float* __restrict__ b2,
                                           const float* basis, float* rk){
#pragma unroll
  for(int p=0;p<5;p++) rk[p]=b2[p];
  for(int h=0;h<64;h++){
    float t=b1[h];
#pragma unroll
    for(int b=0;b<16;b++) t += basis[b]*W1[b*64+h];     // uniform idx -> s_load
    float sg = t/(1.f+__expf(-t));
#pragma unroll
    for(int p=0;p<5;p++) rk[p]+=sg*W2[h*5+p];
  }
}

__device__ __forceinline__ void edge_geom(const float* __restrict__ pos, int src, int dst,
                                          float& yx, float& yy, float& yz, float* basis){
  float px = pos[src*3+0]-pos[dst*3+0];
  float py = pos[src*3+1]-pos[dst*3+1];
  float pz = pos[src*3+2]-pos[dst*3+2];
  float r = sqrtf(px*px+py*py+pz*pz);
  float inv = 1.f/(r+1e-9f);
  yx=px*inv; yy=py*inv; yz=pz*inv;
#pragma unroll
  for(int b=0;b<16;b++){
    float d=(r - (10.f/15.f)*(float)b)*1.6f;            // centers linspace(0,10,16); width = MAXR/NB = 0.625
    basis[b]=__expf(-d*d);
  }
}

// ---------- CSR build ----------
__global__ __launch_bounds__(256) void k_hist(const int* __restrict__ edst, int* __restrict__ deg){
  int e = blockIdx.x*256 + threadIdx.x;
  if(e<EE) atomicAdd(&deg[edst[e]], 1);
}

__global__ __launch_bounds__(1024) void k_scan(const int* __restrict__ deg, int* __restrict__ rowptr){
  __shared__ int sm[1024];
  __shared__ int carry;
  int t = threadIdx.x;
  if(t==0) carry=0;
  __syncthreads();
  for(int base=0; base<NN; base+=1024){
    int x = (base+t<NN)? deg[base+t] : 0;
    sm[t]=x; __syncthreads();
    for(int off=1; off<1024; off<<=1){
      int y = (t>=off)? sm[t-off] : 0;
      __syncthreads();
      sm[t]+=y;
      __syncthreads();
    }
    int incl = sm[t];
    if(base+t<NN) rowptr[base+t] = carry + incl - x;   // exclusive
    __syncthreads();
    if(t==1023) carry += sm[1023];
    __syncthreads();
  }
  if(t==0) rowptr[NN]=carry;
}

__global__ __launch_bounds__(256) void k_fill(const int* __restrict__ edst,
                                              const int* __restrict__ rowptr,
                                              int* __restrict__ cursor,
                                              int* __restrict__ eid){
  int e = blockIdx.x*256 + threadIdx.x;
  if(e>=EE) return;
  int d = edst[e];
  int p = atomicAdd(&cursor[d], 1);
  eid[rowptr[d]+p] = e;
}

// ---------- s = f @ W_in ----------
__global__ __launch_bounds__(256) void k_sinit(const float* __restrict__ f,
                                               const float* __restrict__ Win,
                                               float* __restrict__ s){
  int n = blockIdx.x*256 + threadIdx.x;
  if(n>=NN) return;
  float fi[32], acc[32];
  const float4* fp = reinterpret_cast<const float4*>(f + (size_t)n*32);
#pragma unroll
  for(int i=0;i<8;i++){ float4 t=fp[i]; fi[4*i]=t.x; fi[4*i+1]=t.y; fi[4*i+2]=t.z; fi[4*i+3]=t.w; }
#pragma unroll
  for(int j=0;j<32;j++) acc[j]=0.f;
  for(int i=0;i<32;i++){
    float c=fi[i];
#pragma unroll
    for(int j=0;j<32;j++) acc[j]+=c*Win[i*32+j];
  }
  float4* sp = reinterpret_cast<float4*>(s + (size_t)n*32);
#pragma unroll
  for(int i=0;i<8;i++){ float4 t; t.x=acc[4*i]; t.y=acc[4*i+1]; t.z=acc[4*i+2]; t.w=acc[4*i+3]; sp[i]=t; }
}

// ---------- per-node precompute into packed rows ----------
// QP[n][80]  : [q_s 0..31][q_v 32..79]
// SP[n][480] : [AKss 0][AKsv 32][PKvs 48][PKvvs 96][PKvvv 192]
//              [AVss 240][AVsv 272][PVvs 288][PVvvs 336][PVvvv 432]
__global__ __launch_bounds__(256) void k_nodeprep(
  const float* __restrict__ s, const float* __restrict__ v,
  const float* __restrict__ Wqs, const float* __restrict__ Wqv,
  const float* __restrict__ Kss, const float* __restrict__ Ksv, const float* __restrict__ Kvs,
  const float* __restrict__ Kvvs, const float* __restrict__ Kvvv,
  const float* __restrict__ Vss, const float* __restrict__ Vsv, const float* __restrict__ Vvs,
  const float* __restrict__ Vvvs, const float* __restrict__ Vvvv,
  float* __restrict__ QP, float* __restrict__ SP)
{
  int n = blockIdx.x*256 + threadIdx.x;
  if(n>=NN) return;
  float sn[32], vn[48];
  const float4* sp=reinterpret_cast<const float4*>(s+(size_t)n*32);
#pragma unroll
  for(int i=0;i<8;i++){ float4 t=sp[i]; sn[4*i]=t.x; sn[4*i+1]=t.y; sn[4*i+2]=t.z; sn[4*i+3]=t.w; }
  const float4* vp=reinterpret_cast<const float4*>(v+(size_t)n*48);
#pragma unroll
  for(int i=0;i<12;i++){ float4 t=vp[i]; vn[4*i]=t.x; vn[4*i+1]=t.y; vn[4*i+2]=t.z; vn[4*i+3]=t.w; }

  float* qrow = QP + (size_t)n*80;
  float* brow = SP + (size_t)n*480;

#define SMAT32(W, OUTP) { float acc[32]; \
  _Pragma("unroll") for(int j=0;j<32;j++) acc[j]=0.f; \
  for(int i=0;i<32;i++){ float c=sn[i]; \
    _Pragma("unroll") for(int j=0;j<32;j++) acc[j]+=c*W[i*32+j]; } \
  _Pragma("unroll") for(int j=0;j<32;j++) (OUTP)[j]=acc[j]; }
#define SMAT16(W, OUTP) { float acc[16]; \
  _Pragma("unroll") for(int j=0;j<16;j++) acc[j]=0.f; \
  for(int i=0;i<32;i++){ float c=sn[i]; \
    _Pragma("unroll") for(int j=0;j<16;j++) acc[j]+=c*W[i*16+j]; } \
  _Pragma("unroll") for(int j=0;j<16;j++) (OUTP)[j]=acc[j]; }
#define VMAT16(W, OUTP) \
  for(int w=0;w<16;w++){ float ax=0,ay=0,az=0; \
    _Pragma("unroll") for(int t=0;t<16;t++){ float wt=W[t*16+w]; ax+=vn[t*3]*wt; ay+=vn[t*3+1]*wt; az+=vn[t*3+2]*wt; } \
    (OUTP)[w*3]=ax; (OUTP)[w*3+1]=ay; (OUTP)[w*3+2]=az; }
#define VMAT32(W, OUTP) \
  for(int j=0;j<32;j++){ float ax=0,ay=0,az=0; \
    _Pragma("unroll") for(int t=0;t<16;t++){ float wt=W[t*32+j]; ax+=vn[t*3]*wt; ay+=vn[t*3+1]*wt; az+=vn[t*3+2]*wt; } \
    (OUTP)[j*3]=ax; (OUTP)[j*3+1]=ay; (OUTP)[j*3+2]=az; }

  SMAT32(Wqs, qrow)
  VMAT16(Wqv, qrow+32)
  SMAT32(Kss, brow)
  SMAT16(Ksv, brow+32)
  VMAT16(Kvs, brow+48)
  VMAT32(Kvvs, brow+96)
  VMAT16(Kvvv, brow+192)
  SMAT32(Vss, brow+240)
  SMAT16(Vsv, brow+272)
  VMAT16(Vvs, brow+288)
  VMAT32(Vvvs, brow+336)
  VMAT16(Vvvv, brow+432)
#undef SMAT32
#undef SMAT16
#undef VMAT16
#undef VMAT32
}

// ---------- fused edge pass: logit + bf16 message record, NO atomics ----------
__global__ __launch_bounds__(256) void k_edge(
  const float* __restrict__ pos, const int* __restrict__ esrc, const int* __restrict__ edst,
  const float* __restrict__ W1k, const float* __restrict__ b1k,
  const float* __restrict__ W2k, const float* __restrict__ b2k,
  const float* __restrict__ W1v, const float* __restrict__ b1v,
  const float* __restrict__ W2v, const float* __restrict__ b2v,
  const float* __restrict__ QP, const float* __restrict__ SP,
  float* __restrict__ logit, unsigned* __restrict__ rec)
{
  int e = blockIdx.x*256 + threadIdx.x;
  if(e>=EE) return;
  int src=esrc[e], dst=edst[e];
  float yx,yy,yz, basis[16];
  edge_geom(pos,src,dst,yx,yy,yz,basis);
  float rk[5], rv[5];
  radial_mlp(W1k,b1k,W2k,b2k,basis,rk);
  radial_mlp(W1v,b1v,W2v,b2v,basis,rv);

  const float* q = QP + (size_t)dst*80;
  const float* b = SP + (size_t)src*480;

  float lg=0.f;
#pragma unroll
  for(int j=0;j<32;j++){
    float d = yx*b[96+j*3]+yy*b[96+j*3+1]+yz*b[96+j*3+2];
    lg += q[j]*(rk[0]*b[j] + rk[3]*d);
  }
#pragma unroll
  for(int w=0;w<16;w++){
    float ax=b[192+w*3],ay=b[192+w*3+1],az=b[192+w*3+2];
    float cx=ay*yz-az*yy, cy=az*yx-ax*yz, cz=ax*yy-ay*yx;   // cross(PKvvv, y)
    float aw=rk[1]*b[32+w];
    float kx=aw*yx + rk[2]*b[48+w*3]   + rk[4]*cx;
    float ky=aw*yy + rk[2]*b[48+w*3+1] + rk[4]*cy;
    float kz=aw*yz + rk[2]*b[48+w*3+2] + rk[4]*cz;
    lg += q[32+w*3]*kx + q[32+w*3+1]*ky + q[32+w*3+2]*kz;
  }
  lg *= 0.11180339887498948f;   // (S + 3V)^-0.5 = 80^-0.5
  logit[e]=lg;

  float m[80];
#pragma unroll
  for(int j=0;j<32;j++){
    float d = yx*b[336+j*3]+yy*b[336+j*3+1]+yz*b[336+j*3+2];
    m[j] = rv[0]*b[240+j] + rv[3]*d;
  }
#pragma unroll
  for(int w=0;w<16;w++){
    float ax=b[432+w*3],ay=b[432+w*3+1],az=b[432+w*3+2];
    float cx=ay*yz-az*yy, cy=az*yx-ax*yz, cz=ax*yy-ay*yx;   // cross(PVvvv, y)
    float aw=rv[1]*b[272+w];
    m[32+w*3]   = aw*yx + rv[2]*b[288+w*3]   + rv[4]*cx;
    m[32+w*3+1] = aw*yy + rv[2]*b[288+w*3+1] + rv[4]*cy;
    m[32+w*3+2] = aw*yz + rv[2]*b[288+w*3+2] + rv[4]*cz;
  }
  // pack 80 comps -> 40 u32 (bf16 pairs), 10 x 16B stores
  uint4* rp = reinterpret_cast<uint4*>(rec + (size_t)e*40);
#pragma unroll
  for(int k=0;k<10;k++){
    uint4 u;
    u.x = pk2(m[8*k+0], m[8*k+1]);
    u.y = pk2(m[8*k+2], m[8*k+3]);
    u.z = pk2(m[8*k+4], m[8*k+5]);
    u.w = pk2(m[8*k+6], m[8*k+7]);
    rp[k] = u;
  }
}

// ---------- gather: wave-per-node online softmax + residual update ----------
__global__ __launch_bounds__(256) void k_gather(
  const int* __restrict__ rowptr, const int* __restrict__ eid,
  const float* __restrict__ logit, const unsigned* __restrict__ rec,
  float* __restrict__ s, float* __restrict__ v)
{
  int wid = threadIdx.x>>6, lane = threadIdx.x&63;
  int n = blockIdx.x*4 + wid;
  if(n>=NN) return;
  int i0=rowptr[n], i1=rowptr[n+1];
  bool act = lane<40;
  float mx=-3.4e38f, z=0.f, aX=0.f, aY=0.f;

  int i=i0;
  for(; i+1<i1; i+=2){
    int e0=eid[i], e1=eid[i+1];
    float lg0=logit[e0], lg1=logit[e1];
    unsigned c0 = act ? rec[(size_t)e0*40+lane] : 0u;
    unsigned c1 = act ? rec[(size_t)e1*40+lane] : 0u;
    { float nm=fmaxf(mx,lg0); float sc=__expf(mx-nm); float a=__expf(lg0-nm);
      z=z*sc+a; aX=aX*sc+a*bf2f(c0&0xffffu); aY=aY*sc+a*bf2f(c0>>16); mx=nm; }
    { float nm=fmaxf(mx,lg1); float sc=__expf(mx-nm); float a=__expf(lg1-nm);
      z=z*sc+a; aX=aX*sc+a*bf2f(c1&0xffffu); aY=aY*sc+a*bf2f(c1>>16); mx=nm; }
  }
  if(i<i1){
    int e0=eid[i];
    float lg0=logit[e0];
    unsigned c0 = act ? rec[(size_t)e0*40+lane] : 0u;
    float nm=fmaxf(mx,lg0); float sc=__expf(mx-nm); float a=__expf(lg0-nm);
    z=z*sc+a; aX=aX*sc+a*bf2f(c0&0xffffu); aY=aY*sc+a*bf2f(c0>>16); mx=nm;
  }

  float zi = 1.f/(z+1e-9f);
  int c = lane*2;
  if(lane<16){
    float2* spp = reinterpret_cast<float2*>(s + (size_t)n*32 + c);
    float2 t = *spp; t.x += aX*zi; t.y += aY*zi; *spp = t;
  } else if(lane<40){
    float2* vpp = reinterpret_cast<float2*>(v + (size_t)n*48 + (c-32));
    float2 t = *vpp; t.x += aX*zi; t.y += aY*zi; *vpp = t;
  }
}

// ---------- readout: FullyConnectedTensorProduct (f32 output) ----------
__global__ __launch_bounds__(256) void k_readout(
  const float* __restrict__ s, const float* __restrict__ v,
  const float* __restrict__ Wsss, const float* __restrict__ Wvvs,
  const float* __restrict__ Wsvv, const float* __restrict__ Wvsv, const float* __restrict__ Wvvv,
  float* __restrict__ out)
{
  int n = blockIdx.x*256 + threadIdx.x;
  if(n>=NN) return;
  float sn[32], vn[48];
  const float4* sp=reinterpret_cast<const float4*>(s+(size_t)n*32);
#pragma unroll
  for(int i=0;i<8;i++){ float4 t=sp[i]; sn[4*i]=t.x; sn[4*i+1]=t.y; sn[4*i+2]=t.z; sn[4*i+3]=t.w; }
  const float4* vp=reinterpret_cast<const float4*>(v+(size_t)n*48);
#pragma unroll
  for(int i=0;i<12;i++){ float4 t=vp[i]; vn[4*i]=t.x; vn[4*i+1]=t.y; vn[4*i+2]=t.z; vn[4*i+3]=t.w; }

  float os[16];
#pragma unroll
  for(int o=0;o<16;o++) os[o]=0.f;
  for(int a=0;a<32;a++){
    float sa=sn[a];
    for(int t=0;t<32;t++){
      float st=sa*sn[t];
      const float* w=Wsss+((size_t)a*32+t)*16;
#pragma unroll
      for(int o=0;o<16;o++) os[o]+=st*w[o];
    }
  }
  for(int a=0;a<16;a++){
    float ax=vn[a*3],ay=vn[a*3+1],az=vn[a*3+2];
    for(int b=0;b<16;b++){
      float d=ax*vn[b*3]+ay*vn[b*3+1]+az*vn[b*3+2];
      const float* w=Wvvs+((size_t)a*16+b)*16;
#pragma unroll
      for(int o=0;o<16;o++) os[o]+=d*w[o];
    }
  }
  float ov[24];
#pragma unroll
  for(int t=0;t<24;t++) ov[t]=0.f;
  for(int w=0;w<16;w++){
    float B[8];
#pragma unroll
    for(int o=0;o<8;o++) B[o]=0.f;
    for(int a=0;a<32;a++){
      const float* ww=Wsvv+((size_t)a*16+w)*8;
      float sa=sn[a];
#pragma unroll
      for(int o=0;o<8;o++) B[o]+=sa*ww[o];
    }
#pragma unroll
    for(int o=0;o<8;o++){ float b=B[o]; ov[o*3]+=b*vn[w*3]; ov[o*3+1]+=b*vn[w*3+1]; ov[o*3+2]+=b*vn[w*3+2]; }
  }
  for(int vv=0;vv<16;vv++){
    float B[8];
#pragma unroll
    for(int o=0;o<8;o++) B[o]=0.f;
    for(int a=0;a<32;a++){
      const float* ww=Wvsv+((size_t)vv*32+a)*8;
      float sa=sn[a];
#pragma unroll
      for(int o=0;o<8;o++) B[o]+=sa*ww[o];
    }
#pragma unroll
    for(int o=0;o<8;o++){ float b=B[o]; ov[o*3]+=b*vn[vv*3]; ov[o*3+1]+=b*vn[vv*3+1]; ov[o*3+2]+=b*vn[vv*3+2]; }
  }
  for(int a=0;a<16;a++){
    float ax=vn[a*3],ay=vn[a*3+1],az=vn[a*3+2];
    for(int b=0;b<16;b++){
      float bx=vn[b*3],by=vn[b*3+1],bz=vn[b*3+2];
      float cx=ay*bz-az*by, cy=az*bx-ax*bz, cz=ax*by-ay*bx;
      const float* w=Wvvv+((size_t)a*16+b)*8;
#pragma unroll
      for(int o=0;o<8;o++){ float wv=w[o]; ov[o*3]+=cx*wv; ov[o*3+1]+=cy*wv; ov[o*3+2]+=cz*wv; }
    }
  }
  float* op = out + (size_t)n*40;
#pragma unroll
  for(int o=0;o<16;o++) op[o]=os[o];
#pragma unroll
  for(int t=0;t<24;t++) op[16+t]=ov[t];
}

// ---------- launch ----------
extern "C" void kernel_launch(void* const* d_in, const int* in_sizes, int n_in,
                              void* d_out, int out_size, void* d_ws, size_t ws_size,
                              hipStream_t stream) {
  const float* f      = (const float*)d_in[0];
  const float* pos    = (const float*)d_in[1];
  const float* W_in   = (const float*)d_in[2];
  const float* Wq_s   = (const float*)d_in[3];
  const float* Wq_v   = (const float*)d_in[4];
  const float* Wk_ss  = (const float*)d_in[5];
  const float* Wk_sv  = (const float*)d_in[6];
  const float* Wk_vs  = (const float*)d_in[7];
  const float* Wk_vvs = (const float*)d_in[8];
  const float* Wk_vvv = (const float*)d_in[9];
  const float* W1k    = (const float*)d_in[10];
  const float* b1k    = (const float*)d_in[11];
  const float* W2k    = (const float*)d_in[12];
  const float* b2k    = (const float*)d_in[13];
  const float* Wv_ss  = (const float*)d_in[14];
  const float* Wv_sv  = (const float*)d_in[15];
  const float* Wv_vs  = (const float*)d_in[16];
  const float* Wv_vvs = (const float*)d_in[17];
  const float* Wv_vvv = (const float*)d_in[18];
  const float* W1v    = (const float*)d_in[19];
  const float* b1v    = (const float*)d_in[20];
  const float* W2v    = (const float*)d_in[21];
  const float* b2v    = (const float*)d_in[22];
  const float* Wr_sss = (const float*)d_in[23];
  const float* Wr_vvs = (const float*)d_in[24];
  const float* Wr_svv = (const float*)d_in[25];
  const float* Wr_vsv = (const float*)d_in[26];
  const float* Wr_vvv = (const float*)d_in[27];
  const int* esrc     = (const int*)d_in[28];
  const int* edst     = (const int*)d_in[29];

  float* w = (float*)d_ws;
  size_t off=0;
  auto take=[&](size_t ne){ float* p=w+off; off+=ne; return p; };
  float* s      = take((size_t)NN*32);
  float* v      = take((size_t)NN*48);
  float* QP     = take((size_t)NN*80);
  float* SP     = take((size_t)NN*480);
  float* logit  = take((size_t)EE);
  unsigned* rec = (unsigned*)take((size_t)EE*40);
  int* deg      = (int*)take((size_t)NN);
  int* cursor   = (int*)take((size_t)NN);
  int* rowptr   = (int*)take((size_t)NN+1);
  int* eid      = (int*)take((size_t)EE);

  const int NB_N = (NN+255)/256;
  const int NB_E = (EE+255)/256;

  // CSR build (edge->dst), once per call
  hipMemsetAsync(deg,    0, (size_t)NN*sizeof(int), stream);
  hipMemsetAsync(cursor, 0, (size_t)NN*sizeof(int), stream);
  k_hist<<<NB_E,256,0,stream>>>(edst, deg);
  k_scan<<<1,1024,0,stream>>>(deg, rowptr);
  k_fill<<<NB_E,256,0,stream>>>(edst, rowptr, cursor, eid);

  hipMemsetAsync(v, 0, (size_t)NN*48*sizeof(float), stream);
  k_sinit<<<NB_N,256,0,stream>>>(f, W_in, s);

  for(int l=0;l<2;l++){
    k_nodeprep<<<NB_N,256,0,stream>>>(s, v,
      Wq_s+l*1024, Wq_v+l*256,
      Wk_ss+l*1024, Wk_sv+l*512, Wk_vs+l*256, Wk_vvs+l*512, Wk_vvv+l*256,
      Wv_ss+l*1024, Wv_sv+l*512, Wv_vs+l*256, Wv_vvs+l*512, Wv_vvv+l*256,
      QP, SP);
    k_edge<<<NB_E,256,0,stream>>>(pos, esrc, edst,
      W1k+l*1024, b1k+l*64, W2k+l*320, b2k+l*5,
      W1v+l*1024, b1v+l*64, W2v+l*320, b2v+l*5,
      QP, SP, logit, rec);
    k_gather<<<(NN+3)/4,256,0,stream>>>(rowptr, eid, logit, rec, s, v);
  }

  k_readout<<<NB_N,256,0,stream>>>(s, v, Wr_sss, Wr_vvs, Wr_svv, Wr_vsv, Wr_vvv,
                                   (float*)d_out);
}

// Round 6
// 2729.306 us; speedup vs baseline: 3.0222x; 1.0727x over previous
//
#include <hip/hip_runtime.h>

#define NN 50000
#define EE 800000

// ---------- bf16 helpers (RNE) ----------
__device__ __forceinline__ unsigned f2bf(float f){
  unsigned u = __float_as_uint(f);
  return (u + 0x7fffu + ((u>>16)&1u)) >> 16;
}
__device__ __forceinline__ float bf2f(unsigned hs){ return __uint_as_float(hs<<16); }
__device__ __forceinline__ unsigned pk2(float a, float b){ return f2bf(a) | (f2bf(b)<<16); }
// extract bf16 comp c from packed u32 array at u32-base
__device__ __forceinline__ float gx(const unsigned* __restrict__ B, int base, int c){
  unsigned u = B[base + (c>>1)];
  return bf2f((c&1)? (u>>16) : (u&0xffffu));
}
__device__ __forceinline__ float gq(const unsigned* __restrict__ Q, int c){
  unsigned u = Q[4 + (c>>1)];
  return bf2f((c&1)? (u>>16) : (u&0xffffu));
}

// radial MLP: basis[16] -> silu(64) -> 5 path weights (uniform weights -> s_loads)
__device__ __forceinline__ void radial_mlp(const float* __restrict__ W1,
                                           const float* __restrict__ b1,
                                           const float* __restrict__ W2,
                                           const float* __restrict__ b2,
                                           const float* basis, float* rk){
#pragma unroll
  for(int p=0;p<5;p++) rk[p]=b2[p];
  for(int h=0;h<64;h++){
    float t=b1[h];
#pragma unroll
    for(int b=0;b<16;b++) t += basis[b]*W1[b*64+h];
    float sg = t/(1.f+__expf(-t));
#pragma unroll
    for(int p=0;p<5;p++) rk[p]+=sg*W2[h*5+p];
  }
}

// ---------- CSR build ----------
__global__ __launch_bounds__(256) void k_hist(const int* __restrict__ esrc, const int* __restrict__ edst,
                                              int* __restrict__ deg_s, int* __restrict__ deg_d){
  int e = blockIdx.x*256 + threadIdx.x;
  if(e<EE){ atomicAdd(&deg_s[esrc[e]],1); atomicAdd(&deg_d[edst[e]],1); }
}

// exclusive scan of deg[0..NN) -> rowptr[0..NN], few-sync version
__global__ __launch_bounds__(1024) void k_scan(const int* __restrict__ deg, int* __restrict__ rowptr){
  __shared__ int wsum[16];
  const int C = (NN + 1023)/1024;
  int t = threadIdx.x, lane = t&63, wid = t>>6;
  int lo = t*C, hi = lo+C; if(lo>NN) lo=NN; if(hi>NN) hi=NN;
  int loc = 0;
  for(int i=lo;i<hi;i++) loc += deg[i];
  int x = loc;
#pragma unroll
  for(int off=1; off<64; off<<=1){ int y = __shfl_up(x, off); if(lane>=off) x += y; }
  if(lane==63) wsum[wid] = x;
  __syncthreads();
  if(wid==0 && lane<16){
    int w = wsum[lane];
#pragma unroll
    for(int off=1; off<16; off<<=1){ int y = __shfl_up(w, off); if(lane>=off) w += y; }
    wsum[lane]=w;
  }
  __syncthreads();
  int base = (wid>0? wsum[wid-1]:0) + (x - loc);
  int run = base;
  for(int i=lo;i<hi;i++){ rowptr[i] = run; run += deg[i]; }
  if(t==1023) rowptr[NN] = run;
}

// place edges in src-sorted order; write packed src/dst arrays at sorted pos
__global__ __launch_bounds__(256) void k_fill_src(const int* __restrict__ esrc, const int* __restrict__ edst,
                                                  const int* __restrict__ rp_s, int* __restrict__ cur_s,
                                                  int* __restrict__ esrc_s, int* __restrict__ edst_s){
  int e = blockIdx.x*256 + threadIdx.x;
  if(e>=EE) return;
  int s = esrc[e], d = edst[e];
  int q = rp_s[s] + atomicAdd(&cur_s[s],1);
  esrc_s[q]=s; edst_s[q]=d;
}
// dst-CSR whose entries are sorted positions q
__global__ __launch_bounds__(256) void k_fill_dst(const int* __restrict__ edst_s,
                                                  const int* __restrict__ rp_d, int* __restrict__ cur_d,
                                                  int* __restrict__ eidq){
  int q = blockIdx.x*256 + threadIdx.x;
  if(q>=EE) return;
  int d = edst_s[q];
  int p = rp_d[d] + atomicAdd(&cur_d[d],1);
  eidq[p] = q;
}

// ---------- s = f @ W_in ----------
__global__ __launch_bounds__(256) void k_sinit(const float* __restrict__ f,
                                               const float* __restrict__ Win,
                                               float* __restrict__ s){
  int n = blockIdx.x*256 + threadIdx.x;
  if(n>=NN) return;
  float fi[32], acc[32];
  const float4* fp = reinterpret_cast<const float4*>(f + (size_t)n*32);
#pragma unroll
  for(int i=0;i<8;i++){ float4 t=fp[i]; fi[4*i]=t.x; fi[4*i+1]=t.y; fi[4*i+2]=t.z; fi[4*i+3]=t.w; }
#pragma unroll
  for(int j=0;j<32;j++) acc[j]=0.f;
  for(int i=0;i<32;i++){
    float c=fi[i];
#pragma unroll
    for(int j=0;j<32;j++) acc[j]+=c*Win[i*32+j];
  }
  float4* sp = reinterpret_cast<float4*>(s + (size_t)n*32);
#pragma unroll
  for(int i=0;i<8;i++){ float4 t; t.x=acc[4*i]; t.y=acc[4*i+1]; t.z=acc[4*i+2]; t.w=acc[4*i+3]; sp[i]=t; }
}

// ---------- per-node precompute into packed bf16 rows ----------
// QPh row (64 u32, 256B): [0..2]=pos f32 bits, [3]=pad, [4..44)=q 80 comps (qs 0..31, qv 32..79)
// SPh row (256 u32, 1024B): u32 bases: AKss 0, AKsv 16, PKvs 24, PKvvs 48, PKvvv 96,
//                           AVss 120, AVsv 136, PVvs 144, PVvvs 168, PVvvv 216, pos f32 at 240..242
__global__ __launch_bounds__(256) void k_nodeprep(
  const float* __restrict__ s, const float* __restrict__ v, const float* __restrict__ pos,
  const float* __restrict__ Wqs, const float* __restrict__ Wqv,
  const float* __restrict__ Kss, const float* __restrict__ Ksv, const float* __restrict__ Kvs,
  const float* __restrict__ Kvvs, const float* __restrict__ Kvvv,
  const float* __restrict__ Vss, const float* __restrict__ Vsv, const float* __restrict__ Vvs,
  const float* __restrict__ Vvvs, const float* __restrict__ Vvvv,
  unsigned* __restrict__ QPh, unsigned* __restrict__ SPh)
{
  int n = blockIdx.x*256 + threadIdx.x;
  if(n>=NN) return;
  float sn[32], vn[48];
  const float4* sp=reinterpret_cast<const float4*>(s+(size_t)n*32);
#pragma unroll
  for(int i=0;i<8;i++){ float4 t=sp[i]; sn[4*i]=t.x; sn[4*i+1]=t.y; sn[4*i+2]=t.z; sn[4*i+3]=t.w; }
  const float4* vp=reinterpret_cast<const float4*>(v+(size_t)n*48);
#pragma unroll
  for(int i=0;i<12;i++){ float4 t=vp[i]; vn[4*i]=t.x; vn[4*i+1]=t.y; vn[4*i+2]=t.z; vn[4*i+3]=t.w; }

  unsigned* qrow = QPh + (size_t)n*64;
  unsigned* brow = SPh + (size_t)n*256;

#define SMAT32C(W, ARR) { \
  _Pragma("unroll") for(int j=0;j<32;j++) ARR[j]=0.f; \
  for(int i=0;i<32;i++){ float c=sn[i]; \
    _Pragma("unroll") for(int j=0;j<32;j++) ARR[j]+=c*W[i*32+j]; } }
#define SMAT16C(W, ARR) { \
  _Pragma("unroll") for(int j=0;j<16;j++) ARR[j]=0.f; \
  for(int i=0;i<32;i++){ float c=sn[i]; \
    _Pragma("unroll") for(int j=0;j<16;j++) ARR[j]+=c*W[i*16+j]; } }
#define VMAT16C(W, ARR) \
  for(int w=0;w<16;w++){ float ax=0,ay=0,az=0; \
    _Pragma("unroll") for(int t=0;t<16;t++){ float wt=W[t*16+w]; ax+=vn[t*3]*wt; ay+=vn[t*3+1]*wt; az+=vn[t*3+2]*wt; } \
    ARR[w*3]=ax; ARR[w*3+1]=ay; ARR[w*3+2]=az; }
#define VMAT32C(W, ARR) \
  for(int j=0;j<32;j++){ float ax=0,ay=0,az=0; \
    _Pragma("unroll") for(int t=0;t<16;t++){ float wt=W[t*32+j]; ax+=vn[t*3]*wt; ay+=vn[t*3+1]*wt; az+=vn[t*3+2]*wt; } \
    ARR[j*3]=ax; ARR[j*3+1]=ay; ARR[j*3+2]=az; }
#define PACKST(ARR, NCOMP, ROW, BASE) { \
  uint4* dst4 = reinterpret_cast<uint4*>((ROW) + (BASE)); \
  _Pragma("unroll") for(int k=0;k<(NCOMP)/8;k++){ \
    uint4 u; u.x=pk2(ARR[8*k],ARR[8*k+1]); u.y=pk2(ARR[8*k+2],ARR[8*k+3]); \
    u.z=pk2(ARR[8*k+4],ARR[8*k+5]); u.w=pk2(ARR[8*k+6],ARR[8*k+7]); dst4[k]=u; } }

  float a32[32], a96[96];
  // QP row
  qrow[0]=__float_as_uint(pos[(size_t)n*3]);
  qrow[1]=__float_as_uint(pos[(size_t)n*3+1]);
  qrow[2]=__float_as_uint(pos[(size_t)n*3+2]);
  qrow[3]=0u;
  SMAT32C(Wqs, a32)  PACKST(a32, 32, qrow, 4)
  { float a48[48]; VMAT16C(Wqv, a48) PACKST(a48, 48, qrow, 20) }
  // SP row, K side
  SMAT32C(Kss, a32)  PACKST(a32, 32, brow, 0)
  { float a16[16]; SMAT16C(Ksv, a16) PACKST(a16, 16, brow, 16) }
  { float a48[48]; VMAT16C(Kvs, a48) PACKST(a48, 48, brow, 24) }
  VMAT32C(Kvvs, a96) PACKST(a96, 96, brow, 48)
  { float a48[48]; VMAT16C(Kvvv, a48) PACKST(a48, 48, brow, 96) }
  // SP row, V side
  SMAT32C(Vss, a32)  PACKST(a32, 32, brow, 120)
  { float a16[16]; SMAT16C(Vsv, a16) PACKST(a16, 16, brow, 136) }
  { float a48[48]; VMAT16C(Vvs, a48) PACKST(a48, 48, brow, 144) }
  VMAT32C(Vvvs, a96) PACKST(a96, 96, brow, 168)
  { float a48[48]; VMAT16C(Vvvv, a48) PACKST(a48, 48, brow, 216) }
  brow[240]=qrow[0]; // src pos only equals this node's pos
  brow[240]=__float_as_uint(pos[(size_t)n*3]);
  brow[241]=__float_as_uint(pos[(size_t)n*3+1]);
  brow[242]=__float_as_uint(pos[(size_t)n*3+2]);
#undef SMAT32C
#undef SMAT16C
#undef VMAT16C
#undef VMAT32C
#undef PACKST
}

// ---------- fused edge pass over src-sorted edges: logit + bf16 message record ----------
// rec row: 48 u32 (192B): [0..40)=80 msg comps bf16, [40]=logit f32 bits
__global__ __launch_bounds__(256) void k_edge(
  const int* __restrict__ esrc_s, const int* __restrict__ edst_s,
  const float* __restrict__ W1k, const float* __restrict__ b1k,
  const float* __restrict__ W2k, const float* __restrict__ b2k,
  const float* __restrict__ W1v, const float* __restrict__ b1v,
  const float* __restrict__ W2v, const float* __restrict__ b2v,
  const unsigned* __restrict__ QPh, const unsigned* __restrict__ SPh,
  unsigned* __restrict__ rec)
{
  int q = blockIdx.x*256 + threadIdx.x;
  if(q>=EE) return;
  int src=esrc_s[q], dst=edst_s[q];
  const unsigned* B = SPh + (size_t)src*256;
  const unsigned* Q = QPh + (size_t)dst*64;
  float px = __uint_as_float(B[240]) - __uint_as_float(Q[0]);
  float py = __uint_as_float(B[241]) - __uint_as_float(Q[1]);
  float pz = __uint_as_float(B[242]) - __uint_as_float(Q[2]);
  float r = sqrtf(px*px+py*py+pz*pz);
  float inv = 1.f/(r+1e-9f);
  float yx=px*inv, yy=py*inv, yz=pz*inv;
  float basis[16];
#pragma unroll
  for(int b=0;b<16;b++){
    float d=(r - (10.f/15.f)*(float)b)*1.6f;
    basis[b]=__expf(-d*d);
  }
  float rk[5], rv[5];
  radial_mlp(W1k,b1k,W2k,b2k,basis,rk);
  radial_mlp(W1v,b1v,W2v,b2v,basis,rv);

  float lg=0.f;
#pragma unroll
  for(int j=0;j<32;j++){
    float d = yx*gx(B,48,3*j)+yy*gx(B,48,3*j+1)+yz*gx(B,48,3*j+2);
    lg += gq(Q,j)*(rk[0]*gx(B,0,j) + rk[3]*d);
  }
#pragma unroll
  for(int w=0;w<16;w++){
    float ax=gx(B,96,3*w),ay=gx(B,96,3*w+1),az=gx(B,96,3*w+2);
    float cx=ay*yz-az*yy, cy=az*yx-ax*yz, cz=ax*yy-ay*yx;   // cross(PKvvv, y)
    float aw=rk[1]*gx(B,16,w);
    float kx=aw*yx + rk[2]*gx(B,24,3*w)   + rk[4]*cx;
    float ky=aw*yy + rk[2]*gx(B,24,3*w+1) + rk[4]*cy;
    float kz=aw*yz + rk[2]*gx(B,24,3*w+2) + rk[4]*cz;
    lg += gq(Q,32+3*w)*kx + gq(Q,32+3*w+1)*ky + gq(Q,32+3*w+2)*kz;
  }
  lg *= 0.11180339887498948f;   // (S+3V)^-0.5 = 80^-0.5

  unsigned rbuf[40];
#pragma unroll
  for(int j2=0;j2<16;j2++){
    int j=2*j2;
    float d0 = yx*gx(B,168,3*j)  +yy*gx(B,168,3*j+1)+yz*gx(B,168,3*j+2);
    float d1 = yx*gx(B,168,3*j+3)+yy*gx(B,168,3*j+4)+yz*gx(B,168,3*j+5);
    float m0 = rv[0]*gx(B,120,j)   + rv[3]*d0;
    float m1 = rv[0]*gx(B,120,j+1) + rv[3]*d1;
    rbuf[j2]=pk2(m0,m1);
  }
#pragma unroll
  for(int w2=0;w2<8;w2++){
    float mm[6];
#pragma unroll
    for(int k=0;k<2;k++){
      int ww=2*w2+k;
      float ax=gx(B,216,3*ww),ay=gx(B,216,3*ww+1),az=gx(B,216,3*ww+2);
      float cx=ay*yz-az*yy, cy=az*yx-ax*yz, cz=ax*yy-ay*yx;   // cross(PVvvv, y)
      float aw=rv[1]*gx(B,136,ww);
      mm[3*k+0]=aw*yx + rv[2]*gx(B,144,3*ww)   + rv[4]*cx;
      mm[3*k+1]=aw*yy + rv[2]*gx(B,144,3*ww+1) + rv[4]*cy;
      mm[3*k+2]=aw*yz + rv[2]*gx(B,144,3*ww+2) + rv[4]*cz;
    }
    rbuf[16+3*w2]  =pk2(mm[0],mm[1]);
    rbuf[16+3*w2+1]=pk2(mm[2],mm[3]);
    rbuf[16+3*w2+2]=pk2(mm[4],mm[5]);
  }
  uint4* rp = reinterpret_cast<uint4*>(rec + (size_t)q*48);
#pragma unroll
  for(int k=0;k<10;k++){
    uint4 u; u.x=rbuf[4*k]; u.y=rbuf[4*k+1]; u.z=rbuf[4*k+2]; u.w=rbuf[4*k+3];
    rp[k]=u;
  }
  rec[(size_t)q*48+40] = __float_as_uint(lg);
}

// ---------- gather: wave-per-node, exact chunk max + shfl-broadcast accumulate ----------
__global__ __launch_bounds__(256) void k_gather(
  const int* __restrict__ rp_d, const int* __restrict__ eidq,
  const unsigned* __restrict__ rec,
  float* __restrict__ s, float* __restrict__ v)
{
  int wid = threadIdx.x>>6, lane = threadIdx.x&63;
  int n = blockIdx.x*4 + wid;
  if(n>=NN) return;
  int i0=rp_d[n], i1=rp_d[n+1];
  float mx=-3.4e38f, z=0.f, aX=0.f, aY=0.f;
  for(int base=i0; base<i1; base+=64){
    int cnt = i1-base; if(cnt>64) cnt=64;
    int q = 0; float lg = -3.4e38f;
    if(lane<cnt){ q = eidq[base+lane]; lg = __uint_as_float(rec[(size_t)q*48+40]); }
    float cm = lg;
#pragma unroll
    for(int off=32; off; off>>=1) cm = fmaxf(cm, __shfl_xor(cm, off));
    if(cm > mx){
      float sc = __expf(mx - cm);        // first chunk: exp(-inf)=0, state is 0 anyway
      z*=sc; aX*=sc; aY*=sc; mx=cm;
    }
    float a = (lane<cnt)? __expf(lg - mx) : 0.f;
    for(int i=0;i<cnt;i++){
      float ai = __shfl(a, i);
      int   qi = __shfl(q, i);
      unsigned c = (lane<40)? rec[(size_t)qi*48+lane] : 0u;
      aX += ai*bf2f(c&0xffffu);
      aY += ai*bf2f(c>>16);
      z  += ai;
    }
  }
  float zi = 1.f/(z+1e-9f);
  int c = lane*2;
  if(lane<16){
    float2* spp = reinterpret_cast<float2*>(s + (size_t)n*32 + c);
    float2 t = *spp; t.x += aX*zi; t.y += aY*zi; *spp = t;
  } else if(lane<40){
    float2* vpp = reinterpret_cast<float2*>(v + (size_t)n*48 + (c-32));
    float2 t = *vpp; t.x += aX*zi; t.y += aY*zi; *vpp = t;
  }
}

// ---------- readout: FullyConnectedTensorProduct (f32 output) ----------
__global__ __launch_bounds__(256) void k_readout(
  const float* __restrict__ s, const float* __restrict__ v,
  const float* __restrict__ Wsss, const float* __restrict__ Wvvs,
  const float* __restrict__ Wsvv, const float* __restrict__ Wvsv, const float* __restrict__ Wvvv,
  float* __restrict__ out)
{
  int n = blockIdx.x*256 + threadIdx.x;
  if(n>=NN) return;
  float sn[32], vn[48];
  const float4* sp=reinterpret_cast<const float4*>(s+(size_t)n*32);
#pragma unroll
  for(int i=0;i<8;i++){ float4 t=sp[i]; sn[4*i]=t.x; sn[4*i+1]=t.y; sn[4*i+2]=t.z; sn[4*i+3]=t.w; }
  const float4* vp=reinterpret_cast<const float4*>(v+(size_t)n*48);
#pragma unroll
  for(int i=0;i<12;i++){ float4 t=vp[i]; vn[4*i]=t.x; vn[4*i+1]=t.y; vn[4*i+2]=t.z; vn[4*i+3]=t.w; }

  float os[16];
#pragma unroll
  for(int o=0;o<16;o++) os[o]=0.f;
  for(int a=0;a<32;a++){
    float sa=sn[a];
    for(int t=0;t<32;t++){
      float st=sa*sn[t];
      const float* w=Wsss+((size_t)a*32+t)*16;
#pragma unroll
      for(int o=0;o<16;o++) os[o]+=st*w[o];
    }
  }
  for(int a=0;a<16;a++){
    float ax=vn[a*3],ay=vn[a*3+1],az=vn[a*3+2];
    for(int b=0;b<16;b++){
      float d=ax*vn[b*3]+ay*vn[b*3+1]+az*vn[b*3+2];
      const float* w=Wvvs+((size_t)a*16+b)*16;
#pragma unroll
      for(int o=0;o<16;o++) os[o]+=d*w[o];
    }
  }
  float ov[24];
#pragma unroll
  for(int t=0;t<24;t++) ov[t]=0.f;
  for(int w=0;w<16;w++){
    float B[8];
#pragma unroll
    for(int o=0;o<8;o++) B[o]=0.f;
    for(int a=0;a<32;a++){
      const float* ww=Wsvv+((size_t)a*16+w)*8;
      float sa=sn[a];
#pragma unroll
      for(int o=0;o<8;o++) B[o]+=sa*ww[o];
    }
#pragma unroll
    for(int o=0;o<8;o++){ float b=B[o]; ov[o*3]+=b*vn[w*3]; ov[o*3+1]+=b*vn[w*3+1]; ov[o*3+2]+=b*vn[w*3+2]; }
  }
  for(int vv=0;vv<16;vv++){
    float B[8];
#pragma unroll
    for(int o=0;o<8;o++) B[o]=0.f;
    for(int a=0;a<32;a++){
      const float* ww=Wvsv+((size_t)vv*32+a)*8;
      float sa=sn[a];
#pragma unroll
      for(int o=0;o<8;o++) B[o]+=sa*ww[o];
    }
#pragma unroll
    for(int o=0;o<8;o++){ float b=B[o]; ov[o*3]+=b*vn[vv*3]; ov[o*3+1]+=b*vn[vv*3+1]; ov[o*3+2]+=b*vn[vv*3+2]; }
  }
  for(int a=0;a<16;a++){
    float ax=vn[a*3],ay=vn[a*3+1],az=vn[a*3+2];
    for(int b=0;b<16;b++){
      float bx=vn[b*3],by=vn[b*3+1],bz=vn[b*3+2];
      float cx=ay*bz-az*by, cy=az*bx-ax*bz, cz=ax*by-ay*bx;
      const float* w=Wvvv+((size_t)a*16+b)*8;
#pragma unroll
      for(int o=0;o<8;o++){ float wv=w[o]; ov[o*3]+=cx*wv; ov[o*3+1]+=cy*wv; ov[o*3+2]+=cz*wv; }
    }
  }
  float* op = out + (size_t)n*40;
#pragma unroll
  for(int o=0;o<16;o++) op[o]=os[o];
#pragma unroll
  for(int t=0;t<24;t++) op[16+t]=ov[t];
}

// ---------- launch ----------
extern "C" void kernel_launch(void* const* d_in, const int* in_sizes, int n_in,
                              void* d_out, int out_size, void* d_ws, size_t ws_size,
                              hipStream_t stream) {
  const float* f      = (const float*)d_in[0];
  const float* pos    = (const float*)d_in[1];
  const float* W_in   = (const float*)d_in[2];
  const float* Wq_s   = (const float*)d_in[3];
  const float* Wq_v   = (const float*)d_in[4];
  const float* Wk_ss  = (const float*)d_in[5];
  const float* Wk_sv  = (const float*)d_in[6];
  const float* Wk_vs  = (const float*)d_in[7];
  const float* Wk_vvs = (const float*)d_in[8];
  const float* Wk_vvv = (const float*)d_in[9];
  const float* W1k    = (const float*)d_in[10];
  const float* b1k    = (const float*)d_in[11];
  const float* W2k    = (const float*)d_in[12];
  const float* b2k    = (const float*)d_in[13];
  const float* Wv_ss  = (const float*)d_in[14];
  const float* Wv_sv  = (const float*)d_in[15];
  const float* Wv_vs  = (const float*)d_in[16];
  const float* Wv_vvs = (const float*)d_in[17];
  const float* Wv_vvv = (const float*)d_in[18];
  const float* W1v    = (const float*)d_in[19];
  const float* b1v    = (const float*)d_in[20];
  const float* W2v    = (const float*)d_in[21];
  const float* b2v    = (const float*)d_in[22];
  const float* Wr_sss = (const float*)d_in[23];
  const float* Wr_vvs = (const float*)d_in[24];
  const float* Wr_svv = (const float*)d_in[25];
  const float* Wr_vsv = (const float*)d_in[26];
  const float* Wr_vvv = (const float*)d_in[27];
  const int* esrc     = (const int*)d_in[28];
  const int* edst     = (const int*)d_in[29];

  char* w = (char*)d_ws;
  size_t off=0;
  auto takeB=[&](size_t bytes){ char* p=w+off; off+=(bytes+255)&~(size_t)255; return p; };
  float*    s      = (float*)   takeB((size_t)NN*32*4);
  float*    v      = (float*)   takeB((size_t)NN*48*4);
  unsigned* QPh    = (unsigned*)takeB((size_t)NN*64*4);
  unsigned* SPh    = (unsigned*)takeB((size_t)NN*256*4);
  unsigned* rec    = (unsigned*)takeB((size_t)EE*48*4);
  int*      esrc_s = (int*)     takeB((size_t)EE*4);
  int*      edst_s = (int*)     takeB((size_t)EE*4);
  int*      eidq   = (int*)     takeB((size_t)EE*4);
  int*      degs   = (int*)     takeB((size_t)NN*4*4);   // deg_s, cur_s, deg_d, cur_d contiguous
  int*      rp_s   = (int*)     takeB((size_t)(NN+1)*4);
  int*      rp_d   = (int*)     takeB((size_t)(NN+1)*4);
  int* deg_s=degs, *cur_s=degs+NN, *deg_d=degs+2*NN, *cur_d=degs+3*NN;

  const int NB_N = (NN+255)/256;
  const int NB_E = (EE+255)/256;

  // CSR build (src-sorted order + dst-CSR over sorted positions), once per call
  hipMemsetAsync(degs, 0, (size_t)NN*4*4, stream);
  k_hist<<<NB_E,256,0,stream>>>(esrc, edst, deg_s, deg_d);
  k_scan<<<1,1024,0,stream>>>(deg_s, rp_s);
  k_scan<<<1,1024,0,stream>>>(deg_d, rp_d);
  k_fill_src<<<NB_E,256,0,stream>>>(esrc, edst, rp_s, cur_s, esrc_s, edst_s);
  k_fill_dst<<<NB_E,256,0,stream>>>(edst_s, rp_d, cur_d, eidq);

  hipMemsetAsync(v, 0, (size_t)NN*48*4, stream);
  k_sinit<<<NB_N,256,0,stream>>>(f, W_in, s);

  for(int l=0;l<2;l++){
    k_nodeprep<<<NB_N,256,0,stream>>>(s, v, pos,
      Wq_s+l*1024, Wq_v+l*256,
      Wk_ss+l*1024, Wk_sv+l*512, Wk_vs+l*256, Wk_vvs+l*512, Wk_vvv+l*256,
      Wv_ss+l*1024, Wv_sv+l*512, Wv_vs+l*256, Wv_vvs+l*512, Wv_vvv+l*256,
      QPh, SPh);
    k_edge<<<NB_E,256,0,stream>>>(esrc_s, edst_s,
      W1k+l*1024, b1k+l*64, W2k+l*320, b2k+l*5,
      W1v+l*1024, b1v+l*64, W2v+l*320, b2v+l*5,
      QPh, SPh, rec);
    k_gather<<<(NN+3)/4,256,0,stream>>>(rp_d, eidq, rec, s, v);
  }

  k_readout<<<NB_N,256,0,stream>>>(s, v, Wr_sss, Wr_vvs, Wr_svv, Wr_vsv, Wr_vvv,
                                   (float*)d_out);
}

// Round 7
// 2148.679 us; speedup vs baseline: 3.8389x; 1.2702x over previous
//
#include <hip/hip_runtime.h>

#define NN 50000
#define EE 800000
#define NBIN 8192
#define RMAXT 17.33f

// ---------- bf16 helpers (RNE) ----------
__device__ __forceinline__ unsigned f2bf(float f){
  unsigned u = __float_as_uint(f);
  return (u + 0x7fffu + ((u>>16)&1u)) >> 16;
}
__device__ __forceinline__ float bf2f(unsigned hs){ return __uint_as_float(hs<<16); }
__device__ __forceinline__ unsigned pk2(float a, float b){ return f2bf(a) | (f2bf(b)<<16); }
__device__ __forceinline__ float gx(const unsigned* __restrict__ B, int base, int c){
  unsigned u = B[base + (c>>1)];
  return bf2f((c&1)? (u>>16) : (u&0xffffu));
}
__device__ __forceinline__ float gq(const unsigned* __restrict__ Q, int c){
  unsigned u = Q[4 + (c>>1)];
  return bf2f((c&1)? (u>>16) : (u&0xffffu));
}

// radial MLP (exact) — used only by the LUT builder now
__device__ __forceinline__ void radial_mlp(const float* __restrict__ W1,
                                           const float* __restrict__ b1,
                                           const float* __restrict__ W2,
                                           const float* __restrict__ b2,
                                           const float* basis, float* rk){
#pragma unroll
  for(int p=0;p<5;p++) rk[p]=b2[p];
  for(int h=0;h<64;h++){
    float t=b1[h];
#pragma unroll
    for(int b=0;b<16;b++) t += basis[b]*W1[b*64+h];
    float sg = t/(1.f+__expf(-t));
#pragma unroll
    for(int p=0;p<5;p++) rk[p]+=sg*W2[h*5+p];
  }
}

// ---------- radial LUT: RT[layer][bin][16] = [rk0..4, rv0..4, pad6] ----------
__global__ __launch_bounds__(256) void k_lut(
  const float* __restrict__ W1k, const float* __restrict__ b1k,
  const float* __restrict__ W2k, const float* __restrict__ b2k,
  const float* __restrict__ W1v, const float* __restrict__ b1v,
  const float* __restrict__ W2v, const float* __restrict__ b2v,
  float* __restrict__ RT)
{
  int idx = blockIdx.x*256 + threadIdx.x;
  if(idx >= 2*NBIN) return;
  int l = idx / NBIN, bin = idx % NBIN;
  float r = (float)bin * (RMAXT/(float)(NBIN-1));
  float basis[16];
#pragma unroll
  for(int b=0;b<16;b++){
    float d=(r - (10.f/15.f)*(float)b)*1.6f;
    basis[b]=__expf(-d*d);
  }
  float rk[5], rv[5];
  radial_mlp(W1k+l*1024, b1k+l*64, W2k+l*320, b2k+l*5, basis, rk);
  radial_mlp(W1v+l*1024, b1v+l*64, W2v+l*320, b2v+l*5, basis, rv);
  float* row = RT + ((size_t)l*NBIN + bin)*16;
#pragma unroll
  for(int p=0;p<5;p++) row[p]=rk[p];
#pragma unroll
  for(int p=0;p<5;p++) row[5+p]=rv[p];
  row[10]=0.f; row[11]=0.f;
}

// ---------- CSR build ----------
__global__ __launch_bounds__(256) void k_hist(const int* __restrict__ esrc, const int* __restrict__ edst,
                                              int* __restrict__ deg_s, int* __restrict__ deg_d){
  int e = blockIdx.x*256 + threadIdx.x;
  if(e<EE){ atomicAdd(&deg_s[esrc[e]],1); atomicAdd(&deg_d[edst[e]],1); }
}

__global__ __launch_bounds__(1024) void k_scan(const int* __restrict__ deg, int* __restrict__ rowptr){
  __shared__ int wsum[16];
  const int C = (NN + 1023)/1024;
  int t = threadIdx.x, lane = t&63, wid = t>>6;
  int lo = t*C, hi = lo+C; if(lo>NN) lo=NN; if(hi>NN) hi=NN;
  int loc = 0;
  for(int i=lo;i<hi;i++) loc += deg[i];
  int x = loc;
#pragma unroll
  for(int off=1; off<64; off<<=1){ int y = __shfl_up(x, off); if(lane>=off) x += y; }
  if(lane==63) wsum[wid] = x;
  __syncthreads();
  if(wid==0 && lane<16){
    int w = wsum[lane];
#pragma unroll
    for(int off=1; off<16; off<<=1){ int y = __shfl_up(w, off); if(lane>=off) w += y; }
    wsum[lane]=w;
  }
  __syncthreads();
  int base = (wid>0? wsum[wid-1]:0) + (x - loc);
  int run = base;
  for(int i=lo;i<hi;i++){ rowptr[i] = run; run += deg[i]; }
  if(t==1023) rowptr[NN] = run;
}

__global__ __launch_bounds__(256) void k_fill_src(const int* __restrict__ esrc, const int* __restrict__ edst,
                                                  const int* __restrict__ rp_s, int* __restrict__ cur_s,
                                                  int* __restrict__ esrc_s, int* __restrict__ edst_s){
  int e = blockIdx.x*256 + threadIdx.x;
  if(e>=EE) return;
  int s = esrc[e], d = edst[e];
  int q = rp_s[s] + atomicAdd(&cur_s[s],1);
  esrc_s[q]=s; edst_s[q]=d;
}
__global__ __launch_bounds__(256) void k_fill_dst(const int* __restrict__ edst_s,
                                                  const int* __restrict__ rp_d, int* __restrict__ cur_d,
                                                  int* __restrict__ eidq){
  int q = blockIdx.x*256 + threadIdx.x;
  if(q>=EE) return;
  int d = edst_s[q];
  int p = rp_d[d] + atomicAdd(&cur_d[d],1);
  eidq[p] = q;
}

// ---------- s = f @ W_in ----------
__global__ __launch_bounds__(256) void k_sinit(const float* __restrict__ f,
                                               const float* __restrict__ Win,
                                               float* __restrict__ s){
  int n = blockIdx.x*256 + threadIdx.x;
  if(n>=NN) return;
  float fi[32], acc[32];
  const float4* fp = reinterpret_cast<const float4*>(f + (size_t)n*32);
#pragma unroll
  for(int i=0;i<8;i++){ float4 t=fp[i]; fi[4*i]=t.x; fi[4*i+1]=t.y; fi[4*i+2]=t.z; fi[4*i+3]=t.w; }
#pragma unroll
  for(int j=0;j<32;j++) acc[j]=0.f;
  for(int i=0;i<32;i++){
    float c=fi[i];
#pragma unroll
    for(int j=0;j<32;j++) acc[j]+=c*Win[i*32+j];
  }
  float4* sp = reinterpret_cast<float4*>(s + (size_t)n*32);
#pragma unroll
  for(int i=0;i<8;i++){ float4 t; t.x=acc[4*i]; t.y=acc[4*i+1]; t.z=acc[4*i+2]; t.w=acc[4*i+3]; sp[i]=t; }
}

// ---------- per-node precompute into packed bf16 rows ----------
// QPh row (64 u32): [0..2]=pos f32, [3]=pad, [4..44)=80 q comps
// SPh row (256 u32): AKss 0, AKsv 16, PKvs 24, PKvvs 48, PKvvv 96,
//                    AVss 120, AVsv 136, PVvs 144, PVvvs 168, PVvvv 216, pos 240..242
__global__ __launch_bounds__(256) void k_nodeprep(
  const float* __restrict__ s, const float* __restrict__ v, const float* __restrict__ pos,
  const float* __restrict__ Wqs, const float* __restrict__ Wqv,
  const float* __restrict__ Kss, const float* __restrict__ Ksv, const float* __restrict__ Kvs,
  const float* __restrict__ Kvvs, const float* __restrict__ Kvvv,
  const float* __restrict__ Vss, const float* __restrict__ Vsv, const float* __restrict__ Vvs,
  const float* __restrict__ Vvvs, const float* __restrict__ Vvvv,
  unsigned* __restrict__ QPh, unsigned* __restrict__ SPh)
{
  int n = blockIdx.x*256 + threadIdx.x;
  if(n>=NN) return;
  float sn[32], vn[48];
  const float4* sp=reinterpret_cast<const float4*>(s+(size_t)n*32);
#pragma unroll
  for(int i=0;i<8;i++){ float4 t=sp[i]; sn[4*i]=t.x; sn[4*i+1]=t.y; sn[4*i+2]=t.z; sn[4*i+3]=t.w; }
  const float4* vp=reinterpret_cast<const float4*>(v+(size_t)n*48);
#pragma unroll
  for(int i=0;i<12;i++){ float4 t=vp[i]; vn[4*i]=t.x; vn[4*i+1]=t.y; vn[4*i+2]=t.z; vn[4*i+3]=t.w; }

  unsigned* qrow = QPh + (size_t)n*64;
  unsigned* brow = SPh + (size_t)n*256;

#define SMAT32C(W, ARR) { \
  _Pragma("unroll") for(int j=0;j<32;j++) ARR[j]=0.f; \
  for(int i=0;i<32;i++){ float c=sn[i]; \
    _Pragma("unroll") for(int j=0;j<32;j++) ARR[j]+=c*W[i*32+j]; } }
#define SMAT16C(W, ARR) { \
  _Pragma("unroll") for(int j=0;j<16;j++) ARR[j]=0.f; \
  for(int i=0;i<32;i++){ float c=sn[i]; \
    _Pragma("unroll") for(int j=0;j<16;j++) ARR[j]+=c*W[i*16+j]; } }
#define VMAT16C(W, ARR) \
  for(int w=0;w<16;w++){ float ax=0,ay=0,az=0; \
    _Pragma("unroll") for(int t=0;t<16;t++){ float wt=W[t*16+w]; ax+=vn[t*3]*wt; ay+=vn[t*3+1]*wt; az+=vn[t*3+2]*wt; } \
    ARR[w*3]=ax; ARR[w*3+1]=ay; ARR[w*3+2]=az; }
#define VMAT32C(W, ARR) \
  for(int j=0;j<32;j++){ float ax=0,ay=0,az=0; \
    _Pragma("unroll") for(int t=0;t<16;t++){ float wt=W[t*32+j]; ax+=vn[t*3]*wt; ay+=vn[t*3+1]*wt; az+=vn[t*3+2]*wt; } \
    ARR[j*3]=ax; ARR[j*3+1]=ay; ARR[j*3+2]=az; }
#define PACKST(ARR, NCOMP, ROW, BASE) { \
  uint4* dst4 = reinterpret_cast<uint4*>((ROW) + (BASE)); \
  _Pragma("unroll") for(int k=0;k<(NCOMP)/8;k++){ \
    uint4 u; u.x=pk2(ARR[8*k],ARR[8*k+1]); u.y=pk2(ARR[8*k+2],ARR[8*k+3]); \
    u.z=pk2(ARR[8*k+4],ARR[8*k+5]); u.w=pk2(ARR[8*k+6],ARR[8*k+7]); dst4[k]=u; } }

  float a32[32], a96[96];
  qrow[0]=__float_as_uint(pos[(size_t)n*3]);
  qrow[1]=__float_as_uint(pos[(size_t)n*3+1]);
  qrow[2]=__float_as_uint(pos[(size_t)n*3+2]);
  qrow[3]=0u;
  SMAT32C(Wqs, a32)  PACKST(a32, 32, qrow, 4)
  { float a48[48]; VMAT16C(Wqv, a48) PACKST(a48, 48, qrow, 20) }
  SMAT32C(Kss, a32)  PACKST(a32, 32, brow, 0)
  { float a16[16]; SMAT16C(Ksv, a16) PACKST(a16, 16, brow, 16) }
  { float a48[48]; VMAT16C(Kvs, a48) PACKST(a48, 48, brow, 24) }
  VMAT32C(Kvvs, a96) PACKST(a96, 96, brow, 48)
  { float a48[48]; VMAT16C(Kvvv, a48) PACKST(a48, 48, brow, 96) }
  SMAT32C(Vss, a32)  PACKST(a32, 32, brow, 120)
  { float a16[16]; SMAT16C(Vsv, a16) PACKST(a16, 16, brow, 136) }
  { float a48[48]; VMAT16C(Vvs, a48) PACKST(a48, 48, brow, 144) }
  VMAT32C(Vvvs, a96) PACKST(a96, 96, brow, 168)
  { float a48[48]; VMAT16C(Vvvv, a48) PACKST(a48, 48, brow, 216) }
  brow[240]=__float_as_uint(pos[(size_t)n*3]);
  brow[241]=__float_as_uint(pos[(size_t)n*3+1]);
  brow[242]=__float_as_uint(pos[(size_t)n*3+2]);
#undef SMAT32C
#undef SMAT16C
#undef VMAT16C
#undef VMAT32C
#undef PACKST
}

// ---------- fused edge pass (src-sorted): LUT radial + logit + bf16 message ----------
// rec row: 40 u32 (160B) = 80 msg comps; logit separate
__global__ __launch_bounds__(256,4) void k_edge(
  const int* __restrict__ esrc_s, const int* __restrict__ edst_s,
  const float* __restrict__ RT,
  const unsigned* __restrict__ QPh, const unsigned* __restrict__ SPh,
  float* __restrict__ logit, unsigned* __restrict__ rec)
{
  int q = blockIdx.x*256 + threadIdx.x;
  if(q>=EE) return;
  int src=esrc_s[q], dst=edst_s[q];
  const unsigned* B = SPh + (size_t)src*256;
  const unsigned* Q = QPh + (size_t)dst*64;
  float px = __uint_as_float(B[240]) - __uint_as_float(Q[0]);
  float py = __uint_as_float(B[241]) - __uint_as_float(Q[1]);
  float pz = __uint_as_float(B[242]) - __uint_as_float(Q[2]);
  float r = sqrtf(px*px+py*py+pz*pz);
  float inv = 1.f/(r+1e-9f);
  float yx=px*inv, yy=py*inv, yz=pz*inv;

  // radial LUT lerp
  float u = r * ((float)(NBIN-1)/RMAXT);
  int i0 = (int)u; if(i0 > NBIN-2) i0 = NBIN-2;
  float fr = u - (float)i0; fr = fminf(fr, 1.f);
  const float4* T0 = reinterpret_cast<const float4*>(RT + (size_t)i0*16);
  const float4* T1 = reinterpret_cast<const float4*>(RT + (size_t)(i0+1)*16);
  float4 A0=T0[0], B0=T0[1], C0=T0[2];
  float4 A1=T1[0], B1=T1[1], C1=T1[2];
  float rk0=A0.x+fr*(A1.x-A0.x), rk1=A0.y+fr*(A1.y-A0.y);
  float rk2=A0.z+fr*(A1.z-A0.z), rk3=A0.w+fr*(A1.w-A0.w);
  float rk4=B0.x+fr*(B1.x-B0.x);
  float rv0=B0.y+fr*(B1.y-B0.y), rv1=B0.z+fr*(B1.z-B0.z);
  float rv2=B0.w+fr*(B1.w-B0.w);
  float rv3=C0.x+fr*(C1.x-C0.x), rv4=C0.y+fr*(C1.y-C0.y);

  float lg=0.f;
#pragma unroll
  for(int j=0;j<32;j++){
    float d = yx*gx(B,48,3*j)+yy*gx(B,48,3*j+1)+yz*gx(B,48,3*j+2);
    lg += gq(Q,j)*(rk0*gx(B,0,j) + rk3*d);
  }
#pragma unroll
  for(int w=0;w<16;w++){
    float ax=gx(B,96,3*w),ay=gx(B,96,3*w+1),az=gx(B,96,3*w+2);
    float cx=ay*yz-az*yy, cy=az*yx-ax*yz, cz=ax*yy-ay*yx;   // cross(PKvvv, y)
    float aw=rk1*gx(B,16,w);
    float kx=aw*yx + rk2*gx(B,24,3*w)   + rk4*cx;
    float ky=aw*yy + rk2*gx(B,24,3*w+1) + rk4*cy;
    float kz=aw*yz + rk2*gx(B,24,3*w+2) + rk4*cz;
    lg += gq(Q,32+3*w)*kx + gq(Q,32+3*w+1)*ky + gq(Q,32+3*w+2)*kz;
  }
  lg *= 0.11180339887498948f;   // (S+3V)^-0.5
  logit[q]=lg;

  uint4* rp = reinterpret_cast<uint4*>(rec + (size_t)q*40);
  // s-part comps 0..31, streamed stores
#pragma unroll
  for(int j2=0;j2<4;j2++){
    float m8[8];
#pragma unroll
    for(int k=0;k<8;k++){
      int j=8*j2+k;
      float d = yx*gx(B,168,3*j)+yy*gx(B,168,3*j+1)+yz*gx(B,168,3*j+2);
      m8[k] = rv0*gx(B,120,j) + rv3*d;
    }
    uint4 u2; u2.x=pk2(m8[0],m8[1]); u2.y=pk2(m8[2],m8[3]);
    u2.z=pk2(m8[4],m8[5]); u2.w=pk2(m8[6],m8[7]);
    rp[j2]=u2;
  }
  // v-part comps 32..79
  unsigned rb[24];
#pragma unroll
  for(int w2=0;w2<8;w2++){
    float mm[6];
#pragma unroll
    for(int k=0;k<2;k++){
      int ww=2*w2+k;
      float ax=gx(B,216,3*ww),ay=gx(B,216,3*ww+1),az=gx(B,216,3*ww+2);
      float cx=ay*yz-az*yy, cy=az*yx-ax*yz, cz=ax*yy-ay*yx;   // cross(PVvvv, y)
      float aw=rv1*gx(B,136,ww);
      mm[3*k+0]=aw*yx + rv2*gx(B,144,3*ww)   + rv4*cx;
      mm[3*k+1]=aw*yy + rv2*gx(B,144,3*ww+1) + rv4*cy;
      mm[3*k+2]=aw*yz + rv2*gx(B,144,3*ww+2) + rv4*cz;
    }
    rb[3*w2]  =pk2(mm[0],mm[1]);
    rb[3*w2+1]=pk2(mm[2],mm[3]);
    rb[3*w2+2]=pk2(mm[4],mm[5]);
  }
#pragma unroll
  for(int k=0;k<6;k++){
    uint4 u2; u2.x=rb[4*k]; u2.y=rb[4*k+1]; u2.z=rb[4*k+2]; u2.w=rb[4*k+3];
    rp[4+k]=u2;
  }
}

// ---------- gather: wave-per-node, chunk max + 4-deep shfl-broadcast accumulate ----------
__global__ __launch_bounds__(256) void k_gather(
  const int* __restrict__ rp_d, const int* __restrict__ eidq,
  const float* __restrict__ logit, const unsigned* __restrict__ rec,
  float* __restrict__ s, float* __restrict__ v)
{
  int wid = threadIdx.x>>6, lane = threadIdx.x&63;
  int n = blockIdx.x*4 + wid;
  if(n>=NN) return;
  int i0=rp_d[n], i1=rp_d[n+1];
  bool act = lane<40;
  float mx=-3.4e38f, z=0.f, aX=0.f, aY=0.f;
  for(int base=i0; base<i1; base+=64){
    int cnt = i1-base; if(cnt>64) cnt=64;
    int q = 0; float lg = -3.4e38f;
    if(lane<cnt){ q = eidq[base+lane]; lg = logit[q]; }
    float cm = lg;
#pragma unroll
    for(int off=32; off; off>>=1) cm = fmaxf(cm, __shfl_xor(cm, off));
    if(cm > mx){
      float sc = __expf(mx - cm);
      z*=sc; aX*=sc; aY*=sc; mx=cm;
    }
    float a = (lane<cnt)? __expf(lg - mx) : 0.f;
    int i=0;
    for(; i+4<=cnt; i+=4){
      int q0=__shfl(q,i), q1=__shfl(q,i+1), q2=__shfl(q,i+2), q3=__shfl(q,i+3);
      float a0=__shfl(a,i), a1=__shfl(a,i+1), a2=__shfl(a,i+2), a3=__shfl(a,i+3);
      unsigned c0 = act? rec[(size_t)q0*40+lane] : 0u;
      unsigned c1 = act? rec[(size_t)q1*40+lane] : 0u;
      unsigned c2 = act? rec[(size_t)q2*40+lane] : 0u;
      unsigned c3 = act? rec[(size_t)q3*40+lane] : 0u;
      aX += a0*bf2f(c0&0xffffu) + a1*bf2f(c1&0xffffu) + a2*bf2f(c2&0xffffu) + a3*bf2f(c3&0xffffu);
      aY += a0*bf2f(c0>>16)     + a1*bf2f(c1>>16)     + a2*bf2f(c2>>16)     + a3*bf2f(c3>>16);
      z  += a0+a1+a2+a3;
    }
    for(; i<cnt; i++){
      int   qi = __shfl(q, i);
      float ai = __shfl(a, i);
      unsigned c = act? rec[(size_t)qi*40+lane] : 0u;
      aX += ai*bf2f(c&0xffffu);
      aY += ai*bf2f(c>>16);
      z  += ai;
    }
  }
  float zi = 1.f/(z+1e-9f);
  int c = lane*2;
  if(lane<16){
    float2* spp = reinterpret_cast<float2*>(s + (size_t)n*32 + c);
    float2 t = *spp; t.x += aX*zi; t.y += aY*zi; *spp = t;
  } else if(lane<40){
    float2* vpp = reinterpret_cast<float2*>(v + (size_t)n*48 + (c-32));
    float2 t = *vpp; t.x += aX*zi; t.y += aY*zi; *vpp = t;
  }
}

// ---------- readout: FullyConnectedTensorProduct (f32 output) ----------
__global__ __launch_bounds__(256) void k_readout(
  const float* __restrict__ s, const float* __restrict__ v,
  const float* __restrict__ Wsss, const float* __restrict__ Wvvs,
  const float* __restrict__ Wsvv, const float* __restrict__ Wvsv, const float* __restrict__ Wvvv,
  float* __restrict__ out)
{
  int n = blockIdx.x*256 + threadIdx.x;
  if(n>=NN) return;
  float sn[32], vn[48];
  const float4* sp=reinterpret_cast<const float4*>(s+(size_t)n*32);
#pragma unroll
  for(int i=0;i<8;i++){ float4 t=sp[i]; sn[4*i]=t.x; sn[4*i+1]=t.y; sn[4*i+2]=t.z; sn[4*i+3]=t.w; }
  const float4* vp=reinterpret_cast<const float4*>(v+(size_t)n*48);
#pragma unroll
  for(int i=0;i<12;i++){ float4 t=vp[i]; vn[4*i]=t.x; vn[4*i+1]=t.y; vn[4*i+2]=t.z; vn[4*i+3]=t.w; }

  float os[16];
#pragma unroll
  for(int o=0;o<16;o++) os[o]=0.f;
  for(int a=0;a<32;a++){
    float sa=sn[a];
    for(int t=0;t<32;t++){
      float st=sa*sn[t];
      const float* w=Wsss+((size_t)a*32+t)*16;
#pragma unroll
      for(int o=0;o<16;o++) os[o]+=st*w[o];
    }
  }
  for(int a=0;a<16;a++){
    float ax=vn[a*3],ay=vn[a*3+1],az=vn[a*3+2];
    for(int b=0;b<16;b++){
      float d=ax*vn[b*3]+ay*vn[b*3+1]+az*vn[b*3+2];
      const float* w=Wvvs+((size_t)a*16+b)*16;
#pragma unroll
      for(int o=0;o<16;o++) os[o]+=d*w[o];
    }
  }
  float ov[24];
#pragma unroll
  for(int t=0;t<24;t++) ov[t]=0.f;
  for(int w=0;w<16;w++){
    float B[8];
#pragma unroll
    for(int o=0;o<8;o++) B[o]=0.f;
    for(int a=0;a<32;a++){
      const float* ww=Wsvv+((size_t)a*16+w)*8;
      float sa=sn[a];
#pragma unroll
      for(int o=0;o<8;o++) B[o]+=sa*ww[o];
    }
#pragma unroll
    for(int o=0;o<8;o++){ float b=B[o]; ov[o*3]+=b*vn[w*3]; ov[o*3+1]+=b*vn[w*3+1]; ov[o*3+2]+=b*vn[w*3+2]; }
  }
  for(int vv=0;vv<16;vv++){
    float B[8];
#pragma unroll
    for(int o=0;o<8;o++) B[o]=0.f;
    for(int a=0;a<32;a++){
      const float* ww=Wvsv+((size_t)vv*32+a)*8;
      float sa=sn[a];
#pragma unroll
      for(int o=0;o<8;o++) B[o]+=sa*ww[o];
    }
#pragma unroll
    for(int o=0;o<8;o++){ float b=B[o]; ov[o*3]+=b*vn[vv*3]; ov[o*3+1]+=b*vn[vv*3+1]; ov[o*3+2]+=b*vn[vv*3+2]; }
  }
  for(int a=0;a<16;a++){
    float ax=vn[a*3],ay=vn[a*3+1],az=vn[a*3+2];
    for(int b=0;b<16;b++){
      float bx=vn[b*3],by=vn[b*3+1],bz=vn[b*3+2];
      float cx=ay*bz-az*by, cy=az*bx-ax*bz, cz=ax*by-ay*bx;
      const float* w=Wvvv+((size_t)a*16+b)*8;
#pragma unroll
      for(int o=0;o<8;o++){ float wv=w[o]; ov[o*3]+=cx*wv; ov[o*3+1]+=cy*wv; ov[o*3+2]+=cz*wv; }
    }
  }
  float* op = out + (size_t)n*40;
#pragma unroll
  for(int o=0;o<16;o++) op[o]=os[o];
#pragma unroll
  for(int t=0;t<24;t++) op[16+t]=ov[t];
}

// ---------- launch ----------
extern "C" void kernel_launch(void* const* d_in, const int* in_sizes, int n_in,
                              void* d_out, int out_size, void* d_ws, size_t ws_size,
                              hipStream_t stream) {
  const float* f      = (const float*)d_in[0];
  const float* pos    = (const float*)d_in[1];
  const float* W_in   = (const float*)d_in[2];
  const float* Wq_s   = (const float*)d_in[3];
  const float* Wq_v   = (const float*)d_in[4];
  const float* Wk_ss  = (const float*)d_in[5];
  const float* Wk_sv  = (const float*)d_in[6];
  const float* Wk_vs  = (const float*)d_in[7];
  const float* Wk_vvs = (const float*)d_in[8];
  const float* Wk_vvv = (const float*)d_in[9];
  const float* W1k    = (const float*)d_in[10];
  const float* b1k    = (const float*)d_in[11];
  const float* W2k    = (const float*)d_in[12];
  const float* b2k    = (const float*)d_in[13];
  const float* Wv_ss  = (const float*)d_in[14];
  const float* Wv_sv  = (const float*)d_in[15];
  const float* Wv_vs  = (const float*)d_in[16];
  const float* Wv_vvs = (const float*)d_in[17];
  const float* Wv_vvv = (const float*)d_in[18];
  const float* W1v    = (const float*)d_in[19];
  const float* b1v    = (const float*)d_in[20];
  const float* W2v    = (const float*)d_in[21];
  const float* b2v    = (const float*)d_in[22];
  const float* Wr_sss = (const float*)d_in[23];
  const float* Wr_vvs = (const float*)d_in[24];
  const float* Wr_svv = (const float*)d_in[25];
  const float* Wr_vsv = (const float*)d_in[26];
  const float* Wr_vvv = (const float*)d_in[27];
  const int* esrc     = (const int*)d_in[28];
  const int* edst     = (const int*)d_in[29];

  char* w = (char*)d_ws;
  size_t off=0;
  auto takeB=[&](size_t bytes){ char* p=w+off; off+=(bytes+255)&~(size_t)255; return p; };
  float*    s      = (float*)   takeB((size_t)NN*32*4);
  float*    v      = (float*)   takeB((size_t)NN*48*4);
  unsigned* QPh    = (unsigned*)takeB((size_t)NN*64*4);
  unsigned* SPh    = (unsigned*)takeB((size_t)NN*256*4);
  unsigned* rec    = (unsigned*)takeB((size_t)EE*40*4);
  float*    logit  = (float*)   takeB((size_t)EE*4);
  float*    RT     = (float*)   takeB((size_t)2*NBIN*16*4);
  int*      esrc_s = (int*)     takeB((size_t)EE*4);
  int*      edst_s = (int*)     takeB((size_t)EE*4);
  int*      eidq   = (int*)     takeB((size_t)EE*4);
  int*      degs   = (int*)     takeB((size_t)NN*4*4);
  int*      rp_s   = (int*)     takeB((size_t)(NN+1)*4);
  int*      rp_d   = (int*)     takeB((size_t)(NN+1)*4);
  int* deg_s=degs, *cur_s=degs+NN, *deg_d=degs+2*NN, *cur_d=degs+3*NN;

  const int NB_N = (NN+255)/256;
  const int NB_E = (EE+255)/256;

  // radial LUT for both layers
  k_lut<<<(2*NBIN+255)/256,256,0,stream>>>(W1k,b1k,W2k,b2k, W1v,b1v,W2v,b2v, RT);

  // CSR build
  hipMemsetAsync(degs, 0, (size_t)NN*4*4, stream);
  k_hist<<<NB_E,256,0,stream>>>(esrc, edst, deg_s, deg_d);
  k_scan<<<1,1024,0,stream>>>(deg_s, rp_s);
  k_scan<<<1,1024,0,stream>>>(deg_d, rp_d);
  k_fill_src<<<NB_E,256,0,stream>>>(esrc, edst, rp_s, cur_s, esrc_s, edst_s);
  k_fill_dst<<<NB_E,256,0,stream>>>(edst_s, rp_d, cur_d, eidq);

  hipMemsetAsync(v, 0, (size_t)NN*48*4, stream);
  k_sinit<<<NB_N,256,0,stream>>>(f, W_in, s);

  for(int l=0;l<2;l++){
    k_nodeprep<<<NB_N,256,0,stream>>>(s, v, pos,
      Wq_s+l*1024, Wq_v+l*256,
      Wk_ss+l*1024, Wk_sv+l*512, Wk_vs+l*256, Wk_vvs+l*512, Wk_vvv+l*256,
      Wv_ss+l*1024, Wv_sv+l*512, Wv_vs+l*256, Wv_vvs+l*512, Wv_vvv+l*256,
      QPh, SPh);
    k_edge<<<NB_E,256,0,stream>>>(esrc_s, edst_s, RT + (size_t)l*NBIN*16,
      QPh, SPh, logit, rec);
    k_gather<<<(NN+3)/4,256,0,stream>>>(rp_d, eidq, logit, rec, s, v);
  }

  k_readout<<<NB_N,256,0,stream>>>(s, v, Wr_sss, Wr_vvs, Wr_svv, Wr_vsv, Wr_vvv,
                                   (float*)d_out);
}

// Round 9
// 1938.960 us; speedup vs baseline: 4.2541x; 1.1082x over previous
//
#include <hip/hip_runtime.h>

#define NN 50000
#define EE 800000
#define NBIN 8192
#define RMAXT 17.33f

// ---------- bf16 helpers (RNE) ----------
__device__ __forceinline__ unsigned f2bf(float f){
  unsigned u = __float_as_uint(f);
  return (u + 0x7fffu + ((u>>16)&1u)) >> 16;
}
__device__ __forceinline__ float bf2f(unsigned hs){ return __uint_as_float(hs<<16); }
__device__ __forceinline__ unsigned pk2(float a, float b){ return f2bf(a) | (f2bf(b)<<16); }
__device__ __forceinline__ float gx(const unsigned* __restrict__ B, int base, int c){
  unsigned u = B[base + (c>>1)];
  return bf2f((c&1)? (u>>16) : (u&0xffffu));
}
__device__ __forceinline__ float gq(const unsigned* __restrict__ Q, int c){
  unsigned u = Q[4 + (c>>1)];
  return bf2f((c&1)? (u>>16) : (u&0xffffu));
}

// radial MLP (exact) — used only by the LUT builder
__device__ __forceinline__ void radial_mlp(const float* __restrict__ W1,
                                           const float* __restrict__ b1,
                                           const float* __restrict__ W2,
                                           const float* __restrict__ b2,
                                           const float* basis, float* rk){
#pragma unroll
  for(int p=0;p<5;p++) rk[p]=b2[p];
  for(int h=0;h<64;h++){
    float t=b1[h];
#pragma unroll
    for(int b=0;b<16;b++) t += basis[b]*W1[b*64+h];
    float sg = t/(1.f+__expf(-t));
#pragma unroll
    for(int p=0;p<5;p++) rk[p]+=sg*W2[h*5+p];
  }
}

// ---------- radial LUT: RT[layer][bin][16] = [rk0..4, rv0..4, pad6] ----------
__global__ __launch_bounds__(256) void k_lut(
  const float* __restrict__ W1k, const float* __restrict__ b1k,
  const float* __restrict__ W2k, const float* __restrict__ b2k,
  const float* __restrict__ W1v, const float* __restrict__ b1v,
  const float* __restrict__ W2v, const float* __restrict__ b2v,
  float* __restrict__ RT)
{
  int idx = blockIdx.x*256 + threadIdx.x;
  if(idx >= 2*NBIN) return;
  int l = idx / NBIN, bin = idx % NBIN;
  float r = (float)bin * (RMAXT/(float)(NBIN-1));
  float basis[16];
#pragma unroll
  for(int b=0;b<16;b++){
    float d=(r - (10.f/15.f)*(float)b)*1.6f;
    basis[b]=__expf(-d*d);
  }
  float rk[5], rv[5];
  radial_mlp(W1k+l*1024, b1k+l*64, W2k+l*320, b2k+l*5, basis, rk);
  radial_mlp(W1v+l*1024, b1v+l*64, W2v+l*320, b2v+l*5, basis, rv);
  float* row = RT + ((size_t)l*NBIN + bin)*16;
#pragma unroll
  for(int p=0;p<5;p++) row[p]=rk[p];
#pragma unroll
  for(int p=0;p<5;p++) row[5+p]=rv[p];
  row[10]=0.f; row[11]=0.f;
}

// ---------- CSR build ----------
__global__ __launch_bounds__(256) void k_hist(const int* __restrict__ esrc, const int* __restrict__ edst,
                                              int* __restrict__ deg_s, int* __restrict__ deg_d){
  int e = blockIdx.x*256 + threadIdx.x;
  if(e<EE){ atomicAdd(&deg_s[esrc[e]],1); atomicAdd(&deg_d[edst[e]],1); }
}

__global__ __launch_bounds__(1024) void k_scan(const int* __restrict__ deg, int* __restrict__ rowptr){
  __shared__ int wsum[16];
  const int C = (NN + 1023)/1024;
  int t = threadIdx.x, lane = t&63, wid = t>>6;
  int lo = t*C, hi = lo+C; if(lo>NN) lo=NN; if(hi>NN) hi=NN;
  int loc = 0;
  for(int i=lo;i<hi;i++) loc += deg[i];
  int x = loc;
#pragma unroll
  for(int off=1; off<64; off<<=1){ int y = __shfl_up(x, off); if(lane>=off) x += y; }
  if(lane==63) wsum[wid] = x;
  __syncthreads();
  if(wid==0 && lane<16){
    int w = wsum[lane];
#pragma unroll
    for(int off=1; off<16; off<<=1){ int y = __shfl_up(w, off); if(lane>=off) w += y; }
    wsum[lane]=w;
  }
  __syncthreads();
  int base = (wid>0? wsum[wid-1]:0) + (x - loc);
  int run = base;
  for(int i=lo;i<hi;i++){ rowptr[i] = run; run += deg[i]; }
  if(t==1023) rowptr[NN] = run;
}

__global__ __launch_bounds__(256) void k_fill_src(const int* __restrict__ esrc, const int* __restrict__ edst,
                                                  const int* __restrict__ rp_s, int* __restrict__ cur_s,
                                                  int* __restrict__ esrc_s, int* __restrict__ edst_s){
  int e = blockIdx.x*256 + threadIdx.x;
  if(e>=EE) return;
  int s = esrc[e], d = edst[e];
  int q = rp_s[s] + atomicAdd(&cur_s[s],1);
  esrc_s[q]=s; edst_s[q]=d;
}
__global__ __launch_bounds__(256) void k_fill_dst(const int* __restrict__ edst_s,
                                                  const int* __restrict__ rp_d, int* __restrict__ cur_d,
                                                  int* __restrict__ eidq){
  int q = blockIdx.x*256 + threadIdx.x;
  if(q>=EE) return;
  int d = edst_s[q];
  int p = rp_d[d] + atomicAdd(&cur_d[d],1);
  eidq[p] = q;
}

// ---------- s = f @ W_in ----------
__global__ __launch_bounds__(256) void k_sinit(const float* __restrict__ f,
                                               const float* __restrict__ Win,
                                               float* __restrict__ s){
  int n = blockIdx.x*256 + threadIdx.x;
  if(n>=NN) return;
  float fi[32], acc[32];
  const float4* fp = reinterpret_cast<const float4*>(f + (size_t)n*32);
#pragma unroll
  for(int i=0;i<8;i++){ float4 t=fp[i]; fi[4*i]=t.x; fi[4*i+1]=t.y; fi[4*i+2]=t.z; fi[4*i+3]=t.w; }
#pragma unroll
  for(int j=0;j<32;j++) acc[j]=0.f;
  for(int i=0;i<32;i++){
    float c=fi[i];
#pragma unroll
    for(int j=0;j<32;j++) acc[j]+=c*Win[i*32+j];
  }
  float4* sp = reinterpret_cast<float4*>(s + (size_t)n*32);
#pragma unroll
  for(int i=0;i<8;i++){ float4 t; t.x=acc[4*i]; t.y=acc[4*i+1]; t.z=acc[4*i+2]; t.w=acc[4*i+3]; sp[i]=t; }
}

// ---------- per-node precompute into packed bf16 rows ----------
// QPh row (64 u32): [0..2]=pos f32, [3]=pad, [4..44)=80 q comps
// SPh row (256 u32): AKss 0, AKsv 16, PKvs 24, PKvvs 48, PKvvv 96,
//                    AVss 120, AVsv 136, PVvs 144, PVvvs 168, PVvvv 216, pos 240..242
__global__ __launch_bounds__(256) void k_nodeprep(
  const float* __restrict__ s, const float* __restrict__ v, const float* __restrict__ pos,
  const float* __restrict__ Wqs, const float* __restrict__ Wqv,
  const float* __restrict__ Kss, const float* __restrict__ Ksv, const float* __restrict__ Kvs,
  const float* __restrict__ Kvvs, const float* __restrict__ Kvvv,
  const float* __restrict__ Vss, const float* __restrict__ Vsv, const float* __restrict__ Vvs,
  const float* __restrict__ Vvvs, const float* __restrict__ Vvvv,
  unsigned* __restrict__ QPh, unsigned* __restrict__ SPh)
{
  int n = blockIdx.x*256 + threadIdx.x;
  if(n>=NN) return;
  float sn[32], vn[48];
  const float4* sp=reinterpret_cast<const float4*>(s+(size_t)n*32);
#pragma unroll
  for(int i=0;i<8;i++){ float4 t=sp[i]; sn[4*i]=t.x; sn[4*i+1]=t.y; sn[4*i+2]=t.z; sn[4*i+3]=t.w; }
  const float4* vp=reinterpret_cast<const float4*>(v+(size_t)n*48);
#pragma unroll
  for(int i=0;i<12;i++){ float4 t=vp[i]; vn[4*i]=t.x; vn[4*i+1]=t.y; vn[4*i+2]=t.z; vn[4*i+3]=t.w; }

  unsigned* qrow = QPh + (size_t)n*64;
  unsigned* brow = SPh + (size_t)n*256;

#define SMAT32C(W, ARR) { \
  _Pragma("unroll") for(int j=0;j<32;j++) ARR[j]=0.f; \
  for(int i=0;i<32;i++){ float c=sn[i]; \
    _Pragma("unroll") for(int j=0;j<32;j++) ARR[j]+=c*W[i*32+j]; } }
#define SMAT16C(W, ARR) { \
  _Pragma("unroll") for(int j=0;j<16;j++) ARR[j]=0.f; \
  for(int i=0;i<32;i++){ float c=sn[i]; \
    _Pragma("unroll") for(int j=0;j<16;j++) ARR[j]+=c*W[i*16+j]; } }
#define VMAT16C(W, ARR) \
  for(int w=0;w<16;w++){ float ax=0,ay=0,az=0; \
    _Pragma("unroll") for(int t=0;t<16;t++){ float wt=W[t*16+w]; ax+=vn[t*3]*wt; ay+=vn[t*3+1]*wt; az+=vn[t*3+2]*wt; } \
    ARR[w*3]=ax; ARR[w*3+1]=ay; ARR[w*3+2]=az; }
#define VMAT32C(W, ARR) \
  for(int j=0;j<32;j++){ float ax=0,ay=0,az=0; \
    _Pragma("unroll") for(int t=0;t<16;t++){ float wt=W[t*32+j]; ax+=vn[t*3]*wt; ay+=vn[t*3+1]*wt; az+=vn[t*3+2]*wt; } \
    ARR[j*3]=ax; ARR[j*3+1]=ay; ARR[j*3+2]=az; }
#define PACKST(ARR, NCOMP, ROW, BASE) { \
  uint4* dst4 = reinterpret_cast<uint4*>((ROW) + (BASE)); \
  _Pragma("unroll") for(int k=0;k<(NCOMP)/8;k++){ \
    uint4 u; u.x=pk2(ARR[8*k],ARR[8*k+1]); u.y=pk2(ARR[8*k+2],ARR[8*k+3]); \
    u.z=pk2(ARR[8*k+4],ARR[8*k+5]); u.w=pk2(ARR[8*k+6],ARR[8*k+7]); dst4[k]=u; } }

  float a32[32], a96[96];
  qrow[0]=__float_as_uint(pos[(size_t)n*3]);
  qrow[1]=__float_as_uint(pos[(size_t)n*3+1]);
  qrow[2]=__float_as_uint(pos[(size_t)n*3+2]);
  qrow[3]=0u;
  SMAT32C(Wqs, a32)  PACKST(a32, 32, qrow, 4)
  { float a48[48]; VMAT16C(Wqv, a48) PACKST(a48, 48, qrow, 20) }
  SMAT32C(Kss, a32)  PACKST(a32, 32, brow, 0)
  { float a16[16]; SMAT16C(Ksv, a16) PACKST(a16, 16, brow, 16) }
  { float a48[48]; VMAT16C(Kvs, a48) PACKST(a48, 48, brow, 24) }
  VMAT32C(Kvvs, a96) PACKST(a96, 96, brow, 48)
  { float a48[48]; VMAT16C(Kvvv, a48) PACKST(a48, 48, brow, 96) }
  SMAT32C(Vss, a32)  PACKST(a32, 32, brow, 120)
  { float a16[16]; SMAT16C(Vsv, a16) PACKST(a16, 16, brow, 136) }
  { float a48[48]; VMAT16C(Vvs, a48) PACKST(a48, 48, brow, 144) }
  VMAT32C(Vvvs, a96) PACKST(a96, 96, brow, 168)
  { float a48[48]; VMAT16C(Vvvv, a48) PACKST(a48, 48, brow, 216) }
  brow[240]=__float_as_uint(pos[(size_t)n*3]);
  brow[241]=__float_as_uint(pos[(size_t)n*3+1]);
  brow[242]=__float_as_uint(pos[(size_t)n*3+2]);
#undef SMAT32C
#undef SMAT16C
#undef VMAT16C
#undef VMAT32C
#undef PACKST
}

// ---------- fused edge pass (src-sorted): LUT radial + logit + bf16 message ----------
// rec row: 40 u32 (160B) = 80 msg comps; logit separate.
// NOTE: plain launch_bounds — R7's (256,4) clamp forced VGPR=64 and spilled
// the B-row working set to scratch (FETCH 122->777MB, WRITE 188->744MB).
__global__ __launch_bounds__(256) void k_edge(
  const int* __restrict__ esrc_s, const int* __restrict__ edst_s,
  const float* __restrict__ RT,
  const unsigned* __restrict__ QPh, const unsigned* __restrict__ SPh,
  float* __restrict__ logit, unsigned* __restrict__ rec)
{
  int q = blockIdx.x*256 + threadIdx.x;
  if(q>=EE) return;
  int src=esrc_s[q], dst=edst_s[q];
  const unsigned* B = SPh + (size_t)src*256;
  const unsigned* Q = QPh + (size_t)dst*64;
  float px = __uint_as_float(B[240]) - __uint_as_float(Q[0]);
  float py = __uint_as_float(B[241]) - __uint_as_float(Q[1]);
  float pz = __uint_as_float(B[242]) - __uint_as_float(Q[2]);
  float r = sqrtf(px*px+py*py+pz*pz);
  float inv = 1.f/(r+1e-9f);
  float yx=px*inv, yy=py*inv, yz=pz*inv;

  // radial LUT lerp
  float u = r * ((float)(NBIN-1)/RMAXT);
  int i0 = (int)u; if(i0 > NBIN-2) i0 = NBIN-2;
  float fr = u - (float)i0; fr = fminf(fr, 1.f);
  const float4* T0 = reinterpret_cast<const float4*>(RT + (size_t)i0*16);
  const float4* T1 = reinterpret_cast<const float4*>(RT + (size_t)(i0+1)*16);
  float4 A0=T0[0], B0=T0[1], C0=T0[2];
  float4 A1=T1[0], B1=T1[1], C1=T1[2];
  float rk0=A0.x+fr*(A1.x-A0.x), rk1=A0.y+fr*(A1.y-A0.y);
  float rk2=A0.z+fr*(A1.z-A0.z), rk3=A0.w+fr*(A1.w-A0.w);
  float rk4=B0.x+fr*(B1.x-B0.x);
  float rv0=B0.y+fr*(B1.y-B0.y), rv1=B0.z+fr*(B1.z-B0.z);
  float rv2=B0.w+fr*(B1.w-B0.w);
  float rv3=C0.x+fr*(C1.x-C0.x), rv4=C0.y+fr*(C1.y-C0.y);

  float lg=0.f;
#pragma unroll
  for(int j=0;j<32;j++){
    float d = yx*gx(B,48,3*j)+yy*gx(B,48,3*j+1)+yz*gx(B,48,3*j+2);
    lg += gq(Q,j)*(rk0*gx(B,0,j) + rk3*d);
  }
#pragma unroll
  for(int w=0;w<16;w++){
    float ax=gx(B,96,3*w),ay=gx(B,96,3*w+1),az=gx(B,96,3*w+2);
    float cx=ay*yz-az*yy, cy=az*yx-ax*yz, cz=ax*yy-ay*yx;   // cross(PKvvv, y)
    float aw=rk1*gx(B,16,w);
    float kx=aw*yx + rk2*gx(B,24,3*w)   + rk4*cx;
    float ky=aw*yy + rk2*gx(B,24,3*w+1) + rk4*cy;
    float kz=aw*yz + rk2*gx(B,24,3*w+2) + rk4*cz;
    lg += gq(Q,32+3*w)*kx + gq(Q,32+3*w+1)*ky + gq(Q,32+3*w+2)*kz;
  }
  lg *= 0.11180339887498948f;   // (S+3V)^-0.5
  logit[q]=lg;

  uint4* rp = reinterpret_cast<uint4*>(rec + (size_t)q*40);
#pragma unroll
  for(int j2=0;j2<4;j2++){
    float m8[8];
#pragma unroll
    for(int k=0;k<8;k++){
      int j=8*j2+k;
      float d = yx*gx(B,168,3*j)+yy*gx(B,168,3*j+1)+yz*gx(B,168,3*j+2);
      m8[k] = rv0*gx(B,120,j) + rv3*d;
    }
    uint4 u2; u2.x=pk2(m8[0],m8[1]); u2.y=pk2(m8[2],m8[3]);
    u2.z=pk2(m8[4],m8[5]); u2.w=pk2(m8[6],m8[7]);
    rp[j2]=u2;
  }
  unsigned rb[24];
#pragma unroll
  for(int w2=0;w2<8;w2++){
    float mm[6];
#pragma unroll
    for(int k=0;k<2;k++){
      int ww=2*w2+k;
      float ax=gx(B,216,3*ww),ay=gx(B,216,3*ww+1),az=gx(B,216,3*ww+2);
      float cx=ay*yz-az*yy, cy=az*yx-ax*yz, cz=ax*yy-ay*yx;   // cross(PVvvv, y)
      float aw=rv1*gx(B,136,ww);
      mm[3*k+0]=aw*yx + rv2*gx(B,144,3*ww)   + rv4*cx;
      mm[3*k+1]=aw*yy + rv2*gx(B,144,3*ww+1) + rv4*cy;
      mm[3*k+2]=aw*yz + rv2*gx(B,144,3*ww+2) + rv4*cz;
    }
    rb[3*w2]  =pk2(mm[0],mm[1]);
    rb[3*w2+1]=pk2(mm[2],mm[3]);
    rb[3*w2+2]=pk2(mm[4],mm[5]);
  }
#pragma unroll
  for(int k=0;k<6;k++){
    uint4 u2; u2.x=rb[4*k]; u2.y=rb[4*k+1]; u2.z=rb[4*k+2]; u2.w=rb[4*k+3];
    rp[4+k]=u2;
  }
}

// ---------- gather: wave-per-node, chunk max + 4-deep shfl-broadcast accumulate ----------
__global__ __launch_bounds__(256) void k_gather(
  const int* __restrict__ rp_d, const int* __restrict__ eidq,
  const float* __restrict__ logit, const unsigned* __restrict__ rec,
  float* __restrict__ s, float* __restrict__ v)
{
  int wid = threadIdx.x>>6, lane = threadIdx.x&63;
  int n = blockIdx.x*4 + wid;
  if(n>=NN) return;
  int i0=rp_d[n], i1=rp_d[n+1];
  bool act = lane<40;
  float mx=-3.4e38f, z=0.f, aX=0.f, aY=0.f;
  for(int base=i0; base<i1; base+=64){
    int cnt = i1-base; if(cnt>64) cnt=64;
    int q = 0; float lg = -3.4e38f;
    if(lane<cnt){ q = eidq[base+lane]; lg = logit[q]; }
    float cm = lg;
#pragma unroll
    for(int off=32; off; off>>=1) cm = fmaxf(cm, __shfl_xor(cm, off));
    if(cm > mx){
      float sc = __expf(mx - cm);
      z*=sc; aX*=sc; aY*=sc; mx=cm;
    }
    float a = (lane<cnt)? __expf(lg - mx) : 0.f;
    int i=0;
    for(; i+4<=cnt; i+=4){
      int q0=__shfl(q,i), q1=__shfl(q,i+1), q2=__shfl(q,i+2), q3=__shfl(q,i+3);
      float a0=__shfl(a,i), a1=__shfl(a,i+1), a2=__shfl(a,i+2), a3=__shfl(a,i+3);
      unsigned c0 = act? rec[(size_t)q0*40+lane] : 0u;
      unsigned c1 = act? rec[(size_t)q1*40+lane] : 0u;
      unsigned c2 = act? rec[(size_t)q2*40+lane] : 0u;
      unsigned c3 = act? rec[(size_t)q3*40+lane] : 0u;
      aX += a0*bf2f(c0&0xffffu) + a1*bf2f(c1&0xffffu) + a2*bf2f(c2&0xffffu) + a3*bf2f(c3&0xffffu);
      aY += a0*bf2f(c0>>16)     + a1*bf2f(c1>>16)     + a2*bf2f(c2>>16)     + a3*bf2f(c3>>16);
      z  += a0+a1+a2+a3;
    }
    for(; i<cnt; i++){
      int   qi = __shfl(q, i);
      float ai = __shfl(a, i);
      unsigned c = act? rec[(size_t)qi*40+lane] : 0u;
      aX += ai*bf2f(c&0xffffu);
      aY += ai*bf2f(c>>16);
      z  += ai;
    }
  }
  float zi = 1.f/(z+1e-9f);
  int c = lane*2;
  if(lane<16){
    float2* spp = reinterpret_cast<float2*>(s + (size_t)n*32 + c);
    float2 t = *spp; t.x += aX*zi; t.y += aY*zi; *spp = t;
  } else if(lane<40){
    float2* vpp = reinterpret_cast<float2*>(v + (size_t)n*48 + (c-32));
    float2 t = *vpp; t.x += aX*zi; t.y += aY*zi; *vpp = t;
  }
}

// ---------- readout: FullyConnectedTensorProduct (f32 output) ----------
__global__ __launch_bounds__(256) void k_readout(
  const float* __restrict__ s, const float* __restrict__ v,
  const float* __restrict__ Wsss, const float* __restrict__ Wvvs,
  const float* __restrict__ Wsvv, const float* __restrict__ Wvsv, const float* __restrict__ Wvvv,
  float* __restrict__ out)
{
  int n = blockIdx.x*256 + threadIdx.x;
  if(n>=NN) return;
  float sn[32], vn[48];
  const float4* sp=reinterpret_cast<const float4*>(s+(size_t)n*32);
#pragma unroll
  for(int i=0;i<8;i++){ float4 t=sp[i]; sn[4*i]=t.x; sn[4*i+1]=t.y; sn[4*i+2]=t.z; sn[4*i+3]=t.w; }
  const float4* vp=reinterpret_cast<const float4*>(v+(size_t)n*48);
#pragma unroll
  for(int i=0;i<12;i++){ float4 t=vp[i]; vn[4*i]=t.x; vn[4*i+1]=t.y; vn[4*i+2]=t.z; vn[4*i+3]=t.w; }

  float os[16];
#pragma unroll
  for(int o=0;o<16;o++) os[o]=0.f;
  for(int a=0;a<32;a++){
    float sa=sn[a];
    for(int t=0;t<32;t++){
      float st=sa*sn[t];
      const float* w=Wsss+((size_t)a*32+t)*16;
#pragma unroll
      for(int o=0;o<16;o++) os[o]+=st*w[o];
    }
  }
  for(int a=0;a<16;a++){
    float ax=vn[a*3],ay=vn[a*3+1],az=vn[a*3+2];
    for(int b=0;b<16;b++){
      float d=ax*vn[b*3]+ay*vn[b*3+1]+az*vn[b*3+2];
      const float* w=Wvvs+((size_t)a*16+b)*16;
#pragma unroll
      for(int o=0;o<16;o++) os[o]+=d*w[o];
    }
  }
  float ov[24];
#pragma unroll
  for(int t=0;t<24;t++) ov[t]=0.f;
  for(int w=0;w<16;w++){
    float B[8];
#pragma unroll
    for(int o=0;o<8;o++) B[o]=0.f;
    for(int a=0;a<32;a++){
      const float* ww=Wsvv+((size_t)a*16+w)*8;
      float sa=sn[a];
#pragma unroll
      for(int o=0;o<8;o++) B[o]+=sa*ww[o];
    }
#pragma unroll
    for(int o=0;o<8;o++){ float b=B[o]; ov[o*3]+=b*vn[w*3]; ov[o*3+1]+=b*vn[w*3+1]; ov[o*3+2]+=b*vn[w*3+2]; }
  }
  for(int vv=0;vv<16;vv++){
    float B[8];
#pragma unroll
    for(int o=0;o<8;o++) B[o]=0.f;
    for(int a=0;a<32;a++){
      const float* ww=Wvsv+((size_t)vv*32+a)*8;
      float sa=sn[a];
#pragma unroll
      for(int o=0;o<8;o++) B[o]+=sa*ww[o];
    }
#pragma unroll
    for(int o=0;o<8;o++){ float b=B[o]; ov[o*3]+=b*vn[vv*3]; ov[o*3+1]+=b*vn[vv*3+1]; ov[o*3+2]+=b*vn[vv*3+2]; }
  }
  for(int a=0;a<16;a++){
    float ax=vn[a*3],ay=vn[a*3+1],az=vn[a*3+2];
    for(int b=0;b<16;b++){
      float bx=vn[b*3],by=vn[b*3+1],bz=vn[b*3+2];
      float cx=ay*bz-az*by, cy=az*bx-ax*bz, cz=ax*by-ay*bx;
      const float* w=Wvvv+((size_t)a*16+b)*8;
#pragma unroll
      for(int o=0;o<8;o++){ float wv=w[o]; ov[o*3]+=cx*wv; ov[o*3+1]+=cy*wv; ov[o*3+2]+=cz*wv; }
    }
  }
  float* op = out + (size_t)n*40;
#pragma unroll
  for(int o=0;o<16;o++) op[o]=os[o];
#pragma unroll
  for(int t=0;t<24;t++) op[16+t]=ov[t];
}

// ---------- launch ----------
extern "C" void kernel_launch(void* const* d_in, const int* in_sizes, int n_in,
                              void* d_out, int out_size, void* d_ws, size_t ws_size,
                              hipStream_t stream) {
  const float* f      = (const float*)d_in[0];
  const float* pos    = (const float*)d_in[1];
  const float* W_in   = (const float*)d_in[2];
  const float* Wq_s   = (const float*)d_in[3];
  const float* Wq_v   = (const float*)d_in[4];
  const float* Wk_ss  = (const float*)d_in[5];
  const float* Wk_sv  = (const float*)d_in[6];
  const float* Wk_vs  = (const float*)d_in[7];
  const float* Wk_vvs = (const float*)d_in[8];
  const float* Wk_vvv = (const float*)d_in[9];
  const float* W1k    = (const float*)d_in[10];
  const float* b1k    = (const float*)d_in[11];
  const float* W2k    = (const float*)d_in[12];
  const float* b2k    = (const float*)d_in[13];
  const float* Wv_ss  = (const float*)d_in[14];
  const float* Wv_sv  = (const float*)d_in[15];
  const float* Wv_vs  = (const float*)d_in[16];
  const float* Wv_vvs = (const float*)d_in[17];
  const float* Wv_vvv = (const float*)d_in[18];
  const float* W1v    = (const float*)d_in[19];
  const float* b1v    = (const float*)d_in[20];
  const float* W2v    = (const float*)d_in[21];
  const float* b2v    = (const float*)d_in[22];
  const float* Wr_sss = (const float*)d_in[23];
  const float* Wr_vvs = (const float*)d_in[24];
  const float* Wr_svv = (const float*)d_in[25];
  const float* Wr_vsv = (const float*)d_in[26];
  const float* Wr_vvv = (const float*)d_in[27];
  const int* esrc     = (const int*)d_in[28];
  const int* edst     = (const int*)d_in[29];

  char* w = (char*)d_ws;
  size_t off=0;
  auto takeB=[&](size_t bytes){ char* p=w+off; off+=(bytes+255)&~(size_t)255; return p; };
  float*    s      = (float*)   takeB((size_t)NN*32*4);
  float*    v      = (float*)   takeB((size_t)NN*48*4);
  unsigned* QPh    = (unsigned*)takeB((size_t)NN*64*4);
  unsigned* SPh    = (unsigned*)takeB((size_t)NN*256*4);
  unsigned* rec    = (unsigned*)takeB((size_t)EE*40*4);
  float*    logit  = (float*)   takeB((size_t)EE*4);
  float*    RT     = (float*)   takeB((size_t)2*NBIN*16*4);
  int*      esrc_s = (int*)     takeB((size_t)EE*4);
  int*      edst_s = (int*)     takeB((size_t)EE*4);
  int*      eidq   = (int*)     takeB((size_t)EE*4);
  int*      degs   = (int*)     takeB((size_t)NN*4*4);
  int*      rp_s   = (int*)     takeB((size_t)(NN+1)*4);
  int*      rp_d   = (int*)     takeB((size_t)(NN+1)*4);
  int* deg_s=degs, *cur_s=degs+NN, *deg_d=degs+2*NN, *cur_d=degs+3*NN;

  const int NB_N = (NN+255)/256;
  const int NB_E = (EE+255)/256;

  // radial LUT for both layers
  k_lut<<<(2*NBIN+255)/256,256,0,stream>>>(W1k,b1k,W2k,b2k, W1v,b1v,W2v,b2v, RT);

  // CSR build
  hipMemsetAsync(degs, 0, (size_t)NN*4*4, stream);
  k_hist<<<NB_E,256,0,stream>>>(esrc, edst, deg_s, deg_d);
  k_scan<<<1,1024,0,stream>>>(deg_s, rp_s);
  k_scan<<<1,1024,0,stream>>>(deg_d, rp_d);
  k_fill_src<<<NB_E,256,0,stream>>>(esrc, edst, rp_s, cur_s, esrc_s, edst_s);
  k_fill_dst<<<NB_E,256,0,stream>>>(edst_s, rp_d, cur_d, eidq);

  hipMemsetAsync(v, 0, (size_t)NN*48*4, stream);
  k_sinit<<<NB_N,256,0,stream>>>(f, W_in, s);

  for(int l=0;l<2;l++){
    k_nodeprep<<<NB_N,256,0,stream>>>(s, v, pos,
      Wq_s+l*1024, Wq_v+l*256,
      Wk_ss+l*1024, Wk_sv+l*512, Wk_vs+l*256, Wk_vvs+l*512, Wk_vvv+l*256,
      Wv_ss+l*1024, Wv_sv+l*512, Wv_vs+l*256, Wv_vvs+l*512, Wv_vvv+l*256,
      QPh, SPh);
    k_edge<<<NB_E,256,0,stream>>>(esrc_s, edst_s, RT + (size_t)l*NBIN*16,
      QPh, SPh, logit, rec);
    k_gather<<<(NN+3)/4,256,0,stream>>>(rp_d, eidq, logit, rec, s, v);
  }

  k_readout<<<NB_N,256,0,stream>>>(s, v, Wr_sss, Wr_vvs, Wr_svv, Wr_vsv, Wr_vvv,
                                   (float*)d_out);
}

// Round 11
// 1303.593 us; speedup vs baseline: 6.3275x; 1.4874x over previous
//
#include <hip/hip_runtime.h>

#define NN 50000
#define EE 800000
#define NBIN 8192
#define RMAXT 17.33f

// ---------- bf16 helpers (RNE) ----------
__device__ __forceinline__ unsigned f2bf(float f){
  unsigned u = __float_as_uint(f);
  return (u + 0x7fffu + ((u>>16)&1u)) >> 16;
}
__device__ __forceinline__ float bf2f(unsigned hs){ return __uint_as_float(hs<<16); }
__device__ __forceinline__ unsigned pk2(float a, float b){ return f2bf(a) | (f2bf(b)<<16); }
__device__ __forceinline__ float gx(const unsigned* __restrict__ B, int base, int c){
  unsigned u = B[base + (c>>1)];
  return bf2f((c&1)? (u>>16) : (u&0xffffu));
}
__device__ __forceinline__ float gq(const unsigned* __restrict__ Q, int c){
  unsigned u = Q[4 + (c>>1)];
  return bf2f((c&1)? (u>>16) : (u&0xffffu));
}

// radial MLP (exact) — used only by the LUT builder
__device__ __forceinline__ void radial_mlp(const float* __restrict__ W1,
                                           const float* __restrict__ b1,
                                           const float* __restrict__ W2,
                                           const float* __restrict__ b2,
                                           const float* basis, float* rk){
#pragma unroll
  for(int p=0;p<5;p++) rk[p]=b2[p];
  for(int h=0;h<64;h++){
    float t=b1[h];
#pragma unroll
    for(int b=0;b<16;b++) t += basis[b]*W1[b*64+h];
    float sg = t/(1.f+__expf(-t));
#pragma unroll
    for(int p=0;p<5;p++) rk[p]+=sg*W2[h*5+p];
  }
}

// ---------- radial LUT ----------
__global__ __launch_bounds__(256) void k_lut(
  const float* __restrict__ W1k, const float* __restrict__ b1k,
  const float* __restrict__ W2k, const float* __restrict__ b2k,
  const float* __restrict__ W1v, const float* __restrict__ b1v,
  const float* __restrict__ W2v, const float* __restrict__ b2v,
  float* __restrict__ RT)
{
  int idx = blockIdx.x*256 + threadIdx.x;
  if(idx >= 2*NBIN) return;
  int l = idx / NBIN, bin = idx % NBIN;
  float r = (float)bin * (RMAXT/(float)(NBIN-1));
  float basis[16];
#pragma unroll
  for(int b=0;b<16;b++){
    float d=(r - (10.f/15.f)*(float)b)*1.6f;
    basis[b]=__expf(-d*d);
  }
  float rk[5], rv[5];
  radial_mlp(W1k+l*1024, b1k+l*64, W2k+l*320, b2k+l*5, basis, rk);
  radial_mlp(W1v+l*1024, b1v+l*64, W2v+l*320, b2v+l*5, basis, rv);
  float* row = RT + ((size_t)l*NBIN + bin)*16;
#pragma unroll
  for(int p=0;p<5;p++) row[p]=rk[p];
#pragma unroll
  for(int p=0;p<5;p++) row[5+p]=rv[p];
  row[10]=0.f; row[11]=0.f;
}

// ---------- CSR build ----------
__global__ __launch_bounds__(256) void k_hist(const int* __restrict__ esrc, const int* __restrict__ edst,
                                              int* __restrict__ deg_s, int* __restrict__ deg_d){
  int e = blockIdx.x*256 + threadIdx.x;
  if(e<EE){ atomicAdd(&deg_s[esrc[e]],1); atomicAdd(&deg_d[edst[e]],1); }
}

__global__ __launch_bounds__(1024) void k_scan(const int* __restrict__ deg, int* __restrict__ rowptr){
  __shared__ int wsum[16];
  const int C = (NN + 1023)/1024;
  int t = threadIdx.x, lane = t&63, wid = t>>6;
  int lo = t*C, hi = lo+C; if(lo>NN) lo=NN; if(hi>NN) hi=NN;
  int loc = 0;
  for(int i=lo;i<hi;i++) loc += deg[i];
  int x = loc;
#pragma unroll
  for(int off=1; off<64; off<<=1){ int y = __shfl_up(x, off); if(lane>=off) x += y; }
  if(lane==63) wsum[wid] = x;
  __syncthreads();
  if(wid==0 && lane<16){
    int w = wsum[lane];
#pragma unroll
    for(int off=1; off<16; off<<=1){ int y = __shfl_up(w, off); if(lane>=off) w += y; }
    wsum[lane]=w;
  }
  __syncthreads();
  int base = (wid>0? wsum[wid-1]:0) + (x - loc);
  int run = base;
  for(int i=lo;i<hi;i++){ rowptr[i] = run; run += deg[i]; }
  if(t==1023) rowptr[NN] = run;
}

__global__ __launch_bounds__(256) void k_fill_src(const int* __restrict__ esrc, const int* __restrict__ edst,
                                                  const int* __restrict__ rp_s, int* __restrict__ cur_s,
                                                  int* __restrict__ esrc_s, int* __restrict__ edst_s){
  int e = blockIdx.x*256 + threadIdx.x;
  if(e>=EE) return;
  int s = esrc[e], d = edst[e];
  int q = rp_s[s] + atomicAdd(&cur_s[s],1);
  esrc_s[q]=s; edst_s[q]=d;
}
__global__ __launch_bounds__(256) void k_fill_dst(const int* __restrict__ edst_s,
                                                  const int* __restrict__ rp_d, int* __restrict__ cur_d,
                                                  int* __restrict__ eidq){
  int q = blockIdx.x*256 + threadIdx.x;
  if(q>=EE) return;
  int d = edst_s[q];
  int p = rp_d[d] + atomicAdd(&cur_d[d],1);
  eidq[p] = q;
}

// ---------- s = f @ W_in ----------
__global__ __launch_bounds__(256) void k_sinit(const float* __restrict__ f,
                                               const float* __restrict__ Win,
                                               float* __restrict__ s){
  int n = blockIdx.x*256 + threadIdx.x;
  if(n>=NN) return;
  float fi[32], acc[32];
  const float4* fp = reinterpret_cast<const float4*>(f + (size_t)n*32);
#pragma unroll
  for(int i=0;i<8;i++){ float4 t=fp[i]; fi[4*i]=t.x; fi[4*i+1]=t.y; fi[4*i+2]=t.z; fi[4*i+3]=t.w; }
#pragma unroll
  for(int j=0;j<32;j++) acc[j]=0.f;
  for(int i=0;i<32;i++){
    float c=fi[i];
#pragma unroll
    for(int j=0;j<32;j++) acc[j]+=c*Win[i*32+j];
  }
  float4* sp = reinterpret_cast<float4*>(s + (size_t)n*32);
#pragma unroll
  for(int i=0;i<8;i++){ float4 t; t.x=acc[4*i]; t.y=acc[4*i+1]; t.z=acc[4*i+2]; t.w=acc[4*i+3]; sp[i]=t; }
}

// ---------- per-node precompute: 4-wave role split + LDS weights ----------
// QPh row (64 u32): [0..2]=pos f32, [3]=pad, [4..44)=80 q comps
// SPh row (256 u32): AKss 0, AKsv 16, PKvs 24, PKvvs 48, PKvvv 96,
//                    AVss 120, AVsv 136, PVvs 144, PVvvs 168, PVvvv 216, pos 240..242
// LDS f32 offsets:
#define LW_QS   0
#define LW_QV   1024
#define LW_KSS  1280
#define LW_KSV  2304
#define LW_KVS  2816
#define LW_KVVS 3072
#define LW_KVVV 3584
#define LW_VSS  3840
#define LW_VSV  4864
#define LW_VVS  5376
#define LW_VVVS 5632
#define LW_VVVV 6144

__device__ __forceinline__ void smat_pack(const float* __restrict__ Wl, const float* sn,
                                          unsigned* __restrict__ dst, int ncol){
  for(int j0=0;j0<ncol;j0+=8){
    float acc[8];
#pragma unroll
    for(int k=0;k<8;k++) acc[k]=0.f;
    for(int i=0;i<32;i++){
      float c=sn[i];
#pragma unroll
      for(int k=0;k<8;k++) acc[k]+=c*Wl[i*ncol+j0+k];
    }
    uint4 u; u.x=pk2(acc[0],acc[1]); u.y=pk2(acc[2],acc[3]);
    u.z=pk2(acc[4],acc[5]); u.w=pk2(acc[6],acc[7]);
    reinterpret_cast<uint4*>(dst)[j0>>3]=u;
  }
}
// 16 vector outputs (w0..w0+15), stride = W row stride; packs 48 comps
__device__ __forceinline__ void vmat16_pack(const float* __restrict__ Wl, const float* vn,
                                            unsigned* __restrict__ dst, int stride, int w0){
  float a48[48];
  for(int w=0;w<16;w++){
    float ax=0.f,ay=0.f,az=0.f;
#pragma unroll
    for(int t=0;t<16;t++){
      float wt=Wl[t*stride+w0+w];
      ax+=vn[t*3]*wt; ay+=vn[t*3+1]*wt; az+=vn[t*3+2]*wt;
    }
    a48[w*3]=ax; a48[w*3+1]=ay; a48[w*3+2]=az;
  }
#pragma unroll
  for(int k=0;k<6;k++){
    uint4 u; u.x=pk2(a48[8*k],a48[8*k+1]); u.y=pk2(a48[8*k+2],a48[8*k+3]);
    u.z=pk2(a48[8*k+4],a48[8*k+5]); u.w=pk2(a48[8*k+6],a48[8*k+7]);
    reinterpret_cast<uint4*>(dst)[k]=u;
  }
}

__global__ __launch_bounds__(256) void k_nodeprep(
  const float* __restrict__ s, const float* __restrict__ v, const float* __restrict__ pos,
  const float* __restrict__ Wqs, const float* __restrict__ Wqv,
  const float* __restrict__ Kss, const float* __restrict__ Ksv, const float* __restrict__ Kvs,
  const float* __restrict__ Kvvs, const float* __restrict__ Kvvv,
  const float* __restrict__ Vss, const float* __restrict__ Vsv, const float* __restrict__ Vvs,
  const float* __restrict__ Vvvs, const float* __restrict__ Vvvv,
  unsigned* __restrict__ QPh, unsigned* __restrict__ SPh)
{
  __shared__ float WL[6400];
  int tid=threadIdx.x;
  for(int i=tid;i<1024;i+=256) WL[LW_QS +i]=Wqs[i];
  for(int i=tid;i<256; i+=256) WL[LW_QV +i]=Wqv[i];
  for(int i=tid;i<1024;i+=256) WL[LW_KSS+i]=Kss[i];
  for(int i=tid;i<512; i+=256) WL[LW_KSV+i]=Ksv[i];
  for(int i=tid;i<256; i+=256) WL[LW_KVS+i]=Kvs[i];
  for(int i=tid;i<512; i+=256) WL[LW_KVVS+i]=Kvvs[i];
  for(int i=tid;i<256; i+=256) WL[LW_KVVV+i]=Kvvv[i];
  for(int i=tid;i<1024;i+=256) WL[LW_VSS+i]=Vss[i];
  for(int i=tid;i<512; i+=256) WL[LW_VSV+i]=Vsv[i];
  for(int i=tid;i<256; i+=256) WL[LW_VVS+i]=Vvs[i];
  for(int i=tid;i<512; i+=256) WL[LW_VVVS+i]=Vvvs[i];
  for(int i=tid;i<256; i+=256) WL[LW_VVVV+i]=Vvvv[i];
  __syncthreads();

  int wid=tid>>6, lane=tid&63;
  int n = blockIdx.x*64 + lane;
  if(n>=NN) return;
  unsigned* qrow = QPh + (size_t)n*64;
  unsigned* brow = SPh + (size_t)n*256;

  if(wid<2){
    float sn[32];
    const float4* sp=reinterpret_cast<const float4*>(s+(size_t)n*32);
#pragma unroll
    for(int i=0;i<8;i++){ float4 t=sp[i]; sn[4*i]=t.x; sn[4*i+1]=t.y; sn[4*i+2]=t.z; sn[4*i+3]=t.w; }
    if(wid==0){
      smat_pack(WL+LW_QS,  sn, qrow+4, 32);
      smat_pack(WL+LW_KSS, sn, brow,   32);
      qrow[0]=__float_as_uint(pos[(size_t)n*3]);
      qrow[1]=__float_as_uint(pos[(size_t)n*3+1]);
      qrow[2]=__float_as_uint(pos[(size_t)n*3+2]);
      qrow[3]=0u;
    }else{
      smat_pack(WL+LW_VSS, sn, brow+120, 32);
      smat_pack(WL+LW_KSV, sn, brow+16,  16);
      smat_pack(WL+LW_VSV, sn, brow+136, 16);
      float vn[48];
      const float4* vp=reinterpret_cast<const float4*>(v+(size_t)n*48);
#pragma unroll
      for(int i=0;i<12;i++){ float4 t=vp[i]; vn[4*i]=t.x; vn[4*i+1]=t.y; vn[4*i+2]=t.z; vn[4*i+3]=t.w; }
      vmat16_pack(WL+LW_QV, vn, qrow+20, 16, 0);
      brow[240]=__float_as_uint(pos[(size_t)n*3]);
      brow[241]=__float_as_uint(pos[(size_t)n*3+1]);
      brow[242]=__float_as_uint(pos[(size_t)n*3+2]);
    }
  }else{
    float vn[48];
    const float4* vp=reinterpret_cast<const float4*>(v+(size_t)n*48);
#pragma unroll
    for(int i=0;i<12;i++){ float4 t=vp[i]; vn[4*i]=t.x; vn[4*i+1]=t.y; vn[4*i+2]=t.z; vn[4*i+3]=t.w; }
    if(wid==2){
      vmat16_pack(WL+LW_KVS,  vn, brow+24,    16, 0);
      vmat16_pack(WL+LW_KVVS, vn, brow+48,    32, 0);
      vmat16_pack(WL+LW_KVVS, vn, brow+48+24, 32, 16);
      vmat16_pack(WL+LW_KVVV, vn, brow+96,    16, 0);
    }else{
      vmat16_pack(WL+LW_VVS,  vn, brow+144,     16, 0);
      vmat16_pack(WL+LW_VVVS, vn, brow+168,     32, 0);
      vmat16_pack(WL+LW_VVVS, vn, brow+168+24,  32, 16);
      vmat16_pack(WL+LW_VVVV, vn, brow+216,     16, 0);
    }
  }
}

// ---------- fused edge pass (src-sorted): LUT radial + logit + bf16 message ----------
__global__ __launch_bounds__(256) void k_edge(
  const int* __restrict__ esrc_s, const int* __restrict__ edst_s,
  const float* __restrict__ RT,
  const unsigned* __restrict__ QPh, const unsigned* __restrict__ SPh,
  float* __restrict__ logit, unsigned* __restrict__ rec)
{
  int q = blockIdx.x*256 + threadIdx.x;
  if(q>=EE) return;
  int src=esrc_s[q], dst=edst_s[q];
  const unsigned* B = SPh + (size_t)src*256;
  const unsigned* Q = QPh + (size_t)dst*64;
  float px = __uint_as_float(B[240]) - __uint_as_float(Q[0]);
  float py = __uint_as_float(B[241]) - __uint_as_float(Q[1]);
  float pz = __uint_as_float(B[242]) - __uint_as_float(Q[2]);
  float r = sqrtf(px*px+py*py+pz*pz);
  float inv = 1.f/(r+1e-9f);
  float yx=px*inv, yy=py*inv, yz=pz*inv;

  float u = r * ((float)(NBIN-1)/RMAXT);
  int i0 = (int)u; if(i0 > NBIN-2) i0 = NBIN-2;
  float fr = u - (float)i0; fr = fminf(fr, 1.f);
  const float4* T0 = reinterpret_cast<const float4*>(RT + (size_t)i0*16);
  const float4* T1 = reinterpret_cast<const float4*>(RT + (size_t)(i0+1)*16);
  float4 A0=T0[0], B0=T0[1], C0=T0[2];
  float4 A1=T1[0], B1=T1[1], C1=T1[2];
  float rk0=A0.x+fr*(A1.x-A0.x), rk1=A0.y+fr*(A1.y-A0.y);
  float rk2=A0.z+fr*(A1.z-A0.z), rk3=A0.w+fr*(A1.w-A0.w);
  float rk4=B0.x+fr*(B1.x-B0.x);
  float rv0=B0.y+fr*(B1.y-B0.y), rv1=B0.z+fr*(B1.z-B0.z);
  float rv2=B0.w+fr*(B1.w-B0.w);
  float rv3=C0.x+fr*(C1.x-C0.x), rv4=C0.y+fr*(C1.y-C0.y);

  float lg=0.f;
#pragma unroll
  for(int j=0;j<32;j++){
    float d = yx*gx(B,48,3*j)+yy*gx(B,48,3*j+1)+yz*gx(B,48,3*j+2);
    lg += gq(Q,j)*(rk0*gx(B,0,j) + rk3*d);
  }
#pragma unroll
  for(int w=0;w<16;w++){
    float ax=gx(B,96,3*w),ay=gx(B,96,3*w+1),az=gx(B,96,3*w+2);
    float cx=ay*yz-az*yy, cy=az*yx-ax*yz, cz=ax*yy-ay*yx;   // cross(PKvvv, y)
    float aw=rk1*gx(B,16,w);
    float kx=aw*yx + rk2*gx(B,24,3*w)   + rk4*cx;
    float ky=aw*yy + rk2*gx(B,24,3*w+1) + rk4*cy;
    float kz=aw*yz + rk2*gx(B,24,3*w+2) + rk4*cz;
    lg += gq(Q,32+3*w)*kx + gq(Q,32+3*w+1)*ky + gq(Q,32+3*w+2)*kz;
  }
  lg *= 0.11180339887498948f;   // (S+3V)^-0.5
  logit[q]=lg;

  uint4* rp = reinterpret_cast<uint4*>(rec + (size_t)q*40);
#pragma unroll
  for(int j2=0;j2<4;j2++){
    float m8[8];
#pragma unroll
    for(int k=0;k<8;k++){
      int j=8*j2+k;
      float d = yx*gx(B,168,3*j)+yy*gx(B,168,3*j+1)+yz*gx(B,168,3*j+2);
      m8[k] = rv0*gx(B,120,j) + rv3*d;
    }
    uint4 u2; u2.x=pk2(m8[0],m8[1]); u2.y=pk2(m8[2],m8[3]);
    u2.z=pk2(m8[4],m8[5]); u2.w=pk2(m8[6],m8[7]);
    rp[j2]=u2;
  }
  unsigned rb[24];
#pragma unroll
  for(int w2=0;w2<8;w2++){
    float mm[6];
#pragma unroll
    for(int k=0;k<2;k++){
      int ww=2*w2+k;
      float ax=gx(B,216,3*ww),ay=gx(B,216,3*ww+1),az=gx(B,216,3*ww+2);
      float cx=ay*yz-az*yy, cy=az*yx-ax*yz, cz=ax*yy-ay*yx;   // cross(PVvvv, y)
      float aw=rv1*gx(B,136,ww);
      mm[3*k+0]=aw*yx + rv2*gx(B,144,3*ww)   + rv4*cx;
      mm[3*k+1]=aw*yy + rv2*gx(B,144,3*ww+1) + rv4*cy;
      mm[3*k+2]=aw*yz + rv2*gx(B,144,3*ww+2) + rv4*cz;
    }
    rb[3*w2]  =pk2(mm[0],mm[1]);
    rb[3*w2+1]=pk2(mm[2],mm[3]);
    rb[3*w2+2]=pk2(mm[4],mm[5]);
  }
#pragma unroll
  for(int k=0;k<6;k++){
    uint4 u2; u2.x=rb[4*k]; u2.y=rb[4*k+1]; u2.z=rb[4*k+2]; u2.w=rb[4*k+3];
    rp[4+k]=u2;
  }
}

// ---------- gather: wave-per-node, chunk max + 4-deep shfl-broadcast accumulate ----------
__global__ __launch_bounds__(256) void k_gather(
  const int* __restrict__ rp_d, const int* __restrict__ eidq,
  const float* __restrict__ logit, const unsigned* __restrict__ rec,
  float* __restrict__ s, float* __restrict__ v)
{
  int wid = threadIdx.x>>6, lane = threadIdx.x&63;
  int n = blockIdx.x*4 + wid;
  if(n>=NN) return;
  int i0=rp_d[n], i1=rp_d[n+1];
  bool act = lane<40;
  float mx=-3.4e38f, z=0.f, aX=0.f, aY=0.f;
  for(int base=i0; base<i1; base+=64){
    int cnt = i1-base; if(cnt>64) cnt=64;
    int q = 0; float lg = -3.4e38f;
    if(lane<cnt){ q = eidq[base+lane]; lg = logit[q]; }
    float cm = lg;
#pragma unroll
    for(int off=32; off; off>>=1) cm = fmaxf(cm, __shfl_xor(cm, off));
    if(cm > mx){
      float sc = __expf(mx - cm);
      z*=sc; aX*=sc; aY*=sc; mx=cm;
    }
    float a = (lane<cnt)? __expf(lg - mx) : 0.f;
    int i=0;
    for(; i+4<=cnt; i+=4){
      int q0=__shfl(q,i), q1=__shfl(q,i+1), q2=__shfl(q,i+2), q3=__shfl(q,i+3);
      float a0=__shfl(a,i), a1=__shfl(a,i+1), a2=__shfl(a,i+2), a3=__shfl(a,i+3);
      unsigned c0 = act? rec[(size_t)q0*40+lane] : 0u;
      unsigned c1 = act? rec[(size_t)q1*40+lane] : 0u;
      unsigned c2 = act? rec[(size_t)q2*40+lane] : 0u;
      unsigned c3 = act? rec[(size_t)q3*40+lane] : 0u;
      aX += a0*bf2f(c0&0xffffu) + a1*bf2f(c1&0xffffu) + a2*bf2f(c2&0xffffu) + a3*bf2f(c3&0xffffu);
      aY += a0*bf2f(c0>>16)     + a1*bf2f(c1>>16)     + a2*bf2f(c2>>16)     + a3*bf2f(c3>>16);
      z  += a0+a1+a2+a3;
    }
    for(; i<cnt; i++){
      int   qi = __shfl(q, i);
      float ai = __shfl(a, i);
      unsigned c = act? rec[(size_t)qi*40+lane] : 0u;
      aX += ai*bf2f(c&0xffffu);
      aY += ai*bf2f(c>>16);
      z  += ai;
    }
  }
  float zi = 1.f/(z+1e-9f);
  int c = lane*2;
  if(lane<16){
    float2* spp = reinterpret_cast<float2*>(s + (size_t)n*32 + c);
    float2 t = *spp; t.x += aX*zi; t.y += aY*zi; *spp = t;
  } else if(lane<40){
    float2* vpp = reinterpret_cast<float2*>(v + (size_t)n*48 + (c-32));
    float2 t = *vpp; t.x += aX*zi; t.y += aY*zi; *vpp = t;
  }
}

// ---------- readout: FullyConnectedTensorProduct (f32 output) ----------
__global__ __launch_bounds__(256) void k_readout(
  const float* __restrict__ s, const float* __restrict__ v,
  const float* __restrict__ Wsss, const float* __restrict__ Wvvs,
  const float* __restrict__ Wsvv, const float* __restrict__ Wvsv, const float* __restrict__ Wvvv,
  float* __restrict__ out)
{
  int n = blockIdx.x*256 + threadIdx.x;
  if(n>=NN) return;
  float sn[32], vn[48];
  const float4* sp=reinterpret_cast<const float4*>(s+(size_t)n*32);
#pragma unroll
  for(int i=0;i<8;i++){ float4 t=sp[i]; sn[4*i]=t.x; sn[4*i+1]=t.y; sn[4*i+2]=t.z; sn[4*i+3]=t.w; }
  const float4* vp=reinterpret_cast<const float4*>(v+(size_t)n*48);
#pragma unroll
  for(int i=0;i<12;i++){ float4 t=vp[i]; vn[4*i]=t.x; vn[4*i+1]=t.y; vn[4*i+2]=t.z; vn[4*i+3]=t.w; }

  float os[16];
#pragma unroll
  for(int o=0;o<16;o++) os[o]=0.f;
  for(int a=0;a<32;a++){
    float sa=sn[a];
    for(int t=0;t<32;t++){
      float st=sa*sn[t];
      const float* w=Wsss+((size_t)a*32+t)*16;
#pragma unroll
      for(int o=0;o<16;o++) os[o]+=st*w[o];
    }
  }
  for(int a=0;a<16;a++){
    float ax=vn[a*3],ay=vn[a*3+1],az=vn[a*3+2];
    for(int b=0;b<16;b++){
      float d=ax*vn[b*3]+ay*vn[b*3+1]+az*vn[b*3+2];
      const float* w=Wvvs+((size_t)a*16+b)*16;
#pragma unroll
      for(int o=0;o<16;o++) os[o]+=d*w[o];
    }
  }
  float ov[24];
#pragma unroll
  for(int t=0;t<24;t++) ov[t]=0.f;
  for(int w=0;w<16;w++){
    float B[8];
#pragma unroll
    for(int o=0;o<8;o++) B[o]=0.f;
    for(int a=0;a<32;a++){
      const float* ww=Wsvv+((size_t)a*16+w)*8;
      float sa=sn[a];
#pragma unroll
      for(int o=0;o<8;o++) B[o]+=sa*ww[o];
    }
#pragma unroll
    for(int o=0;o<8;o++){ float b=B[o]; ov[o*3]+=b*vn[w*3]; ov[o*3+1]+=b*vn[w*3+1]; ov[o*3+2]+=b*vn[w*3+2]; }
  }
  for(int vv=0;vv<16;vv++){
    float B[8];
#pragma unroll
    for(int o=0;o<8;o++) B[o]=0.f;
    for(int a=0;a<32;a++){
      const float* ww=Wvsv+((size_t)vv*32+a)*8;
      float sa=sn[a];
#pragma unroll
      for(int o=0;o<8;o++) B[o]+=sa*ww[o];
    }
#pragma unroll
    for(int o=0;o<8;o++){ float b=B[o]; ov[o*3]+=b*vn[vv*3]; ov[o*3+1]+=b*vn[vv*3+1]; ov[o*3+2]+=b*vn[vv*3+2]; }
  }
  for(int a=0;a<16;a++){
    float ax=vn[a*3],ay=vn[a*3+1],az=vn[a*3+2];
    for(int b=0;b<16;b++){
      float bx=vn[b*3],by=vn[b*3+1],bz=vn[b*3+2];
      float cx=ay*bz-az*by, cy=az*bx-ax*bz, cz=ax*by-ay*bx;
      const float* w=Wvvv+((size_t)a*16+b)*8;
#pragma unroll
      for(int o=0;o<8;o++){ float wv=w[o]; ov[o*3]+=cx*wv; ov[o*3+1]+=cy*wv; ov[o*3+2]+=cz*wv; }
    }
  }
  float* op = out + (size_t)n*40;
#pragma unroll
  for(int o=0;o<16;o++) op[o]=os[o];
#pragma unroll
  for(int t=0;t<24;t++) op[16+t]=ov[t];
}

// ---------- launch ----------
extern "C" void kernel_launch(void* const* d_in, const int* in_sizes, int n_in,
                              void* d_out, int out_size, void* d_ws, size_t ws_size,
                              hipStream_t stream) {
  const float* f      = (const float*)d_in[0];
  const float* pos    = (const float*)d_in[1];
  const float* W_in   = (const float*)d_in[2];
  const float* Wq_s   = (const float*)d_in[3];
  const float* Wq_v   = (const float*)d_in[4];
  const float* Wk_ss  = (const float*)d_in[5];
  const float* Wk_sv  = (const float*)d_in[6];
  const float* Wk_vs  = (const float*)d_in[7];
  const float* Wk_vvs = (const float*)d_in[8];
  const float* Wk_vvv = (const float*)d_in[9];
  const float* W1k    = (const float*)d_in[10];
  const float* b1k    = (const float*)d_in[11];
  const float* W2k    = (const float*)d_in[12];
  const float* b2k    = (const float*)d_in[13];
  const float* Wv_ss  = (const float*)d_in[14];
  const float* Wv_sv  = (const float*)d_in[15];
  const float* Wv_vs  = (const float*)d_in[16];
  const float* Wv_vvs = (const float*)d_in[17];
  const float* Wv_vvv = (const float*)d_in[18];
  const float* W1v    = (const float*)d_in[19];
  const float* b1v    = (const float*)d_in[20];
  const float* W2v    = (const float*)d_in[21];
  const float* b2v    = (const float*)d_in[22];
  const float* Wr_sss = (const float*)d_in[23];
  const float* Wr_vvs = (const float*)d_in[24];
  const float* Wr_svv = (const float*)d_in[25];
  const float* Wr_vsv = (const float*)d_in[26];
  const float* Wr_vvv = (const float*)d_in[27];
  const int* esrc     = (const int*)d_in[28];
  const int* edst     = (const int*)d_in[29];

  char* w = (char*)d_ws;
  size_t off=0;
  auto takeB=[&](size_t bytes){ char* p=w+off; off+=(bytes+255)&~(size_t)255; return p; };
  float*    s      = (float*)   takeB((size_t)NN*32*4);
  float*    v      = (float*)   takeB((size_t)NN*48*4);
  unsigned* QPh    = (unsigned*)takeB((size_t)NN*64*4);
  unsigned* SPh    = (unsigned*)takeB((size_t)NN*256*4);
  unsigned* rec    = (unsigned*)takeB((size_t)EE*40*4);
  float*    logit  = (float*)   takeB((size_t)EE*4);
  float*    RT     = (float*)   takeB((size_t)2*NBIN*16*4);
  int*      esrc_s = (int*)     takeB((size_t)EE*4);
  int*      edst_s = (int*)     takeB((size_t)EE*4);
  int*      eidq   = (int*)     takeB((size_t)EE*4);
  int*      degs   = (int*)     takeB((size_t)NN*4*4);
  int*      rp_s   = (int*)     takeB((size_t)(NN+1)*4);
  int*      rp_d   = (int*)     takeB((size_t)(NN+1)*4);
  int* deg_s=degs, *cur_s=degs+NN, *deg_d=degs+2*NN, *cur_d=degs+3*NN;

  const int NB_N = (NN+255)/256;
  const int NB_E = (EE+255)/256;

  // radial LUT for both layers
  k_lut<<<(2*NBIN+255)/256,256,0,stream>>>(W1k,b1k,W2k,b2k, W1v,b1v,W2v,b2v, RT);

  // CSR build
  hipMemsetAsync(degs, 0, (size_t)NN*4*4, stream);
  k_hist<<<NB_E,256,0,stream>>>(esrc, edst, deg_s, deg_d);
  k_scan<<<1,1024,0,stream>>>(deg_s, rp_s);
  k_scan<<<1,1024,0,stream>>>(deg_d, rp_d);
  k_fill_src<<<NB_E,256,0,stream>>>(esrc, edst, rp_s, cur_s, esrc_s, edst_s);
  k_fill_dst<<<NB_E,256,0,stream>>>(edst_s, rp_d, cur_d, eidq);

  hipMemsetAsync(v, 0, (size_t)NN*48*4, stream);
  k_sinit<<<NB_N,256,0,stream>>>(f, W_in, s);

  for(int l=0;l<2;l++){
    k_nodeprep<<<(NN+63)/64,256,0,stream>>>(s, v, pos,
      Wq_s+l*1024, Wq_v+l*256,
      Wk_ss+l*1024, Wk_sv+l*512, Wk_vs+l*256, Wk_vvs+l*512, Wk_vvv+l*256,
      Wv_ss+l*1024, Wv_sv+l*512, Wv_vs+l*256, Wv_vvs+l*512, Wv_vvv+l*256,
      QPh, SPh);
    k_edge<<<NB_E,256,0,stream>>>(esrc_s, edst_s, RT + (size_t)l*NBIN*16,
      QPh, SPh, logit, rec);
    k_gather<<<(NN+3)/4,256,0,stream>>>(rp_d, eidq, logit, rec, s, v);
  }

  k_readout<<<NB_N,256,0,stream>>>(s, v, Wr_sss, Wr_vvs, Wr_svv, Wr_vsv, Wr_vvv,
                                   (float*)d_out);
}

// Round 12
// 1205.552 us; speedup vs baseline: 6.8421x; 1.0813x over previous
//
#include <hip/hip_runtime.h>

#define NN 50000
#define EE 800000
#define NBIN 8192
#define RMAXT 17.33f

// ---------- bf16 helpers (RNE) ----------
__device__ __forceinline__ unsigned f2bf(float f){
  unsigned u = __float_as_uint(f);
  return (u + 0x7fffu + ((u>>16)&1u)) >> 16;
}
__device__ __forceinline__ float bf2f(unsigned hs){ return __uint_as_float(hs<<16); }
__device__ __forceinline__ unsigned pk2(float a, float b){ return f2bf(a) | (f2bf(b)<<16); }
__device__ __forceinline__ float gx(const unsigned* __restrict__ B, int base, int c){
  unsigned u = B[base + (c>>1)];
  return bf2f((c&1)? (u>>16) : (u&0xffffu));
}
__device__ __forceinline__ float gq(const unsigned* __restrict__ Q, int c){
  unsigned u = Q[4 + (c>>1)];
  return bf2f((c&1)? (u>>16) : (u&0xffffu));
}

// radial MLP (exact) — used only by the LUT builder
__device__ __forceinline__ void radial_mlp(const float* __restrict__ W1,
                                           const float* __restrict__ b1,
                                           const float* __restrict__ W2,
                                           const float* __restrict__ b2,
                                           const float* basis, float* rk){
#pragma unroll
  for(int p=0;p<5;p++) rk[p]=b2[p];
  for(int h=0;h<64;h++){
    float t=b1[h];
#pragma unroll
    for(int b=0;b<16;b++) t += basis[b]*W1[b*64+h];
    float sg = t/(1.f+__expf(-t));
#pragma unroll
    for(int p=0;p<5;p++) rk[p]+=sg*W2[h*5+p];
  }
}

// ---------- radial LUT ----------
__global__ __launch_bounds__(256) void k_lut(
  const float* __restrict__ W1k, const float* __restrict__ b1k,
  const float* __restrict__ W2k, const float* __restrict__ b2k,
  const float* __restrict__ W1v, const float* __restrict__ b1v,
  const float* __restrict__ W2v, const float* __restrict__ b2v,
  float* __restrict__ RT)
{
  int idx = blockIdx.x*256 + threadIdx.x;
  if(idx >= 2*NBIN) return;
  int l = idx / NBIN, bin = idx % NBIN;
  float r = (float)bin * (RMAXT/(float)(NBIN-1));
  float basis[16];
#pragma unroll
  for(int b=0;b<16;b++){
    float d=(r - (10.f/15.f)*(float)b)*1.6f;
    basis[b]=__expf(-d*d);
  }
  float rk[5], rv[5];
  radial_mlp(W1k+l*1024, b1k+l*64, W2k+l*320, b2k+l*5, basis, rk);
  radial_mlp(W1v+l*1024, b1v+l*64, W2v+l*320, b2v+l*5, basis, rv);
  float* row = RT + ((size_t)l*NBIN + bin)*16;
#pragma unroll
  for(int p=0;p<5;p++) row[p]=rk[p];
#pragma unroll
  for(int p=0;p<5;p++) row[5+p]=rv[p];
  row[10]=0.f; row[11]=0.f;
}

// ---------- CSR build ----------
__global__ __launch_bounds__(256) void k_hist(const int* __restrict__ esrc, const int* __restrict__ edst,
                                              int* __restrict__ deg_s, int* __restrict__ deg_d){
  int e = blockIdx.x*256 + threadIdx.x;
  if(e<EE){ atomicAdd(&deg_s[esrc[e]],1); atomicAdd(&deg_d[edst[e]],1); }
}

__global__ __launch_bounds__(1024) void k_scan(const int* __restrict__ deg, int* __restrict__ rowptr){
  __shared__ int wsum[16];
  const int C = (NN + 1023)/1024;
  int t = threadIdx.x, lane = t&63, wid = t>>6;
  int lo = t*C, hi = lo+C; if(lo>NN) lo=NN; if(hi>NN) hi=NN;
  int loc = 0;
  for(int i=lo;i<hi;i++) loc += deg[i];
  int x = loc;
#pragma unroll
  for(int off=1; off<64; off<<=1){ int y = __shfl_up(x, off); if(lane>=off) x += y; }
  if(lane==63) wsum[wid] = x;
  __syncthreads();
  if(wid==0 && lane<16){
    int w = wsum[lane];
#pragma unroll
    for(int off=1; off<16; off<<=1){ int y = __shfl_up(w, off); if(lane>=off) w += y; }
    wsum[lane]=w;
  }
  __syncthreads();
  int base = (wid>0? wsum[wid-1]:0) + (x - loc);
  int run = base;
  for(int i=lo;i<hi;i++){ rowptr[i] = run; run += deg[i]; }
  if(t==1023) rowptr[NN] = run;
}

__global__ __launch_bounds__(256) void k_fill_src(const int* __restrict__ esrc, const int* __restrict__ edst,
                                                  const int* __restrict__ rp_s, int* __restrict__ cur_s,
                                                  int* __restrict__ esrc_s, int* __restrict__ edst_s){
  int e = blockIdx.x*256 + threadIdx.x;
  if(e>=EE) return;
  int s = esrc[e], d = edst[e];
  int q = rp_s[s] + atomicAdd(&cur_s[s],1);
  esrc_s[q]=s; edst_s[q]=d;
}
__global__ __launch_bounds__(256) void k_fill_dst(const int* __restrict__ edst_s,
                                                  const int* __restrict__ rp_d, int* __restrict__ cur_d,
                                                  int* __restrict__ eidq){
  int q = blockIdx.x*256 + threadIdx.x;
  if(q>=EE) return;
  int d = edst_s[q];
  int p = rp_d[d] + atomicAdd(&cur_d[d],1);
  eidq[p] = q;
}

// ---------- s = f @ W_in ----------
__global__ __launch_bounds__(256) void k_sinit(const float* __restrict__ f,
                                               const float* __restrict__ Win,
                                               float* __restrict__ s){
  int n = blockIdx.x*256 + threadIdx.x;
  if(n>=NN) return;
  float fi[32], acc[32];
  const float4* fp = reinterpret_cast<const float4*>(f + (size_t)n*32);
#pragma unroll
  for(int i=0;i<8;i++){ float4 t=fp[i]; fi[4*i]=t.x; fi[4*i+1]=t.y; fi[4*i+2]=t.z; fi[4*i+3]=t.w; }
#pragma unroll
  for(int j=0;j<32;j++) acc[j]=0.f;
  for(int i=0;i<32;i++){
    float c=fi[i];
#pragma unroll
    for(int j=0;j<32;j++) acc[j]+=c*Win[i*32+j];
  }
  float4* sp = reinterpret_cast<float4*>(s + (size_t)n*32);
#pragma unroll
  for(int i=0;i<8;i++){ float4 t; t.x=acc[4*i]; t.y=acc[4*i+1]; t.z=acc[4*i+2]; t.w=acc[4*i+3]; sp[i]=t; }
}

// ---------- per-node precompute: 4-wave role split + LDS weights ----------
// QPh row (64 u32): [0..2]=pos f32, [3]=pad, [4..44)=80 q comps
// SPh row (256 u32): AKss 0, AKsv 16, PKvs 24, PKvvs 48, PKvvv 96,
//                    AVss 120, AVsv 136, PVvs 144, PVvvs 168, PVvvv 216, pos 240..242
// LDS f32 offsets:
#define LW_QS   0
#define LW_QV   1024
#define LW_KSS  1280
#define LW_KSV  2304
#define LW_KVS  2816
#define LW_KVVS 3072
#define LW_KVVV 3584
#define LW_VSS  3840
#define LW_VSV  4864
#define LW_VVS  5376
#define LW_VVVS 5632
#define LW_VVVV 6144

__device__ __forceinline__ void smat_pack(const float* __restrict__ Wl, const float* sn,
                                          unsigned* __restrict__ dst, int ncol){
  for(int j0=0;j0<ncol;j0+=8){
    float acc[8];
#pragma unroll
    for(int k=0;k<8;k++) acc[k]=0.f;
    for(int i=0;i<32;i++){
      float c=sn[i];
#pragma unroll
      for(int k=0;k<8;k++) acc[k]+=c*Wl[i*ncol+j0+k];
    }
    uint4 u; u.x=pk2(acc[0],acc[1]); u.y=pk2(acc[2],acc[3]);
    u.z=pk2(acc[4],acc[5]); u.w=pk2(acc[6],acc[7]);
    reinterpret_cast<uint4*>(dst)[j0>>3]=u;
  }
}
// 16 vector outputs (w0..w0+15), stride = W row stride; packs 48 comps
__device__ __forceinline__ void vmat16_pack(const float* __restrict__ Wl, const float* vn,
                                            unsigned* __restrict__ dst, int stride, int w0){
  float a48[48];
  for(int w=0;w<16;w++){
    float ax=0.f,ay=0.f,az=0.f;
#pragma unroll
    for(int t=0;t<16;t++){
      float wt=Wl[t*stride+w0+w];
      ax+=vn[t*3]*wt; ay+=vn[t*3+1]*wt; az+=vn[t*3+2]*wt;
    }
    a48[w*3]=ax; a48[w*3+1]=ay; a48[w*3+2]=az;
  }
#pragma unroll
  for(int k=0;k<6;k++){
    uint4 u; u.x=pk2(a48[8*k],a48[8*k+1]); u.y=pk2(a48[8*k+2],a48[8*k+3]);
    u.z=pk2(a48[8*k+4],a48[8*k+5]); u.w=pk2(a48[8*k+6],a48[8*k+7]);
    reinterpret_cast<uint4*>(dst)[k]=u;
  }
}

__global__ __launch_bounds__(256) void k_nodeprep(
  const float* __restrict__ s, const float* __restrict__ v, const float* __restrict__ pos,
  const float* __restrict__ Wqs, const float* __restrict__ Wqv,
  const float* __restrict__ Kss, const float* __restrict__ Ksv, const float* __restrict__ Kvs,
  const float* __restrict__ Kvvs, const float* __restrict__ Kvvv,
  const float* __restrict__ Vss, const float* __restrict__ Vsv, const float* __restrict__ Vvs,
  const float* __restrict__ Vvvs, const float* __restrict__ Vvvv,
  unsigned* __restrict__ QPh, unsigned* __restrict__ SPh)
{
  __shared__ float WL[6400];
  int tid=threadIdx.x;
  for(int i=tid;i<1024;i+=256) WL[LW_QS +i]=Wqs[i];
  for(int i=tid;i<256; i+=256) WL[LW_QV +i]=Wqv[i];
  for(int i=tid;i<1024;i+=256) WL[LW_KSS+i]=Kss[i];
  for(int i=tid;i<512; i+=256) WL[LW_KSV+i]=Ksv[i];
  for(int i=tid;i<256; i+=256) WL[LW_KVS+i]=Kvs[i];
  for(int i=tid;i<512; i+=256) WL[LW_KVVS+i]=Kvvs[i];
  for(int i=tid;i<256; i+=256) WL[LW_KVVV+i]=Kvvv[i];
  for(int i=tid;i<1024;i+=256) WL[LW_VSS+i]=Vss[i];
  for(int i=tid;i<512; i+=256) WL[LW_VSV+i]=Vsv[i];
  for(int i=tid;i<256; i+=256) WL[LW_VVS+i]=Vvs[i];
  for(int i=tid;i<512; i+=256) WL[LW_VVVS+i]=Vvvs[i];
  for(int i=tid;i<256; i+=256) WL[LW_VVVV+i]=Vvvv[i];
  __syncthreads();

  int wid=tid>>6, lane=tid&63;
  int n = blockIdx.x*64 + lane;
  if(n>=NN) return;
  unsigned* qrow = QPh + (size_t)n*64;
  unsigned* brow = SPh + (size_t)n*256;

  if(wid<2){
    float sn[32];
    const float4* sp=reinterpret_cast<const float4*>(s+(size_t)n*32);
#pragma unroll
    for(int i=0;i<8;i++){ float4 t=sp[i]; sn[4*i]=t.x; sn[4*i+1]=t.y; sn[4*i+2]=t.z; sn[4*i+3]=t.w; }
    if(wid==0){
      smat_pack(WL+LW_QS,  sn, qrow+4, 32);
      smat_pack(WL+LW_KSS, sn, brow,   32);
      qrow[0]=__float_as_uint(pos[(size_t)n*3]);
      qrow[1]=__float_as_uint(pos[(size_t)n*3+1]);
      qrow[2]=__float_as_uint(pos[(size_t)n*3+2]);
      qrow[3]=0u;
    }else{
      smat_pack(WL+LW_VSS, sn, brow+120, 32);
      smat_pack(WL+LW_KSV, sn, brow+16,  16);
      smat_pack(WL+LW_VSV, sn, brow+136, 16);
      float vn[48];
      const float4* vp=reinterpret_cast<const float4*>(v+(size_t)n*48);
#pragma unroll
      for(int i=0;i<12;i++){ float4 t=vp[i]; vn[4*i]=t.x; vn[4*i+1]=t.y; vn[4*i+2]=t.z; vn[4*i+3]=t.w; }
      vmat16_pack(WL+LW_QV, vn, qrow+20, 16, 0);
      brow[240]=__float_as_uint(pos[(size_t)n*3]);
      brow[241]=__float_as_uint(pos[(size_t)n*3+1]);
      brow[242]=__float_as_uint(pos[(size_t)n*3+2]);
    }
  }else{
    float vn[48];
    const float4* vp=reinterpret_cast<const float4*>(v+(size_t)n*48);
#pragma unroll
    for(int i=0;i<12;i++){ float4 t=vp[i]; vn[4*i]=t.x; vn[4*i+1]=t.y; vn[4*i+2]=t.z; vn[4*i+3]=t.w; }
    if(wid==2){
      vmat16_pack(WL+LW_KVS,  vn, brow+24,    16, 0);
      vmat16_pack(WL+LW_KVVS, vn, brow+48,    32, 0);
      vmat16_pack(WL+LW_KVVS, vn, brow+48+24, 32, 16);
      vmat16_pack(WL+LW_KVVV, vn, brow+96,    16, 0);
    }else{
      vmat16_pack(WL+LW_VVS,  vn, brow+144,     16, 0);
      vmat16_pack(WL+LW_VVVS, vn, brow+168,     32, 0);
      vmat16_pack(WL+LW_VVVS, vn, brow+168+24,  32, 16);
      vmat16_pack(WL+LW_VVVV, vn, brow+216,     16, 0);
    }
  }
}

// ---------- fused edge pass (src-sorted): LUT radial + logit + bf16 message ----------
__global__ __launch_bounds__(256) void k_edge(
  const int* __restrict__ esrc_s, const int* __restrict__ edst_s,
  const float* __restrict__ RT,
  const unsigned* __restrict__ QPh, const unsigned* __restrict__ SPh,
  float* __restrict__ logit, unsigned* __restrict__ rec)
{
  int q = blockIdx.x*256 + threadIdx.x;
  if(q>=EE) return;
  int src=esrc_s[q], dst=edst_s[q];
  const unsigned* B = SPh + (size_t)src*256;
  const unsigned* Q = QPh + (size_t)dst*64;
  float px = __uint_as_float(B[240]) - __uint_as_float(Q[0]);
  float py = __uint_as_float(B[241]) - __uint_as_float(Q[1]);
  float pz = __uint_as_float(B[242]) - __uint_as_float(Q[2]);
  float r = sqrtf(px*px+py*py+pz*pz);
  float inv = 1.f/(r+1e-9f);
  float yx=px*inv, yy=py*inv, yz=pz*inv;

  float u = r * ((float)(NBIN-1)/RMAXT);
  int i0 = (int)u; if(i0 > NBIN-2) i0 = NBIN-2;
  float fr = u - (float)i0; fr = fminf(fr, 1.f);
  const float4* T0 = reinterpret_cast<const float4*>(RT + (size_t)i0*16);
  const float4* T1 = reinterpret_cast<const float4*>(RT + (size_t)(i0+1)*16);
  float4 A0=T0[0], B0=T0[1], C0=T0[2];
  float4 A1=T1[0], B1=T1[1], C1=T1[2];
  float rk0=A0.x+fr*(A1.x-A0.x), rk1=A0.y+fr*(A1.y-A0.y);
  float rk2=A0.z+fr*(A1.z-A0.z), rk3=A0.w+fr*(A1.w-A0.w);
  float rk4=B0.x+fr*(B1.x-B0.x);
  float rv0=B0.y+fr*(B1.y-B0.y), rv1=B0.z+fr*(B1.z-B0.z);
  float rv2=B0.w+fr*(B1.w-B0.w);
  float rv3=C0.x+fr*(C1.x-C0.x), rv4=C0.y+fr*(C1.y-C0.y);

  float lg=0.f;
#pragma unroll
  for(int j=0;j<32;j++){
    float d = yx*gx(B,48,3*j)+yy*gx(B,48,3*j+1)+yz*gx(B,48,3*j+2);
    lg += gq(Q,j)*(rk0*gx(B,0,j) + rk3*d);
  }
#pragma unroll
  for(int w=0;w<16;w++){
    float ax=gx(B,96,3*w),ay=gx(B,96,3*w+1),az=gx(B,96,3*w+2);
    float cx=ay*yz-az*yy, cy=az*yx-ax*yz, cz=ax*yy-ay*yx;   // cross(PKvvv, y)
    float aw=rk1*gx(B,16,w);
    float kx=aw*yx + rk2*gx(B,24,3*w)   + rk4*cx;
    float ky=aw*yy + rk2*gx(B,24,3*w+1) + rk4*cy;
    float kz=aw*yz + rk2*gx(B,24,3*w+2) + rk4*cz;
    lg += gq(Q,32+3*w)*kx + gq(Q,32+3*w+1)*ky + gq(Q,32+3*w+2)*kz;
  }
  lg *= 0.11180339887498948f;   // (S+3V)^-0.5
  logit[q]=lg;

  uint4* rp = reinterpret_cast<uint4*>(rec + (size_t)q*40);
#pragma unroll
  for(int j2=0;j2<4;j2++){
    float m8[8];
#pragma unroll
    for(int k=0;k<8;k++){
      int j=8*j2+k;
      float d = yx*gx(B,168,3*j)+yy*gx(B,168,3*j+1)+yz*gx(B,168,3*j+2);
      m8[k] = rv0*gx(B,120,j) + rv3*d;
    }
    uint4 u2; u2.x=pk2(m8[0],m8[1]); u2.y=pk2(m8[2],m8[3]);
    u2.z=pk2(m8[4],m8[5]); u2.w=pk2(m8[6],m8[7]);
    rp[j2]=u2;
  }
  unsigned rb[24];
#pragma unroll
  for(int w2=0;w2<8;w2++){
    float mm[6];
#pragma unroll
    for(int k=0;k<2;k++){
      int ww=2*w2+k;
      float ax=gx(B,216,3*ww),ay=gx(B,216,3*ww+1),az=gx(B,216,3*ww+2);
      float cx=ay*yz-az*yy, cy=az*yx-ax*yz, cz=ax*yy-ay*yx;   // cross(PVvvv, y)
      float aw=rv1*gx(B,136,ww);
      mm[3*k+0]=aw*yx + rv2*gx(B,144,3*ww)   + rv4*cx;
      mm[3*k+1]=aw*yy + rv2*gx(B,144,3*ww+1) + rv4*cy;
      mm[3*k+2]=aw*yz + rv2*gx(B,144,3*ww+2) + rv4*cz;
    }
    rb[3*w2]  =pk2(mm[0],mm[1]);
    rb[3*w2+1]=pk2(mm[2],mm[3]);
    rb[3*w2+2]=pk2(mm[4],mm[5]);
  }
#pragma unroll
  for(int k=0;k<6;k++){
    uint4 u2; u2.x=rb[4*k]; u2.y=rb[4*k+1]; u2.z=rb[4*k+2]; u2.w=rb[4*k+3];
    rp[4+k]=u2;
  }
}

// ---------- gather: wave-per-node, chunk max + 4-deep shfl-broadcast accumulate ----------
__global__ __launch_bounds__(256) void k_gather(
  const int* __restrict__ rp_d, const int* __restrict__ eidq,
  const float* __restrict__ logit, const unsigned* __restrict__ rec,
  float* __restrict__ s, float* __restrict__ v)
{
  int wid = threadIdx.x>>6, lane = threadIdx.x&63;
  int n = blockIdx.x*4 + wid;
  if(n>=NN) return;
  int i0=rp_d[n], i1=rp_d[n+1];
  bool act = lane<40;
  float mx=-3.4e38f, z=0.f, aX=0.f, aY=0.f;
  for(int base=i0; base<i1; base+=64){
    int cnt = i1-base; if(cnt>64) cnt=64;
    int q = 0; float lg = -3.4e38f;
    if(lane<cnt){ q = eidq[base+lane]; lg = logit[q]; }
    float cm = lg;
#pragma unroll
    for(int off=32; off; off>>=1) cm = fmaxf(cm, __shfl_xor(cm, off));
    if(cm > mx){
      float sc = __expf(mx - cm);
      z*=sc; aX*=sc; aY*=sc; mx=cm;
    }
    float a = (lane<cnt)? __expf(lg - mx) : 0.f;
    int i=0;
    for(; i+4<=cnt; i+=4){
      int q0=__shfl(q,i), q1=__shfl(q,i+1), q2=__shfl(q,i+2), q3=__shfl(q,i+3);
      float a0=__shfl(a,i), a1=__shfl(a,i+1), a2=__shfl(a,i+2), a3=__shfl(a,i+3);
      unsigned c0 = act? rec[(size_t)q0*40+lane] : 0u;
      unsigned c1 = act? rec[(size_t)q1*40+lane] : 0u;
      unsigned c2 = act? rec[(size_t)q2*40+lane] : 0u;
      unsigned c3 = act? rec[(size_t)q3*40+lane] : 0u;
      aX += a0*bf2f(c0&0xffffu) + a1*bf2f(c1&0xffffu) + a2*bf2f(c2&0xffffu) + a3*bf2f(c3&0xffffu);
      aY += a0*bf2f(c0>>16)     + a1*bf2f(c1>>16)     + a2*bf2f(c2>>16)     + a3*bf2f(c3>>16);
      z  += a0+a1+a2+a3;
    }
    for(; i<cnt; i++){
      int   qi = __shfl(q, i);
      float ai = __shfl(a, i);
      unsigned c = act? rec[(size_t)qi*40+lane] : 0u;
      aX += ai*bf2f(c&0xffffu);
      aY += ai*bf2f(c>>16);
      z  += ai;
    }
  }
  float zi = 1.f/(z+1e-9f);
  int c = lane*2;
  if(lane<16){
    float2* spp = reinterpret_cast<float2*>(s + (size_t)n*32 + c);
    float2 t = *spp; t.x += aX*zi; t.y += aY*zi; *spp = t;
  } else if(lane<40){
    float2* vpp = reinterpret_cast<float2*>(v + (size_t)n*48 + (c-32));
    float2 t = *vpp; t.x += aX*zi; t.y += aY*zi; *vpp = t;
  }
}

// ---------- readout: FCTP with bf16 LDS-staged weights ----------
// LDS u32 layout (each u32 = 2 consecutive last-dim weights):
// Wsss 0..8192, Wvvs 8192..10240, Wsvv 10240..12288, Wvsv 12288..14336, Wvvv 14336..15360
__global__ __launch_bounds__(256) void k_readout(
  const float* __restrict__ s, const float* __restrict__ v,
  const float* __restrict__ Wsss, const float* __restrict__ Wvvs,
  const float* __restrict__ Wsvv, const float* __restrict__ Wvsv, const float* __restrict__ Wvvv,
  float* __restrict__ out)
{
  __shared__ unsigned WL[15360];   // 61440 B
  int tid = threadIdx.x;
  for(int i=tid;i<8192;i+=256) WL[i]       = pk2(Wsss[2*i], Wsss[2*i+1]);
  for(int i=tid;i<2048;i+=256) WL[8192+i]  = pk2(Wvvs[2*i], Wvvs[2*i+1]);
  for(int i=tid;i<2048;i+=256) WL[10240+i] = pk2(Wsvv[2*i], Wsvv[2*i+1]);
  for(int i=tid;i<2048;i+=256) WL[12288+i] = pk2(Wvsv[2*i], Wvsv[2*i+1]);
  for(int i=tid;i<1024;i+=256) WL[14336+i] = pk2(Wvvv[2*i], Wvvv[2*i+1]);
  __syncthreads();

  int n = blockIdx.x*256 + tid;
  if(n>=NN) return;
  float sn[32], vn[48];
  const float4* sp=reinterpret_cast<const float4*>(s+(size_t)n*32);
#pragma unroll
  for(int i=0;i<8;i++){ float4 t=sp[i]; sn[4*i]=t.x; sn[4*i+1]=t.y; sn[4*i+2]=t.z; sn[4*i+3]=t.w; }
  const float4* vp=reinterpret_cast<const float4*>(v+(size_t)n*48);
#pragma unroll
  for(int i=0;i<12;i++){ float4 t=vp[i]; vn[4*i]=t.x; vn[4*i+1]=t.y; vn[4*i+2]=t.z; vn[4*i+3]=t.w; }

  float os[16];
#pragma unroll
  for(int o=0;o<16;o++) os[o]=0.f;
  // sss: W[a][t][o] pairs at (a*32+t)*8 + o/2
  for(int a=0;a<32;a++){
    float sa=sn[a];
    for(int t=0;t<32;t++){
      float st=sa*sn[t];
      const unsigned* w=WL+((a<<5)+t)*8;
#pragma unroll
      for(int o2=0;o2<8;o2++){
        unsigned u=w[o2];
        os[2*o2]  +=st*bf2f(u&0xffffu);
        os[2*o2+1]+=st*bf2f(u>>16);
      }
    }
  }
  // vvs: pairs at 8192+(a*16+b)*8
  for(int a=0;a<16;a++){
    float ax=vn[a*3],ay=vn[a*3+1],az=vn[a*3+2];
    for(int b=0;b<16;b++){
      float d=ax*vn[b*3]+ay*vn[b*3+1]+az*vn[b*3+2];
      const unsigned* w=WL+8192+((a<<4)+b)*8;
#pragma unroll
      for(int o2=0;o2<8;o2++){
        unsigned u=w[o2];
        os[2*o2]  +=d*bf2f(u&0xffffu);
        os[2*o2+1]+=d*bf2f(u>>16);
      }
    }
  }
  float ov[24];
#pragma unroll
  for(int t=0;t<24;t++) ov[t]=0.f;
  // svv: B[o]=sum_a s_a W[a][w][o]; pairs at 10240+(a*16+w)*4
  for(int w=0;w<16;w++){
    float B[8];
#pragma unroll
    for(int o=0;o<8;o++) B[o]=0.f;
    for(int a=0;a<32;a++){
      const unsigned* ww=WL+10240+((a<<4)+w)*4;
      float sa=sn[a];
#pragma unroll
      for(int o2=0;o2<4;o2++){
        unsigned u=ww[o2];
        B[2*o2]  +=sa*bf2f(u&0xffffu);
        B[2*o2+1]+=sa*bf2f(u>>16);
      }
    }
#pragma unroll
    for(int o=0;o<8;o++){ float b=B[o]; ov[o*3]+=b*vn[w*3]; ov[o*3+1]+=b*vn[w*3+1]; ov[o*3+2]+=b*vn[w*3+2]; }
  }
  // vsv: pairs at 12288+(vv*32+a)*4
  for(int vv=0;vv<16;vv++){
    float B[8];
#pragma unroll
    for(int o=0;o<8;o++) B[o]=0.f;
    for(int a=0;a<32;a++){
      const unsigned* ww=WL+12288+((vv<<5)+a)*4;
      float sa=sn[a];
#pragma unroll
      for(int o2=0;o2<4;o2++){
        unsigned u=ww[o2];
        B[2*o2]  +=sa*bf2f(u&0xffffu);
        B[2*o2+1]+=sa*bf2f(u>>16);
      }
    }
#pragma unroll
    for(int o=0;o<8;o++){ float b=B[o]; ov[o*3]+=b*vn[vv*3]; ov[o*3+1]+=b*vn[vv*3+1]; ov[o*3+2]+=b*vn[vv*3+2]; }
  }
  // vvv: pairs at 14336+(a*16+b)*4
  for(int a=0;a<16;a++){
    float ax=vn[a*3],ay=vn[a*3+1],az=vn[a*3+2];
    for(int b=0;b<16;b++){
      float bx=vn[b*3],by=vn[b*3+1],bz=vn[b*3+2];
      float cx=ay*bz-az*by, cy=az*bx-ax*bz, cz=ax*by-ay*bx;
      const unsigned* w=WL+14336+((a<<4)+b)*4;
#pragma unroll
      for(int o2=0;o2<4;o2++){
        unsigned u=w[o2];
        float w0=bf2f(u&0xffffu), w1=bf2f(u>>16);
        int oa=2*o2, ob=2*o2+1;
        ov[oa*3]+=cx*w0; ov[oa*3+1]+=cy*w0; ov[oa*3+2]+=cz*w0;
        ov[ob*3]+=cx*w1; ov[ob*3+1]+=cy*w1; ov[ob*3+2]+=cz*w1;
      }
    }
  }
  float* op = out + (size_t)n*40;
#pragma unroll
  for(int o=0;o<16;o++) op[o]=os[o];
#pragma unroll
  for(int t=0;t<24;t++) op[16+t]=ov[t];
}

// ---------- launch ----------
extern "C" void kernel_launch(void* const* d_in, const int* in_sizes, int n_in,
                              void* d_out, int out_size, void* d_ws, size_t ws_size,
                              hipStream_t stream) {
  const float* f      = (const float*)d_in[0];
  const float* pos    = (const float*)d_in[1];
  const float* W_in   = (const float*)d_in[2];
  const float* Wq_s   = (const float*)d_in[3];
  const float* Wq_v   = (const float*)d_in[4];
  const float* Wk_ss  = (const float*)d_in[5];
  const float* Wk_sv  = (const float*)d_in[6];
  const float* Wk_vs  = (const float*)d_in[7];
  const float* Wk_vvs = (const float*)d_in[8];
  const float* Wk_vvv = (const float*)d_in[9];
  const float* W1k    = (const float*)d_in[10];
  const float* b1k    = (const float*)d_in[11];
  const float* W2k    = (const float*)d_in[12];
  const float* b2k    = (const float*)d_in[13];
  const float* Wv_ss  = (const float*)d_in[14];
  const float* Wv_sv  = (const float*)d_in[15];
  const float* Wv_vs  = (const float*)d_in[16];
  const float* Wv_vvs = (const float*)d_in[17];
  const float* Wv_vvv = (const float*)d_in[18];
  const float* W1v    = (const float*)d_in[19];
  const float* b1v    = (const float*)d_in[20];
  const float* W2v    = (const float*)d_in[21];
  const float* b2v    = (const float*)d_in[22];
  const float* Wr_sss = (const float*)d_in[23];
  const float* Wr_vvs = (const float*)d_in[24];
  const float* Wr_svv = (const float*)d_in[25];
  const float* Wr_vsv = (const float*)d_in[26];
  const float* Wr_vvv = (const float*)d_in[27];
  const int* esrc     = (const int*)d_in[28];
  const int* edst     = (const int*)d_in[29];

  char* w = (char*)d_ws;
  size_t off=0;
  auto takeB=[&](size_t bytes){ char* p=w+off; off+=(bytes+255)&~(size_t)255; return p; };
  float*    s      = (float*)   takeB((size_t)NN*32*4);
  float*    v      = (float*)   takeB((size_t)NN*48*4);
  unsigned* QPh    = (unsigned*)takeB((size_t)NN*64*4);
  unsigned* SPh    = (unsigned*)takeB((size_t)NN*256*4);
  unsigned* rec    = (unsigned*)takeB((size_t)EE*40*4);
  float*    logit  = (float*)   takeB((size_t)EE*4);
  float*    RT     = (float*)   takeB((size_t)2*NBIN*16*4);
  int*      esrc_s = (int*)     takeB((size_t)EE*4);
  int*      edst_s = (int*)     takeB((size_t)EE*4);
  int*      eidq   = (int*)     takeB((size_t)EE*4);
  int*      degs   = (int*)     takeB((size_t)NN*4*4);
  int*      rp_s   = (int*)     takeB((size_t)(NN+1)*4);
  int*      rp_d   = (int*)     takeB((size_t)(NN+1)*4);
  int* deg_s=degs, *cur_s=degs+NN, *deg_d=degs+2*NN, *cur_d=degs+3*NN;

  const int NB_N = (NN+255)/256;
  const int NB_E = (EE+255)/256;

  // radial LUT for both layers
  k_lut<<<(2*NBIN+255)/256,256,0,stream>>>(W1k,b1k,W2k,b2k, W1v,b1v,W2v,b2v, RT);

  // CSR build
  hipMemsetAsync(degs, 0, (size_t)NN*4*4, stream);
  k_hist<<<NB_E,256,0,stream>>>(esrc, edst, deg_s, deg_d);
  k_scan<<<1,1024,0,stream>>>(deg_s, rp_s);
  k_scan<<<1,1024,0,stream>>>(deg_d, rp_d);
  k_fill_src<<<NB_E,256,0,stream>>>(esrc, edst, rp_s, cur_s, esrc_s, edst_s);
  k_fill_dst<<<NB_E,256,0,stream>>>(edst_s, rp_d, cur_d, eidq);

  hipMemsetAsync(v, 0, (size_t)NN*48*4, stream);
  k_sinit<<<NB_N,256,0,stream>>>(f, W_in, s);

  for(int l=0;l<2;l++){
    k_nodeprep<<<(NN+63)/64,256,0,stream>>>(s, v, pos,
      Wq_s+l*1024, Wq_v+l*256,
      Wk_ss+l*1024, Wk_sv+l*512, Wk_vs+l*256, Wk_vvs+l*512, Wk_vvv+l*256,
      Wv_ss+l*1024, Wv_sv+l*512, Wv_vs+l*256, Wv_vvs+l*512, Wv_vvv+l*256,
      QPh, SPh);
    k_edge<<<NB_E,256,0,stream>>>(esrc_s, edst_s, RT + (size_t)l*NBIN*16,
      QPh, SPh, logit, rec);
    k_gather<<<(NN+3)/4,256,0,stream>>>(rp_d, eidq, logit, rec, s, v);
  }

  k_readout<<<NB_N,256,0,stream>>>(s, v, Wr_sss, Wr_vvs, Wr_svv, Wr_vsv, Wr_vvv,
                                   (float*)d_out);
}

// Round 14
// 1198.329 us; speedup vs baseline: 6.8833x; 1.0060x over previous
//
#include <hip/hip_runtime.h>

#define NN 50000
#define EE 800000
#define NBIN 8192
#define RMAXT 17.33f

// ---------- bf16 helpers (RNE) ----------
__device__ __forceinline__ unsigned f2bf(float f){
  unsigned u = __float_as_uint(f);
  return (u + 0x7fffu + ((u>>16)&1u)) >> 16;
}
__device__ __forceinline__ float bf2f(unsigned hs){ return __uint_as_float(hs<<16); }
__device__ __forceinline__ unsigned pk2(float a, float b){ return f2bf(a) | (f2bf(b)<<16); }
__device__ __forceinline__ float gx(const unsigned* __restrict__ B, int base, int c){
  unsigned u = B[base + (c>>1)];
  return bf2f((c&1)? (u>>16) : (u&0xffffu));
}
__device__ __forceinline__ float gq(const unsigned* __restrict__ Q, int c){
  unsigned u = Q[4 + (c>>1)];
  return bf2f((c&1)? (u>>16) : (u&0xffffu));
}

// radial MLP (exact) — used only by the LUT builder
__device__ __forceinline__ void radial_mlp(const float* __restrict__ W1,
                                           const float* __restrict__ b1,
                                           const float* __restrict__ W2,
                                           const float* __restrict__ b2,
                                           const float* basis, float* rk){
#pragma unroll
  for(int p=0;p<5;p++) rk[p]=b2[p];
  for(int h=0;h<64;h++){
    float t=b1[h];
#pragma unroll
    for(int b=0;b<16;b++) t += basis[b]*W1[b*64+h];
    float sg = t/(1.f+__expf(-t));
#pragma unroll
    for(int p=0;p<5;p++) rk[p]+=sg*W2[h*5+p];
  }
}

// ---------- radial LUT ----------
__global__ __launch_bounds__(256) void k_lut(
  const float* __restrict__ W1k, const float* __restrict__ b1k,
  const float* __restrict__ W2k, const float* __restrict__ b2k,
  const float* __restrict__ W1v, const float* __restrict__ b1v,
  const float* __restrict__ W2v, const float* __restrict__ b2v,
  float* __restrict__ RT)
{
  int idx = blockIdx.x*256 + threadIdx.x;
  if(idx >= 2*NBIN) return;
  int l = idx / NBIN, bin = idx % NBIN;
  float r = (float)bin * (RMAXT/(float)(NBIN-1));
  float basis[16];
#pragma unroll
  for(int b=0;b<16;b++){
    float d=(r - (10.f/15.f)*(float)b)*1.6f;
    basis[b]=__expf(-d*d);
  }
  float rk[5], rv[5];
  radial_mlp(W1k+l*1024, b1k+l*64, W2k+l*320, b2k+l*5, basis, rk);
  radial_mlp(W1v+l*1024, b1v+l*64, W2v+l*320, b2v+l*5, basis, rv);
  float* row = RT + ((size_t)l*NBIN + bin)*16;
#pragma unroll
  for(int p=0;p<5;p++) row[p]=rk[p];
#pragma unroll
  for(int p=0;p<5;p++) row[5+p]=rv[p];
  row[10]=0.f; row[11]=0.f;
}

// ---------- CSR build ----------
__global__ __launch_bounds__(256) void k_hist(const int* __restrict__ esrc, const int* __restrict__ edst,
                                              int* __restrict__ deg_s, int* __restrict__ deg_d){
  int e = blockIdx.x*256 + threadIdx.x;
  if(e<EE){ atomicAdd(&deg_s[esrc[e]],1); atomicAdd(&deg_d[edst[e]],1); }
}

__global__ __launch_bounds__(1024) void k_scan(const int* __restrict__ deg, int* __restrict__ rowptr){
  __shared__ int wsum[16];
  const int C = (NN + 1023)/1024;
  int t = threadIdx.x, lane = t&63, wid = t>>6;
  int lo = t*C, hi = lo+C; if(lo>NN) lo=NN; if(hi>NN) hi=NN;
  int loc = 0;
  for(int i=lo;i<hi;i++) loc += deg[i];
  int x = loc;
#pragma unroll
  for(int off=1; off<64; off<<=1){ int y = __shfl_up(x, off); if(lane>=off) x += y; }
  if(lane==63) wsum[wid] = x;
  __syncthreads();
  if(wid==0 && lane<16){
    int w = wsum[lane];
#pragma unroll
    for(int off=1; off<16; off<<=1){ int y = __shfl_up(w, off); if(lane>=off) w += y; }
    wsum[lane]=w;
  }
  __syncthreads();
  int base = (wid>0? wsum[wid-1]:0) + (x - loc);
  int run = base;
  for(int i=lo;i<hi;i++){ rowptr[i] = run; run += deg[i]; }
  if(t==1023) rowptr[NN] = run;
}

__global__ __launch_bounds__(256) void k_fill_src(const int* __restrict__ esrc, const int* __restrict__ edst,
                                                  const int* __restrict__ rp_s, int* __restrict__ cur_s,
                                                  int* __restrict__ esrc_s, int* __restrict__ edst_s){
  int e = blockIdx.x*256 + threadIdx.x;
  if(e>=EE) return;
  int s = esrc[e], d = edst[e];
  int q = rp_s[s] + atomicAdd(&cur_s[s],1);
  esrc_s[q]=s; edst_s[q]=d;
}
__global__ __launch_bounds__(256) void k_fill_dst(const int* __restrict__ edst_s,
                                                  const int* __restrict__ rp_d, int* __restrict__ cur_d,
                                                  int* __restrict__ eidq){
  int q = blockIdx.x*256 + threadIdx.x;
  if(q>=EE) return;
  int d = edst_s[q];
  int p = rp_d[d] + atomicAdd(&cur_d[d],1);
  eidq[p] = q;
}

// ---------- s = f @ W_in ----------
__global__ __launch_bounds__(256) void k_sinit(const float* __restrict__ f,
                                               const float* __restrict__ Win,
                                               float* __restrict__ s){
  int n = blockIdx.x*256 + threadIdx.x;
  if(n>=NN) return;
  float fi[32], acc[32];
  const float4* fp = reinterpret_cast<const float4*>(f + (size_t)n*32);
#pragma unroll
  for(int i=0;i<8;i++){ float4 t=fp[i]; fi[4*i]=t.x; fi[4*i+1]=t.y; fi[4*i+2]=t.z; fi[4*i+3]=t.w; }
#pragma unroll
  for(int j=0;j<32;j++) acc[j]=0.f;
  for(int i=0;i<32;i++){
    float c=fi[i];
#pragma unroll
    for(int j=0;j<32;j++) acc[j]+=c*Win[i*32+j];
  }
  float4* sp = reinterpret_cast<float4*>(s + (size_t)n*32);
#pragma unroll
  for(int i=0;i<8;i++){ float4 t; t.x=acc[4*i]; t.y=acc[4*i+1]; t.z=acc[4*i+2]; t.w=acc[4*i+3]; sp[i]=t; }
}

// ---------- per-node precompute: 4-wave role split + LDS weights ----------
// QPh row (64 u32): [0..2]=pos f32, [3]=pad, [4..44)=80 q comps
// SPh row (256 u32): AKss 0, AKsv 16, PKvs 24, PKvvs 48, PKvvv 96,
//                    AVss 120, AVsv 136, PVvs 144, PVvvs 168, PVvvv 216, pos 240..242
#define LW_QS   0
#define LW_QV   1024
#define LW_KSS  1280
#define LW_KSV  2304
#define LW_KVS  2816
#define LW_KVVS 3072
#define LW_KVVV 3584
#define LW_VSS  3840
#define LW_VSV  4864
#define LW_VVS  5376
#define LW_VVVS 5632
#define LW_VVVV 6144

__device__ __forceinline__ void smat_pack(const float* __restrict__ Wl, const float* sn,
                                          unsigned* __restrict__ dst, int ncol){
  for(int j0=0;j0<ncol;j0+=8){
    float acc[8];
#pragma unroll
    for(int k=0;k<8;k++) acc[k]=0.f;
    for(int i=0;i<32;i++){
      float c=sn[i];
#pragma unroll
      for(int k=0;k<8;k++) acc[k]+=c*Wl[i*ncol+j0+k];
    }
    uint4 u; u.x=pk2(acc[0],acc[1]); u.y=pk2(acc[2],acc[3]);
    u.z=pk2(acc[4],acc[5]); u.w=pk2(acc[6],acc[7]);
    reinterpret_cast<uint4*>(dst)[j0>>3]=u;
  }
}
__device__ __forceinline__ void vmat16_pack(const float* __restrict__ Wl, const float* vn,
                                            unsigned* __restrict__ dst, int stride, int w0){
  float a48[48];
  for(int w=0;w<16;w++){
    float ax=0.f,ay=0.f,az=0.f;
#pragma unroll
    for(int t=0;t<16;t++){
      float wt=Wl[t*stride+w0+w];
      ax+=vn[t*3]*wt; ay+=vn[t*3+1]*wt; az+=vn[t*3+2]*wt;
    }
    a48[w*3]=ax; a48[w*3+1]=ay; a48[w*3+2]=az;
  }
#pragma unroll
  for(int k=0;k<6;k++){
    uint4 u; u.x=pk2(a48[8*k],a48[8*k+1]); u.y=pk2(a48[8*k+2],a48[8*k+3]);
    u.z=pk2(a48[8*k+4],a48[8*k+5]); u.w=pk2(a48[8*k+6],a48[8*k+7]);
    reinterpret_cast<uint4*>(dst)[k]=u;
  }
}

__global__ __launch_bounds__(256) void k_nodeprep(
  const float* __restrict__ s, const float* __restrict__ v, const float* __restrict__ pos,
  const float* __restrict__ Wqs, const float* __restrict__ Wqv,
  const float* __restrict__ Kss, const float* __restrict__ Ksv, const float* __restrict__ Kvs,
  const float* __restrict__ Kvvs, const float* __restrict__ Kvvv,
  const float* __restrict__ Vss, const float* __restrict__ Vsv, const float* __restrict__ Vvs,
  const float* __restrict__ Vvvs, const float* __restrict__ Vvvv,
  unsigned* __restrict__ QPh, unsigned* __restrict__ SPh)
{
  __shared__ float WL[6400];
  int tid=threadIdx.x;
  for(int i=tid;i<1024;i+=256) WL[LW_QS +i]=Wqs[i];
  for(int i=tid;i<256; i+=256) WL[LW_QV +i]=Wqv[i];
  for(int i=tid;i<1024;i+=256) WL[LW_KSS+i]=Kss[i];
  for(int i=tid;i<512; i+=256) WL[LW_KSV+i]=Ksv[i];
  for(int i=tid;i<256; i+=256) WL[LW_KVS+i]=Kvs[i];
  for(int i=tid;i<512; i+=256) WL[LW_KVVS+i]=Kvvs[i];
  for(int i=tid;i<256; i+=256) WL[LW_KVVV+i]=Kvvv[i];
  for(int i=tid;i<1024;i+=256) WL[LW_VSS+i]=Vss[i];
  for(int i=tid;i<512; i+=256) WL[LW_VSV+i]=Vsv[i];
  for(int i=tid;i<256; i+=256) WL[LW_VVS+i]=Vvs[i];
  for(int i=tid;i<512; i+=256) WL[LW_VVVS+i]=Vvvs[i];
  for(int i=tid;i<256; i+=256) WL[LW_VVVV+i]=Vvvv[i];
  __syncthreads();

  int wid=tid>>6, lane=tid&63;
  int n = blockIdx.x*64 + lane;
  if(n>=NN) return;
  unsigned* qrow = QPh + (size_t)n*64;
  unsigned* brow = SPh + (size_t)n*256;

  if(wid<2){
    float sn[32];
    const float4* sp=reinterpret_cast<const float4*>(s+(size_t)n*32);
#pragma unroll
    for(int i=0;i<8;i++){ float4 t=sp[i]; sn[4*i]=t.x; sn[4*i+1]=t.y; sn[4*i+2]=t.z; sn[4*i+3]=t.w; }
    if(wid==0){
      smat_pack(WL+LW_QS,  sn, qrow+4, 32);
      smat_pack(WL+LW_KSS, sn, brow,   32);
      qrow[0]=__float_as_uint(pos[(size_t)n*3]);
      qrow[1]=__float_as_uint(pos[(size_t)n*3+1]);
      qrow[2]=__float_as_uint(pos[(size_t)n*3+2]);
      qrow[3]=0u;
    }else{
      smat_pack(WL+LW_VSS, sn, brow+120, 32);
      smat_pack(WL+LW_KSV, sn, brow+16,  16);
      smat_pack(WL+LW_VSV, sn, brow+136, 16);
      float vn[48];
      const float4* vp=reinterpret_cast<const float4*>(v+(size_t)n*48);
#pragma unroll
      for(int i=0;i<12;i++){ float4 t=vp[i]; vn[4*i]=t.x; vn[4*i+1]=t.y; vn[4*i+2]=t.z; vn[4*i+3]=t.w; }
      vmat16_pack(WL+LW_QV, vn, qrow+20, 16, 0);
      brow[240]=__float_as_uint(pos[(size_t)n*3]);
      brow[241]=__float_as_uint(pos[(size_t)n*3+1]);
      brow[242]=__float_as_uint(pos[(size_t)n*3+2]);
    }
  }else{
    float vn[48];
    const float4* vp=reinterpret_cast<const float4*>(v+(size_t)n*48);
#pragma unroll
    for(int i=0;i<12;i++){ float4 t=vp[i]; vn[4*i]=t.x; vn[4*i+1]=t.y; vn[4*i+2]=t.z; vn[4*i+3]=t.w; }
    if(wid==2){
      vmat16_pack(WL+LW_KVS,  vn, brow+24,    16, 0);
      vmat16_pack(WL+LW_KVVS, vn, brow+48,    32, 0);
      vmat16_pack(WL+LW_KVVS, vn, brow+48+24, 32, 16);
      vmat16_pack(WL+LW_KVVV, vn, brow+96,    16, 0);
    }else{
      vmat16_pack(WL+LW_VVS,  vn, brow+144,     16, 0);
      vmat16_pack(WL+LW_VVVS, vn, brow+168,     32, 0);
      vmat16_pack(WL+LW_VVVS, vn, brow+168+24,  32, 16);
      vmat16_pack(WL+LW_VVVV, vn, brow+216,     16, 0);
    }
  }
}

// ---------- fused edge pass (src-sorted): LUT radial + logit + bf16 message ----------
__global__ __launch_bounds__(256) void k_edge(
  const int* __restrict__ esrc_s, const int* __restrict__ edst_s,
  const float* __restrict__ RT,
  const unsigned* __restrict__ QPh, const unsigned* __restrict__ SPh,
  float* __restrict__ logit, unsigned* __restrict__ rec)
{
  int q = blockIdx.x*256 + threadIdx.x;
  if(q>=EE) return;
  int src=esrc_s[q], dst=edst_s[q];
  const unsigned* B = SPh + (size_t)src*256;
  const unsigned* Q = QPh + (size_t)dst*64;
  float px = __uint_as_float(B[240]) - __uint_as_float(Q[0]);
  float py = __uint_as_float(B[241]) - __uint_as_float(Q[1]);
  float pz = __uint_as_float(B[242]) - __uint_as_float(Q[2]);
  float r = sqrtf(px*px+py*py+pz*pz);
  float inv = 1.f/(r+1e-9f);
  float yx=px*inv, yy=py*inv, yz=pz*inv;

  float u = r * ((float)(NBIN-1)/RMAXT);
  int i0 = (int)u; if(i0 > NBIN-2) i0 = NBIN-2;
  float fr = u - (float)i0; fr = fminf(fr, 1.f);
  const float4* T0 = reinterpret_cast<const float4*>(RT + (size_t)i0*16);
  const float4* T1 = reinterpret_cast<const float4*>(RT + (size_t)(i0+1)*16);
  float4 A0=T0[0], B0=T0[1], C0=T0[2];
  float4 A1=T1[0], B1=T1[1], C1=T1[2];
  float rk0=A0.x+fr*(A1.x-A0.x), rk1=A0.y+fr*(A1.y-A0.y);
  float rk2=A0.z+fr*(A1.z-A0.z), rk3=A0.w+fr*(A1.w-A0.w);
  float rk4=B0.x+fr*(B1.x-B0.x);
  float rv0=B0.y+fr*(B1.y-B0.y), rv1=B0.z+fr*(B1.z-B0.z);
  float rv2=B0.w+fr*(B1.w-B0.w);
  float rv3=C0.x+fr*(C1.x-C0.x), rv4=C0.y+fr*(C1.y-C0.y);

  float lg=0.f;
#pragma unroll
  for(int j=0;j<32;j++){
    float d = yx*gx(B,48,3*j)+yy*gx(B,48,3*j+1)+yz*gx(B,48,3*j+2);
    lg += gq(Q,j)*(rk0*gx(B,0,j) + rk3*d);
  }
#pragma unroll
  for(int w=0;w<16;w++){
    float ax=gx(B,96,3*w),ay=gx(B,96,3*w+1),az=gx(B,96,3*w+2);
    float cx=ay*yz-az*yy, cy=az*yx-ax*yz, cz=ax*yy-ay*yx;   // cross(PKvvv, y)
    float aw=rk1*gx(B,16,w);
    float kx=aw*yx + rk2*gx(B,24,3*w)   + rk4*cx;
    float ky=aw*yy + rk2*gx(B,24,3*w+1) + rk4*cy;
    float kz=aw*yz + rk2*gx(B,24,3*w+2) + rk4*cz;
    lg += gq(Q,32+3*w)*kx + gq(Q,32+3*w+1)*ky + gq(Q,32+3*w+2)*kz;
  }
  lg *= 0.11180339887498948f;   // (S+3V)^-0.5
  logit[q]=lg;

  uint4* rp = reinterpret_cast<uint4*>(rec + (size_t)q*40);
#pragma unroll
  for(int j2=0;j2<4;j2++){
    float m8[8];
#pragma unroll
    for(int k=0;k<8;k++){
      int j=8*j2+k;
      float d = yx*gx(B,168,3*j)+yy*gx(B,168,3*j+1)+yz*gx(B,168,3*j+2);
      m8[k] = rv0*gx(B,120,j) + rv3*d;
    }
    uint4 u2; u2.x=pk2(m8[0],m8[1]); u2.y=pk2(m8[2],m8[3]);
    u2.z=pk2(m8[4],m8[5]); u2.w=pk2(m8[6],m8[7]);
    rp[j2]=u2;
  }
  unsigned rb[24];
#pragma unroll
  for(int w2=0;w2<8;w2++){
    float mm[6];
#pragma unroll
    for(int k=0;k<2;k++){
      int ww=2*w2+k;
      float ax=gx(B,216,3*ww),ay=gx(B,216,3*ww+1),az=gx(B,216,3*ww+2);
      float cx=ay*yz-az*yy, cy=az*yx-ax*yz, cz=ax*yy-ay*yx;   // cross(PVvvv, y)
      float aw=rv1*gx(B,136,ww);
      mm[3*k+0]=aw*yx + rv2*gx(B,144,3*ww)   + rv4*cx;
      mm[3*k+1]=aw*yy + rv2*gx(B,144,3*ww+1) + rv4*cy;
      mm[3*k+2]=aw*yz + rv2*gx(B,144,3*ww+2) + rv4*cz;
    }
    rb[3*w2]  =pk2(mm[0],mm[1]);
    rb[3*w2+1]=pk2(mm[2],mm[3]);
    rb[3*w2+2]=pk2(mm[4],mm[5]);
  }
#pragma unroll
  for(int k=0;k<6;k++){
    uint4 u2; u2.x=rb[4*k]; u2.y=rb[4*k+1]; u2.z=rb[4*k+2]; u2.w=rb[4*k+3];
    rp[4+k]=u2;
  }
}

// ---------- gather: wave-per-node, chunk max + 4-deep shfl-broadcast accumulate ----------
__global__ __launch_bounds__(256) void k_gather(
  const int* __restrict__ rp_d, const int* __restrict__ eidq,
  const float* __restrict__ logit, const unsigned* __restrict__ rec,
  float* __restrict__ s, float* __restrict__ v)
{
  int wid = threadIdx.x>>6, lane = threadIdx.x&63;
  int n = blockIdx.x*4 + wid;
  if(n>=NN) return;
  int i0=rp_d[n], i1=rp_d[n+1];
  bool act = lane<40;
  float mx=-3.4e38f, z=0.f, aX=0.f, aY=0.f;
  for(int base=i0; base<i1; base+=64){
    int cnt = i1-base; if(cnt>64) cnt=64;
    int q = 0; float lg = -3.4e38f;
    if(lane<cnt){ q = eidq[base+lane]; lg = logit[q]; }
    float cm = lg;
#pragma unroll
    for(int off=32; off; off>>=1) cm = fmaxf(cm, __shfl_xor(cm, off));
    if(cm > mx){
      float sc = __expf(mx - cm);
      z*=sc; aX*=sc; aY*=sc; mx=cm;
    }
    float a = (lane<cnt)? __expf(lg - mx) : 0.f;
    int i=0;
    for(; i+4<=cnt; i+=4){
      int q0=__shfl(q,i), q1=__shfl(q,i+1), q2=__shfl(q,i+2), q3=__shfl(q,i+3);
      float a0=__shfl(a,i), a1=__shfl(a,i+1), a2=__shfl(a,i+2), a3=__shfl(a,i+3);
      unsigned c0 = act? rec[(size_t)q0*40+lane] : 0u;
      unsigned c1 = act? rec[(size_t)q1*40+lane] : 0u;
      unsigned c2 = act? rec[(size_t)q2*40+lane] : 0u;
      unsigned c3 = act? rec[(size_t)q3*40+lane] : 0u;
      aX += a0*bf2f(c0&0xffffu) + a1*bf2f(c1&0xffffu) + a2*bf2f(c2&0xffffu) + a3*bf2f(c3&0xffffu);
      aY += a0*bf2f(c0>>16)     + a1*bf2f(c1>>16)     + a2*bf2f(c2>>16)     + a3*bf2f(c3>>16);
      z  += a0+a1+a2+a3;
    }
    for(; i<cnt; i++){
      int   qi = __shfl(q, i);
      float ai = __shfl(a, i);
      unsigned c = act? rec[(size_t)qi*40+lane] : 0u;
      aX += ai*bf2f(c&0xffffu);
      aY += ai*bf2f(c>>16);
      z  += ai;
    }
  }
  float zi = 1.f/(z+1e-9f);
  int c = lane*2;
  if(lane<16){
    float2* spp = reinterpret_cast<float2*>(s + (size_t)n*32 + c);
    float2 t = *spp; t.x += aX*zi; t.y += aY*zi; *spp = t;
  } else if(lane<40){
    float2* vpp = reinterpret_cast<float2*>(v + (size_t)n*48 + (c-32));
    float2 t = *vpp; t.x += aX*zi; t.y += aY*zi; *vpp = t;
  }
}

// ---------- readout: FCTP, bf16 LDS weights, 2 threads per node ----------
// LDS u32 layout: Wsss 0..8192, Wvvs 8192..10240, Wsvv 10240..12288,
//                 Wvsv 12288..14336, Wvvv 14336..15360
__global__ __launch_bounds__(256) void k_readout(
  const float* __restrict__ s, const float* __restrict__ v,
  const float* __restrict__ Wsss, const float* __restrict__ Wvvs,
  const float* __restrict__ Wsvv, const float* __restrict__ Wvsv, const float* __restrict__ Wvvv,
  float* __restrict__ out)
{
  __shared__ unsigned WL[15360];   // 61440 B
  int tid = threadIdx.x;
  for(int i=tid;i<8192;i+=256) WL[i]       = pk2(Wsss[2*i], Wsss[2*i+1]);
  for(int i=tid;i<2048;i+=256) WL[8192+i]  = pk2(Wvvs[2*i], Wvvs[2*i+1]);
  for(int i=tid;i<2048;i+=256) WL[10240+i] = pk2(Wsvv[2*i], Wsvv[2*i+1]);
  for(int i=tid;i<2048;i+=256) WL[12288+i] = pk2(Wvsv[2*i], Wvsv[2*i+1]);
  for(int i=tid;i<1024;i+=256) WL[14336+i] = pk2(Wvvv[2*i], Wvvv[2*i+1]);
  __syncthreads();

  int n = blockIdx.x*128 + (tid>>1);
  int half = tid&1;
  if(n>=NN) return;
  float sn[32], vn[48];
  const float4* sp=reinterpret_cast<const float4*>(s+(size_t)n*32);
#pragma unroll
  for(int i=0;i<8;i++){ float4 t=sp[i]; sn[4*i]=t.x; sn[4*i+1]=t.y; sn[4*i+2]=t.z; sn[4*i+3]=t.w; }
  const float4* vp=reinterpret_cast<const float4*>(v+(size_t)n*48);
#pragma unroll
  for(int i=0;i<12;i++){ float4 t=vp[i]; vn[4*i]=t.x; vn[4*i+1]=t.y; vn[4*i+2]=t.z; vn[4*i+3]=t.w; }

  float os[16];
#pragma unroll
  for(int o=0;o<16;o++) os[o]=0.f;
  // sss: half takes a in [16h,16h+16)
  {
    int a0 = half*16;
    for(int a=a0;a<a0+16;a++){
      float sa=sn[a];
      for(int t=0;t<32;t++){
        float st=sa*sn[t];
        const unsigned* w=WL+((a<<5)+t)*8;
#pragma unroll
        for(int o2=0;o2<8;o2++){
          unsigned u=w[o2];
          os[2*o2]  +=st*bf2f(u&0xffffu);
          os[2*o2+1]+=st*bf2f(u>>16);
        }
      }
    }
  }
  // vvs: half takes a in [8h,8h+8)
  {
    int a0 = half*8;
    for(int a=a0;a<a0+8;a++){
      float ax=vn[a*3],ay=vn[a*3+1],az=vn[a*3+2];
      for(int b=0;b<16;b++){
        float d=ax*vn[b*3]+ay*vn[b*3+1]+az*vn[b*3+2];
        const unsigned* w=WL+8192+((a<<4)+b)*8;
#pragma unroll
        for(int o2=0;o2<8;o2++){
          unsigned u=w[o2];
          os[2*o2]  +=d*bf2f(u&0xffffu);
          os[2*o2+1]+=d*bf2f(u>>16);
        }
      }
    }
  }
  float ov[24];
#pragma unroll
  for(int t=0;t<24;t++) ov[t]=0.f;
  // svv: half takes w in [8h,8h+8)
  {
    int w0 = half*8;
    for(int w=w0;w<w0+8;w++){
      float B[8];
#pragma unroll
      for(int o=0;o<8;o++) B[o]=0.f;
      for(int a=0;a<32;a++){
        const unsigned* ww=WL+10240+((a<<4)+w)*4;
        float sa=sn[a];
#pragma unroll
        for(int o2=0;o2<4;o2++){
          unsigned u=ww[o2];
          B[2*o2]  +=sa*bf2f(u&0xffffu);
          B[2*o2+1]+=sa*bf2f(u>>16);
        }
      }
#pragma unroll
      for(int o=0;o<8;o++){ float b=B[o]; ov[o*3]+=b*vn[w*3]; ov[o*3+1]+=b*vn[w*3+1]; ov[o*3+2]+=b*vn[w*3+2]; }
    }
  }
  // vsv: half takes vv in [8h,8h+8)
  {
    int v0 = half*8;
    for(int vv=v0;vv<v0+8;vv++){
      float B[8];
#pragma unroll
      for(int o=0;o<8;o++) B[o]=0.f;
      for(int a=0;a<32;a++){
        const unsigned* ww=WL+12288+((vv<<5)+a)*4;
        float sa=sn[a];
#pragma unroll
        for(int o2=0;o2<4;o2++){
          unsigned u=ww[o2];
          B[2*o2]  +=sa*bf2f(u&0xffffu);
          B[2*o2+1]+=sa*bf2f(u>>16);
        }
      }
#pragma unroll
      for(int o=0;o<8;o++){ float b=B[o]; ov[o*3]+=b*vn[vv*3]; ov[o*3+1]+=b*vn[vv*3+1]; ov[o*3+2]+=b*vn[vv*3+2]; }
    }
  }
  // vvv: half takes a in [8h,8h+8)
  {
    int a0 = half*8;
    for(int a=a0;a<a0+8;a++){
      float ax=vn[a*3],ay=vn[a*3+1],az=vn[a*3+2];
      for(int b=0;b<16;b++){
        float bx=vn[b*3],by=vn[b*3+1],bz=vn[b*3+2];
        float cx=ay*bz-az*by, cy=az*bx-ax*bz, cz=ax*by-ay*bx;
        const unsigned* w=WL+14336+((a<<4)+b)*4;
#pragma unroll
        for(int o2=0;o2<4;o2++){
          unsigned u=w[o2];
          float w0=bf2f(u&0xffffu), w1=bf2f(u>>16);
          int oa=2*o2, ob=2*o2+1;
          ov[oa*3]+=cx*w0; ov[oa*3+1]+=cy*w0; ov[oa*3+2]+=cz*w0;
          ov[ob*3]+=cx*w1; ov[ob*3+1]+=cy*w1; ov[ob*3+2]+=cz*w1;
        }
      }
    }
  }
  // pair-combine (lanes 2k and 2k+1 hold halves of the same node)
#pragma unroll
  for(int o=0;o<16;o++) os[o] += __shfl_xor(os[o], 1);
#pragma unroll
  for(int t=0;t<24;t++) ov[t] += __shfl_xor(ov[t], 1);
  if(half==0){
    float* op = out + (size_t)n*40;
#pragma unroll
    for(int o=0;o<16;o++) op[o]=os[o];
#pragma unroll
    for(int t=0;t<24;t++) op[16+t]=ov[t];
  }
}

// ---------- launch ----------
extern "C" void kernel_launch(void* const* d_in, const int* in_sizes, int n_in,
                              void* d_out, int out_size, void* d_ws, size_t ws_size,
                              hipStream_t stream) {
  const float* f      = (const float*)d_in[0];
  const float* pos    = (const float*)d_in[1];
  const float* W_in   = (const float*)d_in[2];
  const float* Wq_s   = (const float*)d_in[3];
  const float* Wq_v   = (const float*)d_in[4];
  const float* Wk_ss  = (const float*)d_in[5];
  const float* Wk_sv  = (const float*)d_in[6];
  const float* Wk_vs  = (const float*)d_in[7];
  const float* Wk_vvs = (const float*)d_in[8];
  const float* Wk_vvv = (const float*)d_in[9];
  const float* W1k    = (const float*)d_in[10];
  const float* b1k    = (const float*)d_in[11];
  const float* W2k    = (const float*)d_in[12];
  const float* b2k    = (const float*)d_in[13];
  const float* Wv_ss  = (const float*)d_in[14];
  const float* Wv_sv  = (const float*)d_in[15];
  const float* Wv_vs  = (const float*)d_in[16];
  const float* Wv_vvs = (const float*)d_in[17];
  const float* Wv_vvv = (const float*)d_in[18];
  const float* W1v    = (const float*)d_in[19];
  const float* b1v    = (const float*)d_in[20];
  const float* W2v    = (const float*)d_in[21];
  const float* b2v    = (const float*)d_in[22];
  const float* Wr_sss = (const float*)d_in[23];
  const float* Wr_vvs = (const float*)d_in[24];
  const float* Wr_svv = (const float*)d_in[25];
  const float* Wr_vsv = (const float*)d_in[26];
  const float* Wr_vvv = (const float*)d_in[27];
  const int* esrc     = (const int*)d_in[28];
  const int* edst     = (const int*)d_in[29];

  char* w = (char*)d_ws;
  size_t off=0;
  auto takeB=[&](size_t bytes){ char* p=w+off; off+=(bytes+255)&~(size_t)255; return p; };
  float*    s      = (float*)   takeB((size_t)NN*32*4);
  float*    v      = (float*)   takeB((size_t)NN*48*4);
  unsigned* QPh    = (unsigned*)takeB((size_t)NN*64*4);
  unsigned* SPh    = (unsigned*)takeB((size_t)NN*256*4);
  unsigned* rec    = (unsigned*)takeB((size_t)EE*40*4);
  float*    logit  = (float*)   takeB((size_t)EE*4);
  float*    RT     = (float*)   takeB((size_t)2*NBIN*16*4);
  int*      esrc_s = (int*)     takeB((size_t)EE*4);
  int*      edst_s = (int*)     takeB((size_t)EE*4);
  int*      eidq   = (int*)     takeB((size_t)EE*4);
  int*      degs   = (int*)     takeB((size_t)NN*4*4);
  int*      rp_s   = (int*)     takeB((size_t)(NN+1)*4);
  int*      rp_d   = (int*)     takeB((size_t)(NN+1)*4);
  int* deg_s=degs, *cur_s=degs+NN, *deg_d=degs+2*NN, *cur_d=degs+3*NN;

  const int NB_N = (NN+255)/256;
  const int NB_E = (EE+255)/256;

  // radial LUT for both layers
  k_lut<<<(2*NBIN+255)/256,256,0,stream>>>(W1k,b1k,W2k,b2k, W1v,b1v,W2v,b2v, RT);

  // CSR build
  hipMemsetAsync(degs, 0, (size_t)NN*4*4, stream);
  k_hist<<<NB_E,256,0,stream>>>(esrc, edst, deg_s, deg_d);
  k_scan<<<1,1024,0,stream>>>(deg_s, rp_s);
  k_scan<<<1,1024,0,stream>>>(deg_d, rp_d);
  k_fill_src<<<NB_E,256,0,stream>>>(esrc, edst, rp_s, cur_s, esrc_s, edst_s);
  k_fill_dst<<<NB_E,256,0,stream>>>(edst_s, rp_d, cur_d, eidq);

  hipMemsetAsync(v, 0, (size_t)NN*48*4, stream);
  k_sinit<<<NB_N,256,0,stream>>>(f, W_in, s);

  for(int l=0;l<2;l++){
    k_nodeprep<<<(NN+63)/64,256,0,stream>>>(s, v, pos,
      Wq_s+l*1024, Wq_v+l*256,
      Wk_ss+l*1024, Wk_sv+l*512, Wk_vs+l*256, Wk_vvs+l*512, Wk_vvv+l*256,
      Wv_ss+l*1024, Wv_sv+l*512, Wv_vs+l*256, Wv_vvs+l*512, Wv_vvv+l*256,
      QPh, SPh);
    k_edge<<<NB_E,256,0,stream>>>(esrc_s, edst_s, RT + (size_t)l*NBIN*16,
      QPh, SPh, logit, rec);
    k_gather<<<(NN+3)/4,256,0,stream>>>(rp_d, eidq, logit, rec, s, v);
  }

  k_readout<<<(NN+127)/128,256,0,stream>>>(s, v, Wr_sss, Wr_vvs, Wr_svv, Wr_vsv, Wr_vvv,
                                           (float*)d_out);
}